// Round 1
// baseline (1338.086 us; speedup 1.0000x reference)
//
#include <hip/hip_runtime.h>
#include <math.h>

// Problem constants
#define B_DIM 2
#define T_SEQ 1024
#define C_DIM 1024
#define H_DIM 16
#define N_DIM 64
#define M_ROWS (B_DIM * T_SEQ)   // 2048

// GEMM tiling
#define BM 64
#define BN 64
#define BK 16
#define LDPAD 72                 // BM + 8, keeps float4 LDS accesses 16B-aligned

__device__ __forceinline__ float preop_apply(float v, int preop) {
    if (preop == 1) return tanhf(v);
    if (preop == 2) return 1.0f / (1.0f + expf(-v));
    return v;
}

__device__ __forceinline__ float wred64(float v) {
#pragma unroll
    for (int m = 32; m; m >>= 1) v += __shfl_xor(v, m);
    return v;
}

// out[M,Nc] = preop(mix(X)) @ W (+ addend)
// If mixv != null: A[i,c] = x[i,c] + (x[i-1,c] - x[i,c]) * mixv[c], with x[-1]=0 per sequence.
__global__ __launch_bounds__(256) void gemm_kernel(
    const float* __restrict__ X, const float* __restrict__ mixv,
    const float* __restrict__ W, const float* __restrict__ addend,
    float* __restrict__ out,
    int M, int K, int Nc, int preop)
{
    __shared__ float As[BK][LDPAD];
    __shared__ float Bs[BK][LDPAD];

    const int tid = threadIdx.x;
    const int bm0 = blockIdx.y * BM;
    const int bn0 = blockIdx.x * BN;

    // A staging: 64 rows x 16 cols, 4 elems/thread along K
    const int a_row = tid >> 2;
    const int a_col = (tid & 3) << 2;
    // B staging: 16 rows x 64 cols, 4 elems/thread along N
    const int b_row = tid >> 4;
    const int b_col = (tid & 15) << 2;

    // compute micro-tile
    const int tr = (tid >> 4) << 2;
    const int tc = (tid & 15) << 2;

    const int row = bm0 + a_row;
    const int t_in = row & (T_SEQ - 1);

    float acc[4][4];
#pragma unroll
    for (int i = 0; i < 4; ++i)
#pragma unroll
        for (int j = 0; j < 4; ++j) acc[i][j] = 0.0f;

    for (int k0 = 0; k0 < K; k0 += BK) {
        // ---- load A tile (with optional token-shift mix + preop) ----
        {
            const float* xp = X + (size_t)row * K + (k0 + a_col);
            float4 xa = *(const float4*)xp;
            if (mixv) {
                float4 x_prev = make_float4(0.f, 0.f, 0.f, 0.f);
                if (t_in > 0) x_prev = *(const float4*)(xp - K);
                const float4 m4 = *(const float4*)(mixv + k0 + a_col);
                xa.x += (x_prev.x - xa.x) * m4.x;
                xa.y += (x_prev.y - xa.y) * m4.y;
                xa.z += (x_prev.z - xa.z) * m4.z;
                xa.w += (x_prev.w - xa.w) * m4.w;
            }
            if (preop) {
                xa.x = preop_apply(xa.x, preop);
                xa.y = preop_apply(xa.y, preop);
                xa.z = preop_apply(xa.z, preop);
                xa.w = preop_apply(xa.w, preop);
            }
            As[a_col + 0][a_row] = xa.x;
            As[a_col + 1][a_row] = xa.y;
            As[a_col + 2][a_row] = xa.z;
            As[a_col + 3][a_row] = xa.w;
        }
        // ---- load B tile ----
        {
            const int wr = k0 + b_row;
            const int wc = bn0 + b_col;
            float4 bv = make_float4(0.f, 0.f, 0.f, 0.f);
            const float* wp = W + (size_t)wr * Nc;
            if (wc + 3 < Nc) {
                bv = *(const float4*)(wp + wc);
            } else {
                if (wc     < Nc) bv.x = wp[wc];
                if (wc + 1 < Nc) bv.y = wp[wc + 1];
                if (wc + 2 < Nc) bv.z = wp[wc + 2];
            }
            *(float4*)&Bs[b_row][b_col] = bv;
        }
        __syncthreads();
#pragma unroll
        for (int kk = 0; kk < BK; ++kk) {
            const float4 av = *(const float4*)&As[kk][tr];
            const float4 bw = *(const float4*)&Bs[kk][tc];
            acc[0][0] += av.x * bw.x; acc[0][1] += av.x * bw.y;
            acc[0][2] += av.x * bw.z; acc[0][3] += av.x * bw.w;
            acc[1][0] += av.y * bw.x; acc[1][1] += av.y * bw.y;
            acc[1][2] += av.y * bw.z; acc[1][3] += av.y * bw.w;
            acc[2][0] += av.z * bw.x; acc[2][1] += av.z * bw.y;
            acc[2][2] += av.z * bw.z; acc[2][3] += av.z * bw.w;
            acc[3][0] += av.w * bw.x; acc[3][1] += av.w * bw.y;
            acc[3][2] += av.w * bw.z; acc[3][3] += av.w * bw.w;
        }
        __syncthreads();
    }

#pragma unroll
    for (int i = 0; i < 4; ++i) {
        const int orow = bm0 + tr + i;
#pragma unroll
        for (int j = 0; j < 4; ++j) {
            const int oc = bn0 + tc + j;
            if (oc < Nc) {
                float v = acc[i][j];
                if (addend) v += addend[(size_t)orow * Nc + oc];
                out[(size_t)orow * Nc + oc] = v;
            }
        }
    }
}

// Elementwise prep: one wave per (b,t,h); lane = channel within head.
// Reads the raw GEMM outputs, writes the scan inputs (several in place).
__global__ __launch_bounds__(256) void stage3_kernel(
    const float* k_lin, const float* v_lin, const float* v_first,
    const float* w_lora, const float* a_lora, const float* v_gate,
    const float* w0, const float* a0, const float* v0,
    const float* k_k, const float* k_a,
    float* k_out, float* v_out, float* ew_out,
    float* aa_out, float* bb_out)
{
    const int gw = (blockIdx.x * blockDim.x + threadIdx.x) >> 6; // (b*T+t)*H + h
    const int lane = threadIdx.x & 63;
    const int row = gw >> 4;      // b*T + t
    const int h = gw & 15;
    const int c = h * N_DIM + lane;
    const size_t idx = (size_t)row * C_DIM + c;

    const float kl = k_lin[idx];
    float kk = kl * k_k[c];
    float ss = wred64(kk * kk);
    const float nrm = fmaxf(sqrtf(ss), 1e-12f);
    const float kkn = kk / nrm;

    const float a = 1.0f / (1.0f + expf(-(a0[c] + a_lora[idx])));

    const float u = w0[c] + w_lora[idx];
    const float lnw = -log1pf(expf(-u)) - 0.5f;   // -softplus(-u) - 0.5
    const float logw = -expf(lnw);
    const float ew = expf(logw);

    const float sv = 1.0f / (1.0f + expf(-(v0[c] + v_gate[idx])));
    const float vl = v_lin[idx];
    const float v = vl + (v_first[idx] - vl) * sv;

    const float ko = kl * (1.0f + (a - 1.0f) * k_a[c]);

    k_out[idx] = ko;
    v_out[idx] = v;
    ew_out[idx] = ew;
    aa_out[idx] = -kkn;
    bb_out[idx] = kkn * a;
}

// Sequential scan: one wave per (b,h,v). Lane = k. State s[k] = S[v][k], 1 VGPR.
__global__ __launch_bounds__(256) void scan_kernel(
    const float* __restrict__ r, const float* __restrict__ ew,
    const float* __restrict__ k, const float* __restrict__ v,
    const float* __restrict__ aa, const float* __restrict__ bb,
    float* __restrict__ o)
{
    const int gw = (blockIdx.x * blockDim.x + threadIdx.x) >> 6; // (b*H+h)*N + vi
    const int lane = threadIdx.x & 63;
    const int vi = gw & 63;
    const int bh = gw >> 6;       // b*H + h
    const int b = bh >> 4;
    const int h = bh & 15;

    float s = 0.0f;
    const size_t base0 = ((size_t)b * T_SEQ) * C_DIM + (size_t)h * N_DIM;

    for (int t = 0; t < T_SEQ; ++t) {
        const size_t base = base0 + (size_t)t * C_DIM;
        const float rt = r[base + lane];
        const float et = ew[base + lane];
        const float kt = k[base + lane];
        const float at = aa[base + lane];
        const float bt = bb[base + lane];
        const float vt = v[base + vi];

        const float sa = wred64(s * at);
        s = s * et + sa * bt + vt * kt;
        const float ov = wred64(s * rt);
        if (lane == 0) o[base + vi] = ov;
    }
}

// GroupNorm + bonus term + gate: one wave per (b,t,h). y written in place over o.
__global__ __launch_bounds__(256) void post_kernel(
    const float* o, const float* r, const float* k, const float* v, const float* g,
    const float* r_k, const float* ln_w, const float* ln_b,
    float* y)
{
    const int gw = (blockIdx.x * blockDim.x + threadIdx.x) >> 6;
    const int lane = threadIdx.x & 63;
    const int row = gw >> 4;
    const int h = gw & 15;
    const int c = h * N_DIM + lane;
    const size_t idx = (size_t)row * C_DIM + c;

    const float oo = o[idx];
    float s1 = oo, s2 = oo * oo;
#pragma unroll
    for (int m = 32; m; m >>= 1) {
        s1 += __shfl_xor(s1, m);
        s2 += __shfl_xor(s2, m);
    }
    const float mu = s1 * (1.0f / 64.0f);
    const float var = s2 * (1.0f / 64.0f) - mu * mu;
    float yv = (oo - mu) * rsqrtf(var + 0.00064f);
    yv = yv * ln_w[c] + ln_b[c];

    const float t3 = wred64(r[idx] * k[idx] * r_k[c]);
    yv += t3 * v[idx];
    y[idx] = yv * g[idx];
}

extern "C" void kernel_launch(void* const* d_in, const int* in_sizes, int n_in,
                              void* d_out, int out_size, void* d_ws, size_t ws_size,
                              hipStream_t stream) {
    (void)in_sizes; (void)n_in; (void)out_size; (void)ws_size;

    const float* residual = (const float*)d_in[0];
    const float* x        = (const float*)d_in[1];
    const float* v_first  = (const float*)d_in[2];
    // d_in[3]=x0, d_in[4]=dx0, d_in[5]=token_ids : unused by the reference
    const float* mr = (const float*)d_in[6];
    const float* mw = (const float*)d_in[7];
    const float* mk = (const float*)d_in[8];
    const float* mv = (const float*)d_in[9];
    const float* ma = (const float*)d_in[10];
    const float* mg = (const float*)d_in[11];
    const float* w0 = (const float*)d_in[12];
    const float* w1 = (const float*)d_in[13];
    const float* w2 = (const float*)d_in[14];
    const float* a0 = (const float*)d_in[15];
    const float* a1 = (const float*)d_in[16];
    const float* a2 = (const float*)d_in[17];
    const float* v0 = (const float*)d_in[18];
    const float* v1 = (const float*)d_in[19];
    const float* v2 = (const float*)d_in[20];
    const float* g1 = (const float*)d_in[21];
    const float* g2 = (const float*)d_in[22];
    const float* k_k = (const float*)d_in[23];
    const float* k_a = (const float*)d_in[24];
    const float* r_k = (const float*)d_in[25];
    const float* W_r = (const float*)d_in[26];
    const float* W_k = (const float*)d_in[27];
    const float* W_v = (const float*)d_in[28];
    const float* W_o = (const float*)d_in[29];
    const float* ln_w = (const float*)d_in[30];
    const float* ln_b = (const float*)d_in[31];

    float* out = (float*)d_out;
    float* ws = (float*)d_ws;

    const size_t SZ = (size_t)M_ROWS * C_DIM;   // 2M floats
    float* b_r  = ws + 0 * SZ;
    float* b_k  = ws + 1 * SZ;   // k_lin -> k
    float* b_v  = ws + 2 * SZ;   // v_lin -> v
    float* b_w  = ws + 3 * SZ;   // w_lora -> exp(log_w)
    float* b_a  = ws + 4 * SZ;   // a_lora -> bb
    float* b_g  = ws + 5 * SZ;   // g
    float* b_vg = ws + 6 * SZ;   // v_gate -> aa
    float* b_o  = ws + 7 * SZ;   // o -> y
    float* sm   = ws + 8 * SZ;
    float* hw = sm;                    // [M,64]
    float* ha = sm + 131072;           // [M,64]
    float* hv = sm + 262144;           // [M,32]
    float* hg = sm + 327680;           // [M,160]

    const dim3 blk(256);
    auto gemm = [&](const float* X, const float* mx, const float* W,
                    const float* add, float* O, int M, int K, int Nc, int preop) {
        dim3 grid((Nc + BN - 1) / BN, M / BM);
        gemm_kernel<<<grid, blk, 0, stream>>>(X, mx, W, add, O, M, K, Nc, preop);
    };

    // Stage 1: token-shift-mixed projections (K = C = 1024)
    gemm(x, mr, W_r, nullptr, b_r, M_ROWS, C_DIM, C_DIM, 0);
    gemm(x, mk, W_k, nullptr, b_k, M_ROWS, C_DIM, C_DIM, 0);
    gemm(x, mv, W_v, nullptr, b_v, M_ROWS, C_DIM, C_DIM, 0);
    gemm(x, mw, w1, nullptr, hw, M_ROWS, C_DIM, 64, 0);
    gemm(x, ma, a1, nullptr, ha, M_ROWS, C_DIM, 64, 0);
    gemm(x, mv, v1, nullptr, hv, M_ROWS, C_DIM, 32, 0);
    gemm(x, mg, g1, nullptr, hg, M_ROWS, C_DIM, 160, 0);

    // Stage 2: LoRA second matmuls (activation fused as A-preop)
    gemm(hw, nullptr, w2, nullptr, b_w, M_ROWS, 64, C_DIM, 1);   // tanh
    gemm(ha, nullptr, a2, nullptr, b_a, M_ROWS, 64, C_DIM, 0);
    gemm(hv, nullptr, v2, nullptr, b_vg, M_ROWS, 32, C_DIM, 0);
    gemm(hg, nullptr, g2, nullptr, b_g, M_ROWS, 160, C_DIM, 2);  // sigmoid

    // Stage 3: elementwise prep (per-head normalize etc.)
    stage3_kernel<<<dim3((M_ROWS * H_DIM * 64) / 256), blk, 0, stream>>>(
        b_k, b_v, v_first, b_w, b_a, b_vg, w0, a0, v0, k_k, k_a,
        b_k, b_v, b_w, b_vg, b_a);

    // Stage 4: sequential scan, wave per (b,h,v)
    scan_kernel<<<dim3((B_DIM * H_DIM * N_DIM * 64) / 256), blk, 0, stream>>>(
        b_r, b_w, b_k, b_v, b_vg, b_a, b_o);

    // Stage 5: groupnorm + bonus + gate (in place on b_o)
    post_kernel<<<dim3((M_ROWS * H_DIM * 64) / 256), blk, 0, stream>>>(
        b_o, b_r, b_k, b_v, b_g, r_k, ln_w, ln_b, b_o);

    // Stage 6: output projection + residual
    gemm(b_o, nullptr, W_o, residual, out, M_ROWS, C_DIM, C_DIM, 0);
}

// Round 2
// 1118.555 us; speedup vs baseline: 1.1963x; 1.1963x over previous
//
#include <hip/hip_runtime.h>
#include <math.h>

// Problem constants
#define B_DIM 2
#define T_SEQ 1024
#define C_DIM 1024
#define H_DIM 16
#define N_DIM 64
#define M_ROWS (B_DIM * T_SEQ)   // 2048

// GEMM tiling
#define BM 64
#define BN 64
#define BK 16
#define LDPAD 72                 // BM + 8, keeps float4 LDS accesses 16B-aligned

__device__ __forceinline__ float preop_apply(float v, int preop) {
    if (preop == 1) return tanhf(v);
    if (preop == 2) return 1.0f / (1.0f + expf(-v));
    return v;
}

__device__ __forceinline__ float wred64(float v) {
#pragma unroll
    for (int m = 32; m; m >>= 1) v += __shfl_xor(v, m);
    return v;
}

// out[M,Nc] = preop(mix(X)) @ W (+ addend)
// If mixv != null: A[i,c] = x[i,c] + (x[i-1,c] - x[i,c]) * mixv[c], with x[-1]=0 per sequence.
__global__ __launch_bounds__(256) void gemm_kernel(
    const float* __restrict__ X, const float* __restrict__ mixv,
    const float* __restrict__ W, const float* __restrict__ addend,
    float* __restrict__ out,
    int M, int K, int Nc, int preop)
{
    __shared__ float As[BK][LDPAD];
    __shared__ float Bs[BK][LDPAD];

    const int tid = threadIdx.x;
    const int bm0 = blockIdx.y * BM;
    const int bn0 = blockIdx.x * BN;

    // A staging: 64 rows x 16 cols, 4 elems/thread along K
    const int a_row = tid >> 2;
    const int a_col = (tid & 3) << 2;
    // B staging: 16 rows x 64 cols, 4 elems/thread along N
    const int b_row = tid >> 4;
    const int b_col = (tid & 15) << 2;

    // compute micro-tile
    const int tr = (tid >> 4) << 2;
    const int tc = (tid & 15) << 2;

    const int row = bm0 + a_row;
    const int t_in = row & (T_SEQ - 1);

    float acc[4][4];
#pragma unroll
    for (int i = 0; i < 4; ++i)
#pragma unroll
        for (int j = 0; j < 4; ++j) acc[i][j] = 0.0f;

    for (int k0 = 0; k0 < K; k0 += BK) {
        // ---- load A tile (with optional token-shift mix + preop) ----
        {
            const float* xp = X + (size_t)row * K + (k0 + a_col);
            float4 xa = *(const float4*)xp;
            if (mixv) {
                float4 x_prev = make_float4(0.f, 0.f, 0.f, 0.f);
                if (t_in > 0) x_prev = *(const float4*)(xp - K);
                const float4 m4 = *(const float4*)(mixv + k0 + a_col);
                xa.x += (x_prev.x - xa.x) * m4.x;
                xa.y += (x_prev.y - xa.y) * m4.y;
                xa.z += (x_prev.z - xa.z) * m4.z;
                xa.w += (x_prev.w - xa.w) * m4.w;
            }
            if (preop) {
                xa.x = preop_apply(xa.x, preop);
                xa.y = preop_apply(xa.y, preop);
                xa.z = preop_apply(xa.z, preop);
                xa.w = preop_apply(xa.w, preop);
            }
            As[a_col + 0][a_row] = xa.x;
            As[a_col + 1][a_row] = xa.y;
            As[a_col + 2][a_row] = xa.z;
            As[a_col + 3][a_row] = xa.w;
        }
        // ---- load B tile ----
        {
            const int wr = k0 + b_row;
            const int wc = bn0 + b_col;
            float4 bv = make_float4(0.f, 0.f, 0.f, 0.f);
            const float* wp = W + (size_t)wr * Nc;
            if (wc + 3 < Nc) {
                bv = *(const float4*)(wp + wc);
            } else {
                if (wc     < Nc) bv.x = wp[wc];
                if (wc + 1 < Nc) bv.y = wp[wc + 1];
                if (wc + 2 < Nc) bv.z = wp[wc + 2];
            }
            *(float4*)&Bs[b_row][b_col] = bv;
        }
        __syncthreads();
#pragma unroll
        for (int kk = 0; kk < BK; ++kk) {
            const float4 av = *(const float4*)&As[kk][tr];
            const float4 bw = *(const float4*)&Bs[kk][tc];
            acc[0][0] += av.x * bw.x; acc[0][1] += av.x * bw.y;
            acc[0][2] += av.x * bw.z; acc[0][3] += av.x * bw.w;
            acc[1][0] += av.y * bw.x; acc[1][1] += av.y * bw.y;
            acc[1][2] += av.y * bw.z; acc[1][3] += av.y * bw.w;
            acc[2][0] += av.z * bw.x; acc[2][1] += av.z * bw.y;
            acc[2][2] += av.z * bw.z; acc[2][3] += av.z * bw.w;
            acc[3][0] += av.w * bw.x; acc[3][1] += av.w * bw.y;
            acc[3][2] += av.w * bw.z; acc[3][3] += av.w * bw.w;
        }
        __syncthreads();
    }

#pragma unroll
    for (int i = 0; i < 4; ++i) {
        const int orow = bm0 + tr + i;
#pragma unroll
        for (int j = 0; j < 4; ++j) {
            const int oc = bn0 + tc + j;
            if (oc < Nc) {
                float v = acc[i][j];
                if (addend) v += addend[(size_t)orow * Nc + oc];
                out[(size_t)orow * Nc + oc] = v;
            }
        }
    }
}

// Elementwise prep: one wave per (b,t,h); lane = channel within head.
__global__ __launch_bounds__(256) void stage3_kernel(
    const float* k_lin, const float* v_lin, const float* v_first,
    const float* w_lora, const float* a_lora, const float* v_gate,
    const float* w0, const float* a0, const float* v0,
    const float* k_k, const float* k_a,
    float* k_out, float* v_out, float* ew_out,
    float* aa_out, float* bb_out)
{
    const int gw = (blockIdx.x * blockDim.x + threadIdx.x) >> 6; // (b*T+t)*H + h
    const int lane = threadIdx.x & 63;
    const int row = gw >> 4;      // b*T + t
    const int h = gw & 15;
    const int c = h * N_DIM + lane;
    const size_t idx = (size_t)row * C_DIM + c;

    const float kl = k_lin[idx];
    float kk = kl * k_k[c];
    float ss = wred64(kk * kk);
    const float nrm = fmaxf(sqrtf(ss), 1e-12f);
    const float kkn = kk / nrm;

    const float a = 1.0f / (1.0f + expf(-(a0[c] + a_lora[idx])));

    const float u = w0[c] + w_lora[idx];
    const float lnw = -log1pf(expf(-u)) - 0.5f;   // -softplus(-u) - 0.5
    const float logw = -expf(lnw);
    const float ew = expf(logw);

    const float sv = 1.0f / (1.0f + expf(-(v0[c] + v_gate[idx])));
    const float vl = v_lin[idx];
    const float v = vl + (v_first[idx] - vl) * sv;

    const float ko = kl * (1.0f + (a - 1.0f) * k_a[c]);

    k_out[idx] = ko;
    v_out[idx] = v;
    ew_out[idx] = ew;
    aa_out[idx] = -kkn;
    bb_out[idx] = kkn * a;
}

// Sequential scan: one wave per (b,h,v). Lane = k. State s[k] = S[v][k], 1 VGPR.
// Critical-path optimized: only the sa-reduction is on the t->t+1 chain; the
// output reduction for step t-1 runs interleaved with step t's sa butterfly,
// and the 6 loads for step t+1 are prefetched before the butterflies of step t.
__global__ __launch_bounds__(256) void scan_kernel(
    const float* __restrict__ r, const float* __restrict__ ew,
    const float* __restrict__ k, const float* __restrict__ v,
    const float* __restrict__ aa, const float* __restrict__ bb,
    float* __restrict__ o)
{
    const int gw = (blockIdx.x * blockDim.x + threadIdx.x) >> 6; // (b*H+h)*N + vi
    const int lane = threadIdx.x & 63;
    const int vi = gw & 63;
    const int bh = gw >> 6;       // b*H + h
    const int b = bh >> 4;
    const int h = bh & 15;

    float s = 0.0f;
    const size_t base0 = ((size_t)b * T_SEQ) * C_DIM + (size_t)h * N_DIM;

    // preload t = 0
    float rt = r[base0 + lane];
    float et = ew[base0 + lane];
    float kt = k[base0 + lane];
    float at = aa[base0 + lane];
    float bt = bb[base0 + lane];
    float vt = v[base0 + vi];

    float r_prev = 0.0f;          // r of the step whose output is pending

    for (int t = 0; t < T_SEQ; ++t) {
        // prefetch t+1 (clamped on the last step; redundant load, no branch)
        const int tn = (t + 1 < T_SEQ) ? (t + 1) : t;
        const size_t nb = base0 + (size_t)tn * C_DIM;
        const float rn = r[nb + lane];
        const float en = ew[nb + lane];
        const float kn = k[nb + lane];
        const float an = aa[nb + lane];
        const float bn = bb[nb + lane];
        const float vn = v[nb + vi];

        // two interleaved butterflies over s = s_{t-1}:
        //   p -> sa_t = sum_k s*a_t   (critical path)
        //   q -> o_{t-1} = sum_k s*r_{t-1}  (pending output, off critical path)
        float p = s * at;
        float q = s * r_prev;
#pragma unroll
        for (int m = 32; m; m >>= 1) {
            p += __shfl_xor(p, m);
            q += __shfl_xor(q, m);
        }

        if (t > 0 && lane == 0)
            o[base0 + (size_t)(t - 1) * C_DIM + vi] = q;

        // state update
        s = s * et + p * bt + vt * kt;

        r_prev = rt;
        rt = rn; et = en; kt = kn; at = an; bt = bn; vt = vn;
    }

    // final pending output: o_{T-1} = sum_k s * r_{T-1}
    float q = s * r_prev;
    q = wred64(q);
    if (lane == 0)
        o[base0 + (size_t)(T_SEQ - 1) * C_DIM + vi] = q;
}

// GroupNorm + bonus term + gate: one wave per (b,t,h). y written in place over o.
__global__ __launch_bounds__(256) void post_kernel(
    const float* o, const float* r, const float* k, const float* v, const float* g,
    const float* r_k, const float* ln_w, const float* ln_b,
    float* y)
{
    const int gw = (blockIdx.x * blockDim.x + threadIdx.x) >> 6;
    const int lane = threadIdx.x & 63;
    const int row = gw >> 4;
    const int h = gw & 15;
    const int c = h * N_DIM + lane;
    const size_t idx = (size_t)row * C_DIM + c;

    const float oo = o[idx];
    float s1 = oo, s2 = oo * oo;
#pragma unroll
    for (int m = 32; m; m >>= 1) {
        s1 += __shfl_xor(s1, m);
        s2 += __shfl_xor(s2, m);
    }
    const float mu = s1 * (1.0f / 64.0f);
    const float var = s2 * (1.0f / 64.0f) - mu * mu;
    float yv = (oo - mu) * rsqrtf(var + 0.00064f);
    yv = yv * ln_w[c] + ln_b[c];

    const float t3 = wred64(r[idx] * k[idx] * r_k[c]);
    yv += t3 * v[idx];
    y[idx] = yv * g[idx];
}

extern "C" void kernel_launch(void* const* d_in, const int* in_sizes, int n_in,
                              void* d_out, int out_size, void* d_ws, size_t ws_size,
                              hipStream_t stream) {
    (void)in_sizes; (void)n_in; (void)out_size; (void)ws_size;

    const float* residual = (const float*)d_in[0];
    const float* x        = (const float*)d_in[1];
    const float* v_first  = (const float*)d_in[2];
    // d_in[3]=x0, d_in[4]=dx0, d_in[5]=token_ids : unused by the reference
    const float* mr = (const float*)d_in[6];
    const float* mw = (const float*)d_in[7];
    const float* mk = (const float*)d_in[8];
    const float* mv = (const float*)d_in[9];
    const float* ma = (const float*)d_in[10];
    const float* mg = (const float*)d_in[11];
    const float* w0 = (const float*)d_in[12];
    const float* w1 = (const float*)d_in[13];
    const float* w2 = (const float*)d_in[14];
    const float* a0 = (const float*)d_in[15];
    const float* a1 = (const float*)d_in[16];
    const float* a2 = (const float*)d_in[17];
    const float* v0 = (const float*)d_in[18];
    const float* v1 = (const float*)d_in[19];
    const float* v2 = (const float*)d_in[20];
    const float* g1 = (const float*)d_in[21];
    const float* g2 = (const float*)d_in[22];
    const float* k_k = (const float*)d_in[23];
    const float* k_a = (const float*)d_in[24];
    const float* r_k = (const float*)d_in[25];
    const float* W_r = (const float*)d_in[26];
    const float* W_k = (const float*)d_in[27];
    const float* W_v = (const float*)d_in[28];
    const float* W_o = (const float*)d_in[29];
    const float* ln_w = (const float*)d_in[30];
    const float* ln_b = (const float*)d_in[31];

    float* out = (float*)d_out;
    float* ws = (float*)d_ws;

    const size_t SZ = (size_t)M_ROWS * C_DIM;   // 2M floats
    float* b_r  = ws + 0 * SZ;
    float* b_k  = ws + 1 * SZ;   // k_lin -> k
    float* b_v  = ws + 2 * SZ;   // v_lin -> v
    float* b_w  = ws + 3 * SZ;   // w_lora -> exp(log_w)
    float* b_a  = ws + 4 * SZ;   // a_lora -> bb
    float* b_g  = ws + 5 * SZ;   // g
    float* b_vg = ws + 6 * SZ;   // v_gate -> aa
    float* b_o  = ws + 7 * SZ;   // o -> y
    float* sm   = ws + 8 * SZ;
    float* hw = sm;                    // [M,64]
    float* ha = sm + 131072;           // [M,64]
    float* hv = sm + 262144;           // [M,32]
    float* hg = sm + 327680;           // [M,160]

    const dim3 blk(256);
    auto gemm = [&](const float* X, const float* mx, const float* W,
                    const float* add, float* O, int M, int K, int Nc, int preop) {
        dim3 grid((Nc + BN - 1) / BN, M / BM);
        gemm_kernel<<<grid, blk, 0, stream>>>(X, mx, W, add, O, M, K, Nc, preop);
    };

    // Stage 1: token-shift-mixed projections (K = C = 1024)
    gemm(x, mr, W_r, nullptr, b_r, M_ROWS, C_DIM, C_DIM, 0);
    gemm(x, mk, W_k, nullptr, b_k, M_ROWS, C_DIM, C_DIM, 0);
    gemm(x, mv, W_v, nullptr, b_v, M_ROWS, C_DIM, C_DIM, 0);
    gemm(x, mw, w1, nullptr, hw, M_ROWS, C_DIM, 64, 0);
    gemm(x, ma, a1, nullptr, ha, M_ROWS, C_DIM, 64, 0);
    gemm(x, mv, v1, nullptr, hv, M_ROWS, C_DIM, 32, 0);
    gemm(x, mg, g1, nullptr, hg, M_ROWS, C_DIM, 160, 0);

    // Stage 2: LoRA second matmuls (activation fused as A-preop)
    gemm(hw, nullptr, w2, nullptr, b_w, M_ROWS, 64, C_DIM, 1);   // tanh
    gemm(ha, nullptr, a2, nullptr, b_a, M_ROWS, 64, C_DIM, 0);
    gemm(hv, nullptr, v2, nullptr, b_vg, M_ROWS, 32, C_DIM, 0);
    gemm(hg, nullptr, g2, nullptr, b_g, M_ROWS, 160, C_DIM, 2);  // sigmoid

    // Stage 3: elementwise prep (per-head normalize etc.)
    stage3_kernel<<<dim3((M_ROWS * H_DIM * 64) / 256), blk, 0, stream>>>(
        b_k, b_v, v_first, b_w, b_a, b_vg, w0, a0, v0, k_k, k_a,
        b_k, b_v, b_w, b_vg, b_a);

    // Stage 4: sequential scan, wave per (b,h,v)
    scan_kernel<<<dim3((B_DIM * H_DIM * N_DIM * 64) / 256), blk, 0, stream>>>(
        b_r, b_w, b_k, b_v, b_vg, b_a, b_o);

    // Stage 5: groupnorm + bonus + gate (in place on b_o)
    post_kernel<<<dim3((M_ROWS * H_DIM * 64) / 256), blk, 0, stream>>>(
        b_o, b_r, b_k, b_v, b_g, r_k, ln_w, ln_b, b_o);

    // Stage 6: output projection + residual
    gemm(b_o, nullptr, W_o, residual, out, M_ROWS, C_DIM, C_DIM, 0);
}

// Round 4
// 828.045 us; speedup vs baseline: 1.6160x; 1.3508x over previous
//
#include <hip/hip_runtime.h>
#include <math.h>

// Problem constants
#define B_DIM 2
#define T_SEQ 1024
#define C_DIM 1024
#define H_DIM 16
#define N_DIM 64
#define M_ROWS (B_DIM * T_SEQ)   // 2048

// fp32 GEMM tiling (kept for the sensitive w-LoRA path)
#define BM 64
#define BN 64
#define BK 16
#define LDPAD 72

// MFMA GEMM tiling
#define GBM 64
#define GBN 64
#define GBK 64
#define LDK 88                   // padded k-stride: 176B rows (16B-aligned, 2-way banks)

typedef __attribute__((ext_vector_type(8))) short bf16x8;
typedef __attribute__((ext_vector_type(4))) float f32x4;
typedef unsigned short ushortx4 __attribute__((ext_vector_type(4)));
typedef unsigned short ushortx8 __attribute__((ext_vector_type(8)));

__device__ __forceinline__ unsigned short f2bf(float f) {
    unsigned int u = __float_as_uint(f);
    u = (u + 0x7FFFu + ((u >> 16) & 1u)) >> 16;   // RNE
    return (unsigned short)u;
}
__device__ __forceinline__ float bf2f(unsigned short h) {
    return __uint_as_float(((unsigned int)h) << 16);
}

__device__ __forceinline__ float preop_apply(float v, int preop) {
    if (preop == 1) return tanhf(v);
    if (preop == 2) return 1.0f / (1.0f + expf(-v));
    return v;
}

__device__ __forceinline__ float wred64(float v) {
#pragma unroll
    for (int m = 32; m; m >>= 1) v += __shfl_xor(v, m);
    return v;
}

// ---------------- weight transpose + fp32->bf16 convert ----------------
// W [K][N] fp32 -> WT [N][K] bf16.  grid((N+31)/32, (K+31)/32), block(32,8)
__global__ __launch_bounds__(256) void wtrans_kernel(
    const float* __restrict__ W, unsigned short* __restrict__ WT, int K, int N)
{
    __shared__ float tile[32][33];
    const int tx = threadIdx.x, ty = threadIdx.y;
    const int n0 = blockIdx.x * 32, k0 = blockIdx.y * 32;
#pragma unroll
    for (int i = 0; i < 4; ++i) {
        int k = k0 + ty + i * 8, n = n0 + tx;
        if (k < K && n < N) tile[ty + i * 8][tx] = W[(size_t)k * N + n];
    }
    __syncthreads();
#pragma unroll
    for (int i = 0; i < 4; ++i) {
        int n = n0 + ty + i * 8, k = k0 + tx;
        if (n < N && k < K) WT[(size_t)n * K + k] = f2bf(tile[tx][ty + i * 8]);
    }
}

// ---------------- bf16 MFMA GEMM ----------------
// out[M,Nc] = preop(mix(X)) @ W  (+addend), W given pre-transposed bf16 WT[Nc][K].
// 256 thr = 4 waves in 2x2; wave tile 32x32 (2x2 frags of 16x16), BK=64.
template <bool OUTBF16>
__global__ __launch_bounds__(256) void gemm_mfma_kernel(
    const float* __restrict__ X, const float* __restrict__ mixv,
    const unsigned short* __restrict__ WT, const float* __restrict__ addend,
    void* __restrict__ outp, int K, int Nc, int preop)
{
    __shared__ unsigned short As[GBM][LDK];
    __shared__ unsigned short Bs[GBN][LDK];

    const int tid = threadIdx.x;
    const int lane = tid & 63;
    const int wid = tid >> 6;
    const int wr = wid >> 1, wc = wid & 1;
    const int l15 = lane & 15, l4 = lane >> 4;

    const int bm0 = blockIdx.y * GBM;
    const int bn0 = blockIdx.x * GBN;

    // A staging: row = tid>>2, k-slot base = (tid&3)*16, 4 float4 chunks
    const int ar = tid >> 2;
    const int as = (tid & 3) << 4;
    const int row = bm0 + ar;
    const int t_in = row & (T_SEQ - 1);

    // B staging: n = tid>>2, two 8-elem chunks at (tid&3)*16 + {0,8}
    const int brn = tid >> 2;
    const int bks = (tid & 3) << 4;
    const bool bn_ok = (bn0 + brn) < Nc;

    f32x4 acc[2][2] = {};

    for (int k0 = 0; k0 < K; k0 += GBK) {
        // ---- stage A (fp32 load, mix+preop, cvt bf16) ----
#pragma unroll
        for (int i = 0; i < 4; ++i) {
            const int kg = k0 + as + 4 * i;
            float4 xa = make_float4(0.f, 0.f, 0.f, 0.f);
            if (kg < K) {
                const float* xp = X + (size_t)row * K + kg;
                xa = *(const float4*)xp;
                if (mixv) {
                    float4 xp4 = make_float4(0.f, 0.f, 0.f, 0.f);
                    if (t_in > 0) xp4 = *(const float4*)(xp - K);
                    const float4 m4 = *(const float4*)(mixv + kg);
                    xa.x += (xp4.x - xa.x) * m4.x;
                    xa.y += (xp4.y - xa.y) * m4.y;
                    xa.z += (xp4.z - xa.z) * m4.z;
                    xa.w += (xp4.w - xa.w) * m4.w;
                }
                if (preop) {
                    xa.x = preop_apply(xa.x, preop);
                    xa.y = preop_apply(xa.y, preop);
                    xa.z = preop_apply(xa.z, preop);
                    xa.w = preop_apply(xa.w, preop);
                }
            }
            ushortx4 pk;
            pk.x = f2bf(xa.x); pk.y = f2bf(xa.y); pk.z = f2bf(xa.z); pk.w = f2bf(xa.w);
            *(ushortx4*)&As[ar][as + 4 * i] = pk;
        }
        // ---- stage B (bf16 16B loads from pre-transposed WT) ----
#pragma unroll
        for (int i = 0; i < 2; ++i) {
            const int kk = bks + 8 * i;
            const int kg = k0 + kk;
            ushortx8 bv = {0, 0, 0, 0, 0, 0, 0, 0};
            if (bn_ok && kg < K)
                bv = *(const ushortx8*)(WT + (size_t)(bn0 + brn) * K + kg);
            *(ushortx8*)&Bs[brn][kk] = bv;
        }
        __syncthreads();

#pragma unroll
        for (int ks = 0; ks < 2; ++ks) {
            bf16x8 af0 = *(const bf16x8*)&As[wr * 32 +      l15][ks * 32 + l4 * 8];
            bf16x8 af1 = *(const bf16x8*)&As[wr * 32 + 16 + l15][ks * 32 + l4 * 8];
            bf16x8 bg0 = *(const bf16x8*)&Bs[wc * 32 +      l15][ks * 32 + l4 * 8];
            bf16x8 bg1 = *(const bf16x8*)&Bs[wc * 32 + 16 + l15][ks * 32 + l4 * 8];
            acc[0][0] = __builtin_amdgcn_mfma_f32_16x16x32_bf16(af0, bg0, acc[0][0], 0, 0, 0);
            acc[0][1] = __builtin_amdgcn_mfma_f32_16x16x32_bf16(af0, bg1, acc[0][1], 0, 0, 0);
            acc[1][0] = __builtin_amdgcn_mfma_f32_16x16x32_bf16(af1, bg0, acc[1][0], 0, 0, 0);
            acc[1][1] = __builtin_amdgcn_mfma_f32_16x16x32_bf16(af1, bg1, acc[1][1], 0, 0, 0);
        }
        __syncthreads();
    }

    // ---- epilogue: C/D frag row=(l>>4)*4+reg, col=l&15 ----
#pragma unroll
    for (int fi = 0; fi < 2; ++fi)
#pragma unroll
        for (int fj = 0; fj < 2; ++fj) {
            const int ocol = bn0 + wc * 32 + fj * 16 + l15;
            if (ocol < Nc) {
#pragma unroll
                for (int p = 0; p < 4; ++p) {
                    const int orow = bm0 + wr * 32 + fi * 16 + l4 * 4 + p;
                    float v = acc[fi][fj][p];
                    if (addend) v += addend[(size_t)orow * Nc + ocol];
                    if (OUTBF16)
                        ((unsigned short*)outp)[(size_t)orow * Nc + ocol] = f2bf(v);
                    else
                        ((float*)outp)[(size_t)orow * Nc + ocol] = v;
                }
            }
        }
}

// ---------------- fp32 GEMM (w-LoRA path only) ----------------
__global__ __launch_bounds__(256) void gemm_kernel(
    const float* __restrict__ X, const float* __restrict__ mixv,
    const float* __restrict__ W, const float* __restrict__ addend,
    float* __restrict__ out,
    int M, int K, int Nc, int preop)
{
    __shared__ float As[BK][LDPAD];
    __shared__ float Bs[BK][LDPAD];

    const int tid = threadIdx.x;
    const int bm0 = blockIdx.y * BM;
    const int bn0 = blockIdx.x * BN;

    const int a_row = tid >> 2;
    const int a_col = (tid & 3) << 2;
    const int b_row = tid >> 4;
    const int b_col = (tid & 15) << 2;
    const int tr = (tid >> 4) << 2;
    const int tc = (tid & 15) << 2;

    const int row = bm0 + a_row;
    const int t_in = row & (T_SEQ - 1);

    float acc[4][4];
#pragma unroll
    for (int i = 0; i < 4; ++i)
#pragma unroll
        for (int j = 0; j < 4; ++j) acc[i][j] = 0.0f;

    for (int k0 = 0; k0 < K; k0 += BK) {
        {
            const float* xp = X + (size_t)row * K + (k0 + a_col);
            float4 xa = *(const float4*)xp;
            if (mixv) {
                float4 x_prev = make_float4(0.f, 0.f, 0.f, 0.f);
                if (t_in > 0) x_prev = *(const float4*)(xp - K);
                const float4 m4 = *(const float4*)(mixv + k0 + a_col);
                xa.x += (x_prev.x - xa.x) * m4.x;
                xa.y += (x_prev.y - xa.y) * m4.y;
                xa.z += (x_prev.z - xa.z) * m4.z;
                xa.w += (x_prev.w - xa.w) * m4.w;
            }
            if (preop) {
                xa.x = preop_apply(xa.x, preop);
                xa.y = preop_apply(xa.y, preop);
                xa.z = preop_apply(xa.z, preop);
                xa.w = preop_apply(xa.w, preop);
            }
            As[a_col + 0][a_row] = xa.x;
            As[a_col + 1][a_row] = xa.y;
            As[a_col + 2][a_row] = xa.z;
            As[a_col + 3][a_row] = xa.w;
        }
        {
            const int wr = k0 + b_row;
            const int wc = bn0 + b_col;
            float4 bv = make_float4(0.f, 0.f, 0.f, 0.f);
            const float* wp = W + (size_t)wr * Nc;
            if (wc + 3 < Nc) {
                bv = *(const float4*)(wp + wc);
            } else {
                if (wc     < Nc) bv.x = wp[wc];
                if (wc + 1 < Nc) bv.y = wp[wc + 1];
                if (wc + 2 < Nc) bv.z = wp[wc + 2];
            }
            *(float4*)&Bs[b_row][b_col] = bv;
        }
        __syncthreads();
#pragma unroll
        for (int kk = 0; kk < BK; ++kk) {
            const float4 av = *(const float4*)&As[kk][tr];
            const float4 bw = *(const float4*)&Bs[kk][tc];
            acc[0][0] += av.x * bw.x; acc[0][1] += av.x * bw.y;
            acc[0][2] += av.x * bw.z; acc[0][3] += av.x * bw.w;
            acc[1][0] += av.y * bw.x; acc[1][1] += av.y * bw.y;
            acc[1][2] += av.y * bw.z; acc[1][3] += av.y * bw.w;
            acc[2][0] += av.z * bw.x; acc[2][1] += av.z * bw.y;
            acc[2][2] += av.z * bw.z; acc[2][3] += av.z * bw.w;
            acc[3][0] += av.w * bw.x; acc[3][1] += av.w * bw.y;
            acc[3][2] += av.w * bw.z; acc[3][3] += av.w * bw.w;
        }
        __syncthreads();
    }

#pragma unroll
    for (int i = 0; i < 4; ++i) {
        const int orow = bm0 + tr + i;
#pragma unroll
        for (int j = 0; j < 4; ++j) {
            const int oc = bn0 + tc + j;
            if (oc < Nc) {
                float v = acc[i][j];
                if (addend) v += addend[(size_t)orow * Nc + oc];
                out[(size_t)orow * Nc + oc] = v;
            }
        }
    }
}

// ---------------- elementwise prep ----------------
__global__ __launch_bounds__(256) void stage3_kernel(
    const float* k_lin, const float* v_lin, const float* v_first,
    const float* w_lora, const float* a_lora, const float* v_gate,
    const float* w0, const float* a0, const float* v0,
    const float* k_k, const float* k_a,
    float* k_out, float* v_out, float* ew_out,
    float* aa_out, float* bb_out)
{
    const int gw = (blockIdx.x * blockDim.x + threadIdx.x) >> 6; // (b*T+t)*H + h
    const int lane = threadIdx.x & 63;
    const int row = gw >> 4;
    const int h = gw & 15;
    const int c = h * N_DIM + lane;
    const size_t idx = (size_t)row * C_DIM + c;

    const float kl = k_lin[idx];
    float kk = kl * k_k[c];
    float ss = wred64(kk * kk);
    const float nrm = fmaxf(sqrtf(ss), 1e-12f);
    const float kkn = kk / nrm;

    const float a = 1.0f / (1.0f + expf(-(a0[c] + a_lora[idx])));

    const float u = w0[c] + w_lora[idx];
    const float lnw = -log1pf(expf(-u)) - 0.5f;
    const float logw = -expf(lnw);
    const float ew = expf(logw);

    const float sv = 1.0f / (1.0f + expf(-(v0[c] + v_gate[idx])));
    const float vl = v_lin[idx];
    const float v = vl + (v_first[idx] - vl) * sv;

    const float ko = kl * (1.0f + (a - 1.0f) * k_a[c]);

    k_out[idx] = ko;
    v_out[idx] = v;
    ew_out[idx] = ew;
    aa_out[idx] = -kkn;
    bb_out[idx] = kkn * a;
}

// ---------------- sequential scan ----------------
__global__ __launch_bounds__(256) void scan_kernel(
    const float* __restrict__ r, const float* __restrict__ ew,
    const float* __restrict__ k, const float* __restrict__ v,
    const float* __restrict__ aa, const float* __restrict__ bb,
    float* __restrict__ o)
{
    const int gw = (blockIdx.x * blockDim.x + threadIdx.x) >> 6; // (b*H+h)*N + vi
    const int lane = threadIdx.x & 63;
    const int vi = gw & 63;
    const int bh = gw >> 6;
    const int b = bh >> 4;
    const int h = bh & 15;

    float s = 0.0f;
    const size_t base0 = ((size_t)b * T_SEQ) * C_DIM + (size_t)h * N_DIM;

    float rt = r[base0 + lane];
    float et = ew[base0 + lane];
    float kt = k[base0 + lane];
    float at = aa[base0 + lane];
    float bt = bb[base0 + lane];
    float vt = v[base0 + vi];

    float r_prev = 0.0f;

    for (int t = 0; t < T_SEQ; ++t) {
        const int tn = (t + 1 < T_SEQ) ? (t + 1) : t;
        const size_t nb = base0 + (size_t)tn * C_DIM;
        const float rn = r[nb + lane];
        const float en = ew[nb + lane];
        const float kn = k[nb + lane];
        const float an = aa[nb + lane];
        const float bn = bb[nb + lane];
        const float vn = v[nb + vi];

        float p = s * at;
        float q = s * r_prev;
#pragma unroll
        for (int m = 32; m; m >>= 1) {
            p += __shfl_xor(p, m);
            q += __shfl_xor(q, m);
        }

        if (t > 0 && lane == 0)
            o[base0 + (size_t)(t - 1) * C_DIM + vi] = q;

        s = s * et + p * bt + vt * kt;

        r_prev = rt;
        rt = rn; et = en; kt = kn; at = an; bt = bn; vt = vn;
    }

    float q = s * r_prev;
    q = wred64(q);
    if (lane == 0)
        o[base0 + (size_t)(T_SEQ - 1) * C_DIM + vi] = q;
}

// ---------------- groupnorm + bonus + gate (g is bf16) ----------------
__global__ __launch_bounds__(256) void post_kernel(
    const float* o, const float* r, const float* k, const float* v,
    const unsigned short* g,
    const float* r_k, const float* ln_w, const float* ln_b,
    float* y)
{
    const int gw = (blockIdx.x * blockDim.x + threadIdx.x) >> 6;
    const int lane = threadIdx.x & 63;
    const int row = gw >> 4;
    const int h = gw & 15;
    const int c = h * N_DIM + lane;
    const size_t idx = (size_t)row * C_DIM + c;

    const float oo = o[idx];
    float s1 = oo, s2 = oo * oo;
#pragma unroll
    for (int m = 32; m; m >>= 1) {
        s1 += __shfl_xor(s1, m);
        s2 += __shfl_xor(s2, m);
    }
    const float mu = s1 * (1.0f / 64.0f);
    const float var = s2 * (1.0f / 64.0f) - mu * mu;
    float yv = (oo - mu) * rsqrtf(var + 0.00064f);
    yv = yv * ln_w[c] + ln_b[c];

    const float t3 = wred64(r[idx] * k[idx] * r_k[c]);
    yv += t3 * v[idx];
    y[idx] = yv * bf2f(g[idx]);
}

extern "C" void kernel_launch(void* const* d_in, const int* in_sizes, int n_in,
                              void* d_out, int out_size, void* d_ws, size_t ws_size,
                              hipStream_t stream) {
    (void)in_sizes; (void)n_in; (void)out_size; (void)ws_size;

    const float* residual = (const float*)d_in[0];
    const float* x        = (const float*)d_in[1];
    const float* v_first  = (const float*)d_in[2];
    const float* mr = (const float*)d_in[6];
    const float* mw = (const float*)d_in[7];
    const float* mk = (const float*)d_in[8];
    const float* mv = (const float*)d_in[9];
    const float* ma = (const float*)d_in[10];
    const float* mg = (const float*)d_in[11];
    const float* w0 = (const float*)d_in[12];
    const float* w1 = (const float*)d_in[13];
    const float* w2 = (const float*)d_in[14];
    const float* a0 = (const float*)d_in[15];
    const float* a1 = (const float*)d_in[16];
    const float* a2 = (const float*)d_in[17];
    const float* v0 = (const float*)d_in[18];
    const float* v1 = (const float*)d_in[19];
    const float* v2 = (const float*)d_in[20];
    const float* g1 = (const float*)d_in[21];
    const float* g2 = (const float*)d_in[22];
    const float* k_k = (const float*)d_in[23];
    const float* k_a = (const float*)d_in[24];
    const float* r_k = (const float*)d_in[25];
    const float* W_r = (const float*)d_in[26];
    const float* W_k = (const float*)d_in[27];
    const float* W_v = (const float*)d_in[28];
    const float* W_o = (const float*)d_in[29];
    const float* ln_w = (const float*)d_in[30];
    const float* ln_b = (const float*)d_in[31];

    float* out = (float*)d_out;
    char* wsb = (char*)d_ws;

    // ---- workspace layout (bytes); total 68,681,728 B = 65.5 MiB ----
    // (round 2 proved [0, 69.7 MiB) writable; we stay under that)
    float* b_r  = (float*)(wsb + 0);
    float* b_k  = (float*)(wsb + 8388608);
    float* b_v  = (float*)(wsb + 16777216);
    float* b_w  = (float*)(wsb + 25165824);
    float* b_a  = (float*)(wsb + 33554432);
    float* b_vg = (float*)(wsb + 41943040);
    float* b_o  = (float*)(wsb + 50331648);
    unsigned short* b_g = (unsigned short*)(wsb + 58720256);   // bf16 [M][C]
    float* hw = (float*)(wsb + 62914560);   // [M,64] fp32
    float* ha = (float*)(wsb + 63438848);   // [M,64]
    float* hv = (float*)(wsb + 63963136);   // [M,32]
    float* hg = (float*)(wsb + 64225280);   // [M,160]
    unsigned short* wt_a1 = (unsigned short*)(wsb + 65536000); // [64][1024]
    unsigned short* wt_v1 = (unsigned short*)(wsb + 65667072); // [32][1024]
    unsigned short* wt_g1 = (unsigned short*)(wsb + 65732608); // [160][1024]
    unsigned short* wt_a2 = (unsigned short*)(wsb + 66060288); // [1024][64]
    unsigned short* wt_v2 = (unsigned short*)(wsb + 66191360); // [1024][32]
    unsigned short* wt_g2 = (unsigned short*)(wsb + 66256896); // [1024][160]
    unsigned short* wt_big = (unsigned short*)(wsb + 66584576); // [1024][1024] slot

    const dim3 blk(256);
    const dim3 tblk(32, 8);
    auto wtr = [&](const float* W, unsigned short* WT, int K, int N) {
        wtrans_kernel<<<dim3((N + 31) / 32, (K + 31) / 32), tblk, 0, stream>>>(W, WT, K, N);
    };
    auto mgemm = [&](const float* X, const float* mx, const unsigned short* WT,
                     const float* add, float* O, int K, int Nc, int preop) {
        dim3 grid((Nc + GBN - 1) / GBN, M_ROWS / GBM);
        gemm_mfma_kernel<false><<<grid, blk, 0, stream>>>(X, mx, WT, add, (void*)O, K, Nc, preop);
    };
    auto mgemm_bf = [&](const float* X, const float* mx, const unsigned short* WT,
                        unsigned short* O, int K, int Nc, int preop) {
        dim3 grid((Nc + GBN - 1) / GBN, M_ROWS / GBM);
        gemm_mfma_kernel<true><<<grid, blk, 0, stream>>>(X, mx, WT, nullptr, (void*)O, K, Nc, preop);
    };
    auto fgemm = [&](const float* X, const float* mx, const float* W,
                     const float* add, float* O, int M, int K, int Nc, int preop) {
        dim3 grid((Nc + BN - 1) / BN, M / BM);
        gemm_kernel<<<grid, blk, 0, stream>>>(X, mx, W, add, O, M, K, Nc, preop);
    };

    // Stage 0: small weights converted once
    wtr(a1, wt_a1, C_DIM, 64);
    wtr(v1, wt_v1, C_DIM, 32);
    wtr(g1, wt_g1, C_DIM, 160);
    wtr(a2, wt_a2, 64, C_DIM);
    wtr(v2, wt_v2, 32, C_DIM);
    wtr(g2, wt_g2, 160, C_DIM);

    // Stage 1: big projections, ping-ponging one weight slot (stream-ordered)
    wtr(W_r, wt_big, C_DIM, C_DIM);
    mgemm(x, mr, wt_big, nullptr, b_r, C_DIM, C_DIM, 0);
    wtr(W_k, wt_big, C_DIM, C_DIM);
    mgemm(x, mk, wt_big, nullptr, b_k, C_DIM, C_DIM, 0);
    wtr(W_v, wt_big, C_DIM, C_DIM);
    mgemm(x, mv, wt_big, nullptr, b_v, C_DIM, C_DIM, 0);
    fgemm(x, mw, w1, nullptr, hw, M_ROWS, C_DIM, 64, 0);   // fp32 (decay path)
    mgemm(x, ma, wt_a1, nullptr, ha, C_DIM, 64, 0);
    mgemm(x, mv, wt_v1, nullptr, hv, C_DIM, 32, 0);
    mgemm(x, mg, wt_g1, nullptr, hg, C_DIM, 160, 0);

    // Stage 2: LoRA second matmuls
    fgemm(hw, nullptr, w2, nullptr, b_w, M_ROWS, 64, C_DIM, 1);  // tanh, fp32
    mgemm(ha, nullptr, wt_a2, nullptr, b_a, 64, C_DIM, 0);
    mgemm(hv, nullptr, wt_v2, nullptr, b_vg, 32, C_DIM, 0);
    mgemm_bf(hg, nullptr, wt_g2, b_g, 160, C_DIM, 2);            // sigmoid preop, bf16 out

    // Stage 3: elementwise prep
    stage3_kernel<<<dim3((M_ROWS * H_DIM * 64) / 256), blk, 0, stream>>>(
        b_k, b_v, v_first, b_w, b_a, b_vg, w0, a0, v0, k_k, k_a,
        b_k, b_v, b_w, b_vg, b_a);

    // Stage 4: sequential scan
    scan_kernel<<<dim3((B_DIM * H_DIM * N_DIM * 64) / 256), blk, 0, stream>>>(
        b_r, b_w, b_k, b_v, b_vg, b_a, b_o);

    // Stage 5: groupnorm + bonus + gate
    post_kernel<<<dim3((M_ROWS * H_DIM * 64) / 256), blk, 0, stream>>>(
        b_o, b_r, b_k, b_v, b_g, r_k, ln_w, ln_b, b_o);

    // Stage 6: output projection + residual
    wtr(W_o, wt_big, C_DIM, C_DIM);
    mgemm(b_o, nullptr, wt_big, residual, out, C_DIM, C_DIM, 0);
}

// Round 5
// 693.802 us; speedup vs baseline: 1.9286x; 1.1935x over previous
//
#include <hip/hip_runtime.h>
#include <math.h>

// Problem constants
#define B_DIM 2
#define T_SEQ 1024
#define C_DIM 1024
#define H_DIM 16
#define N_DIM 64
#define M_ROWS (B_DIM * T_SEQ)   // 2048

// fp32 GEMM tiling (kept for the sensitive w-LoRA path)
#define BM 64
#define BN 64
#define BK 16
#define LDPAD 72

// MFMA GEMM tiling
#define GBM 64
#define GBN 64
#define GBK 64
#define LDK 88

typedef __attribute__((ext_vector_type(8))) short bf16x8;
typedef __attribute__((ext_vector_type(4))) float f32x4;
typedef unsigned short ushortx4 __attribute__((ext_vector_type(4)));
typedef unsigned short ushortx8 __attribute__((ext_vector_type(8)));

__device__ __forceinline__ unsigned short f2bf(float f) {
    unsigned int u = __float_as_uint(f);
    u = (u + 0x7FFFu + ((u >> 16) & 1u)) >> 16;   // RNE
    return (unsigned short)u;
}
__device__ __forceinline__ float bf2f(unsigned short h) {
    return __uint_as_float(((unsigned int)h) << 16);
}

__device__ __forceinline__ float preop_apply(float v, int preop) {
    if (preop == 1) return tanhf(v);
    if (preop == 2) return 1.0f / (1.0f + expf(-v));
    return v;
}

__device__ __forceinline__ float wred64(float v) {
#pragma unroll
    for (int m = 32; m; m >>= 1) v += __shfl_xor(v, m);
    return v;
}

// DPP wave-64 sum network: after the 6 adds the FULL sum is in lane 63.
// old=0 so masked/invalid lanes contribute +0.
#define DPPADD(v, ctrl)                                                        \
    v += __int_as_float(__builtin_amdgcn_update_dpp(                           \
        0, __float_as_int(v), (ctrl), 0xF, 0xF, false))

// ---------------- weight transpose + fp32->bf16 convert ----------------
__global__ __launch_bounds__(256) void wtrans_kernel(
    const float* __restrict__ W, unsigned short* __restrict__ WT, int K, int N)
{
    __shared__ float tile[32][33];
    const int tx = threadIdx.x, ty = threadIdx.y;
    const int n0 = blockIdx.x * 32, k0 = blockIdx.y * 32;
#pragma unroll
    for (int i = 0; i < 4; ++i) {
        int k = k0 + ty + i * 8, n = n0 + tx;
        if (k < K && n < N) tile[ty + i * 8][tx] = W[(size_t)k * N + n];
    }
    __syncthreads();
#pragma unroll
    for (int i = 0; i < 4; ++i) {
        int n = n0 + ty + i * 8, k = k0 + tx;
        if (n < N && k < K) WT[(size_t)n * K + k] = f2bf(tile[tx][ty + i * 8]);
    }
}

// ---------------- bf16 MFMA GEMM ----------------
// out[(row*Nc+col)*ostride] = preop(mix(X)) @ WT^T (+addend)
template <bool OUTBF16>
__global__ __launch_bounds__(256) void gemm_mfma_kernel(
    const float* __restrict__ X, const float* __restrict__ mixv,
    const unsigned short* __restrict__ WT, const float* __restrict__ addend,
    void* __restrict__ outp, int K, int Nc, int preop, int ostride)
{
    __shared__ unsigned short As[GBM][LDK];
    __shared__ unsigned short Bs[GBN][LDK];

    const int tid = threadIdx.x;
    const int lane = tid & 63;
    const int wid = tid >> 6;
    const int wr = wid >> 1, wc = wid & 1;
    const int l15 = lane & 15, l4 = lane >> 4;

    const int bm0 = blockIdx.y * GBM;
    const int bn0 = blockIdx.x * GBN;

    const int ar = tid >> 2;
    const int as = (tid & 3) << 4;
    const int row = bm0 + ar;
    const int t_in = row & (T_SEQ - 1);

    const int brn = tid >> 2;
    const int bks = (tid & 3) << 4;
    const bool bn_ok = (bn0 + brn) < Nc;

    f32x4 acc[2][2] = {};

    for (int k0 = 0; k0 < K; k0 += GBK) {
#pragma unroll
        for (int i = 0; i < 4; ++i) {
            const int kg = k0 + as + 4 * i;
            float4 xa = make_float4(0.f, 0.f, 0.f, 0.f);
            if (kg < K) {
                const float* xp = X + (size_t)row * K + kg;
                xa = *(const float4*)xp;
                if (mixv) {
                    float4 xp4 = make_float4(0.f, 0.f, 0.f, 0.f);
                    if (t_in > 0) xp4 = *(const float4*)(xp - K);
                    const float4 m4 = *(const float4*)(mixv + kg);
                    xa.x += (xp4.x - xa.x) * m4.x;
                    xa.y += (xp4.y - xa.y) * m4.y;
                    xa.z += (xp4.z - xa.z) * m4.z;
                    xa.w += (xp4.w - xa.w) * m4.w;
                }
                if (preop) {
                    xa.x = preop_apply(xa.x, preop);
                    xa.y = preop_apply(xa.y, preop);
                    xa.z = preop_apply(xa.z, preop);
                    xa.w = preop_apply(xa.w, preop);
                }
            }
            ushortx4 pk;
            pk.x = f2bf(xa.x); pk.y = f2bf(xa.y); pk.z = f2bf(xa.z); pk.w = f2bf(xa.w);
            *(ushortx4*)&As[ar][as + 4 * i] = pk;
        }
#pragma unroll
        for (int i = 0; i < 2; ++i) {
            const int kk = bks + 8 * i;
            const int kg = k0 + kk;
            ushortx8 bv = {0, 0, 0, 0, 0, 0, 0, 0};
            if (bn_ok && kg < K)
                bv = *(const ushortx8*)(WT + (size_t)(bn0 + brn) * K + kg);
            *(ushortx8*)&Bs[brn][kk] = bv;
        }
        __syncthreads();

#pragma unroll
        for (int ks = 0; ks < 2; ++ks) {
            bf16x8 af0 = *(const bf16x8*)&As[wr * 32 +      l15][ks * 32 + l4 * 8];
            bf16x8 af1 = *(const bf16x8*)&As[wr * 32 + 16 + l15][ks * 32 + l4 * 8];
            bf16x8 bg0 = *(const bf16x8*)&Bs[wc * 32 +      l15][ks * 32 + l4 * 8];
            bf16x8 bg1 = *(const bf16x8*)&Bs[wc * 32 + 16 + l15][ks * 32 + l4 * 8];
            acc[0][0] = __builtin_amdgcn_mfma_f32_16x16x32_bf16(af0, bg0, acc[0][0], 0, 0, 0);
            acc[0][1] = __builtin_amdgcn_mfma_f32_16x16x32_bf16(af0, bg1, acc[0][1], 0, 0, 0);
            acc[1][0] = __builtin_amdgcn_mfma_f32_16x16x32_bf16(af1, bg0, acc[1][0], 0, 0, 0);
            acc[1][1] = __builtin_amdgcn_mfma_f32_16x16x32_bf16(af1, bg1, acc[1][1], 0, 0, 0);
        }
        __syncthreads();
    }

#pragma unroll
    for (int fi = 0; fi < 2; ++fi)
#pragma unroll
        for (int fj = 0; fj < 2; ++fj) {
            const int ocol = bn0 + wc * 32 + fj * 16 + l15;
            if (ocol < Nc) {
#pragma unroll
                for (int p = 0; p < 4; ++p) {
                    const int orow = bm0 + wr * 32 + fi * 16 + l4 * 4 + p;
                    float v = acc[fi][fj][p];
                    if (addend) v += addend[(size_t)orow * Nc + ocol];
                    if (OUTBF16)
                        ((unsigned short*)outp)[(size_t)orow * Nc + ocol] = f2bf(v);
                    else
                        ((float*)outp)[((size_t)orow * Nc + ocol) * ostride] = v;
                }
            }
        }
}

// ---------------- fp32 GEMM (w-LoRA path only) ----------------
__global__ __launch_bounds__(256) void gemm_kernel(
    const float* __restrict__ X, const float* __restrict__ mixv,
    const float* __restrict__ W, float* __restrict__ out,
    int M, int K, int Nc, int preop, int ostride)
{
    __shared__ float As[BK][LDPAD];
    __shared__ float Bs[BK][LDPAD];

    const int tid = threadIdx.x;
    const int bm0 = blockIdx.y * BM;
    const int bn0 = blockIdx.x * BN;

    const int a_row = tid >> 2;
    const int a_col = (tid & 3) << 2;
    const int b_row = tid >> 4;
    const int b_col = (tid & 15) << 2;
    const int tr = (tid >> 4) << 2;
    const int tc = (tid & 15) << 2;

    const int row = bm0 + a_row;
    const int t_in = row & (T_SEQ - 1);

    float acc[4][4];
#pragma unroll
    for (int i = 0; i < 4; ++i)
#pragma unroll
        for (int j = 0; j < 4; ++j) acc[i][j] = 0.0f;

    for (int k0 = 0; k0 < K; k0 += BK) {
        {
            const float* xp = X + (size_t)row * K + (k0 + a_col);
            float4 xa = *(const float4*)xp;
            if (mixv) {
                float4 x_prev = make_float4(0.f, 0.f, 0.f, 0.f);
                if (t_in > 0) x_prev = *(const float4*)(xp - K);
                const float4 m4 = *(const float4*)(mixv + k0 + a_col);
                xa.x += (x_prev.x - xa.x) * m4.x;
                xa.y += (x_prev.y - xa.y) * m4.y;
                xa.z += (x_prev.z - xa.z) * m4.z;
                xa.w += (x_prev.w - xa.w) * m4.w;
            }
            if (preop) {
                xa.x = preop_apply(xa.x, preop);
                xa.y = preop_apply(xa.y, preop);
                xa.z = preop_apply(xa.z, preop);
                xa.w = preop_apply(xa.w, preop);
            }
            As[a_col + 0][a_row] = xa.x;
            As[a_col + 1][a_row] = xa.y;
            As[a_col + 2][a_row] = xa.z;
            As[a_col + 3][a_row] = xa.w;
        }
        {
            const int wr = k0 + b_row;
            const int wc = bn0 + b_col;
            float4 bv = make_float4(0.f, 0.f, 0.f, 0.f);
            const float* wp = W + (size_t)wr * Nc;
            if (wc + 3 < Nc) {
                bv = *(const float4*)(wp + wc);
            } else {
                if (wc     < Nc) bv.x = wp[wc];
                if (wc + 1 < Nc) bv.y = wp[wc + 1];
                if (wc + 2 < Nc) bv.z = wp[wc + 2];
            }
            *(float4*)&Bs[b_row][b_col] = bv;
        }
        __syncthreads();
#pragma unroll
        for (int kk = 0; kk < BK; ++kk) {
            const float4 av = *(const float4*)&As[kk][tr];
            const float4 bw = *(const float4*)&Bs[kk][tc];
            acc[0][0] += av.x * bw.x; acc[0][1] += av.x * bw.y;
            acc[0][2] += av.x * bw.z; acc[0][3] += av.x * bw.w;
            acc[1][0] += av.y * bw.x; acc[1][1] += av.y * bw.y;
            acc[1][2] += av.y * bw.z; acc[1][3] += av.y * bw.w;
            acc[2][0] += av.z * bw.x; acc[2][1] += av.z * bw.y;
            acc[2][2] += av.z * bw.z; acc[2][3] += av.z * bw.w;
            acc[3][0] += av.w * bw.x; acc[3][1] += av.w * bw.y;
            acc[3][2] += av.w * bw.z; acc[3][3] += av.w * bw.w;
        }
        __syncthreads();
    }

#pragma unroll
    for (int i = 0; i < 4; ++i) {
        const int orow = bm0 + tr + i;
#pragma unroll
        for (int j = 0; j < 4; ++j) {
            const int oc = bn0 + tc + j;
            if (oc < Nc)
                out[((size_t)orow * Nc + oc) * ostride] = acc[i][j];
        }
    }
}

// ---------------- elementwise prep ----------------
// pk4[idx] holds raw (w_lora, k_lin, a_lora, v_gate); rewritten in place to
// (e^w, k, aa, bb).  b_v holds v_lin, rewritten to v.
__global__ __launch_bounds__(256) void stage3_kernel(
    float4* pk4, float* v_io, const float* v_first,
    const float* w0, const float* a0, const float* v0,
    const float* k_k, const float* k_a)
{
    const int gw = (blockIdx.x * blockDim.x + threadIdx.x) >> 6; // (b*T+t)*H + h
    const int lane = threadIdx.x & 63;
    const int row = gw >> 4;
    const int h = gw & 15;
    const int c = h * N_DIM + lane;
    const size_t idx = (size_t)row * C_DIM + c;

    const float4 raw = pk4[idx];
    const float w_lora = raw.x, kl = raw.y, a_lora = raw.z, v_gate = raw.w;

    float kk = kl * k_k[c];
    float ss = wred64(kk * kk);
    const float nrm = fmaxf(sqrtf(ss), 1e-12f);
    const float kkn = kk / nrm;

    const float a = 1.0f / (1.0f + expf(-(a0[c] + a_lora)));

    const float u = w0[c] + w_lora;
    const float lnw = -log1pf(expf(-u)) - 0.5f;
    const float ew = expf(-expf(lnw));

    const float sv = 1.0f / (1.0f + expf(-(v0[c] + v_gate)));
    const float vl = v_io[idx];
    const float v = vl + (v_first[idx] - vl) * sv;

    const float ko = kl * (1.0f + (a - 1.0f) * k_a[c]);

    pk4[idx] = make_float4(ew, ko, -kkn, kkn * a);
    v_io[idx] = v;
}

// ---------------- sequential scan (DPP reduce) ----------------
// wave per (b,h,v); lane = k. Per step: two interleaved 6-op DPP sum
// networks (sum lands in lane 63); p broadcast via readlane; loads packed
// (float4 + r + v), prefetch distance 2.
#define SCAN_STEP(pk, rt, vt, tcur)                                            \
    do {                                                                       \
        float p_ = s * (pk).z;                                                 \
        float q_ = s * r_prev;                                                 \
        DPPADD(p_, 0x111); DPPADD(q_, 0x111);                                  \
        DPPADD(p_, 0x112); DPPADD(q_, 0x112);                                  \
        DPPADD(p_, 0x114); DPPADD(q_, 0x114);                                  \
        DPPADD(p_, 0x118); DPPADD(q_, 0x118);                                  \
        DPPADD(p_, 0x142); DPPADD(q_, 0x142);                                  \
        DPPADD(p_, 0x143); DPPADD(q_, 0x143);                                  \
        if ((tcur) > 0 && lane == 63)                                          \
            o[vbase + (size_t)((tcur) - 1) * C_DIM] = q_;                      \
        const float ps_ = __int_as_float(                                      \
            __builtin_amdgcn_readlane(__float_as_int(p_), 63));                \
        s = s * (pk).x + ps_ * (pk).w + vt * (pk).y;                           \
        r_prev = rt;                                                           \
    } while (0)

__global__ __launch_bounds__(256) void scan_kernel(
    const float4* __restrict__ pk4, const float* __restrict__ r,
    const float* __restrict__ v, float* __restrict__ o)
{
    const int gw = (blockIdx.x * blockDim.x + threadIdx.x) >> 6; // (b*H+h)*N + vi
    const int lane = threadIdx.x & 63;
    const int vi = gw & 63;
    const int bh = gw >> 6;
    const int b = bh >> 4;
    const int h = bh & 15;

    const size_t base0 = ((size_t)b * T_SEQ) * C_DIM + (size_t)h * N_DIM;
    const size_t lbase = base0 + lane;
    const size_t vbase = base0 + vi;

    float s = 0.0f, r_prev = 0.0f;

    float4 pA = pk4[lbase];
    float  rA = r[lbase];
    float  vA = v[vbase];
    float4 pB = pk4[lbase + C_DIM];
    float  rB = r[lbase + C_DIM];
    float  vB = v[vbase + C_DIM];

    for (int t = 0; t < T_SEQ; t += 2) {
        const int t2 = (t + 2 < T_SEQ) ? t + 2 : T_SEQ - 1;
        const int t3 = (t + 3 < T_SEQ) ? t + 3 : T_SEQ - 1;

        float4 pC = pk4[lbase + (size_t)t2 * C_DIM];
        float  rC = r[lbase + (size_t)t2 * C_DIM];
        float  vC = v[vbase + (size_t)t2 * C_DIM];

        SCAN_STEP(pA, rA, vA, t);

        float4 pD = pk4[lbase + (size_t)t3 * C_DIM];
        float  rD = r[lbase + (size_t)t3 * C_DIM];
        float  vD = v[vbase + (size_t)t3 * C_DIM];

        SCAN_STEP(pB, rB, vB, t + 1);

        pA = pC; rA = rC; vA = vC;
        pB = pD; rB = rD; vB = vD;
    }

    // final pending output: o_{T-1} = sum_k s * r_{T-1}
    float q = s * r_prev;
    DPPADD(q, 0x111); DPPADD(q, 0x112); DPPADD(q, 0x114);
    DPPADD(q, 0x118); DPPADD(q, 0x142); DPPADD(q, 0x143);
    if (lane == 63)
        o[vbase + (size_t)(T_SEQ - 1) * C_DIM] = q;
}

// ---------------- groupnorm + bonus + gate ----------------
__global__ __launch_bounds__(256) void post_kernel(
    const float* o, const float* r, const float4* pk4, const float* v,
    const unsigned short* g,
    const float* r_k, const float* ln_w, const float* ln_b,
    float* y)
{
    const int gw = (blockIdx.x * blockDim.x + threadIdx.x) >> 6;
    const int lane = threadIdx.x & 63;
    const int row = gw >> 4;
    const int h = gw & 15;
    const int c = h * N_DIM + lane;
    const size_t idx = (size_t)row * C_DIM + c;

    const float oo = o[idx];
    float s1 = oo, s2 = oo * oo;
#pragma unroll
    for (int m = 32; m; m >>= 1) {
        s1 += __shfl_xor(s1, m);
        s2 += __shfl_xor(s2, m);
    }
    const float mu = s1 * (1.0f / 64.0f);
    const float var = s2 * (1.0f / 64.0f) - mu * mu;
    float yv = (oo - mu) * rsqrtf(var + 0.00064f);
    yv = yv * ln_w[c] + ln_b[c];

    const float kt = pk4[idx].y;
    const float t3 = wred64(r[idx] * kt * r_k[c]);
    yv += t3 * v[idx];
    y[idx] = yv * bf2f(g[idx]);
}

extern "C" void kernel_launch(void* const* d_in, const int* in_sizes, int n_in,
                              void* d_out, int out_size, void* d_ws, size_t ws_size,
                              hipStream_t stream) {
    (void)in_sizes; (void)n_in; (void)out_size; (void)ws_size;

    const float* residual = (const float*)d_in[0];
    const float* x        = (const float*)d_in[1];
    const float* v_first  = (const float*)d_in[2];
    const float* mr = (const float*)d_in[6];
    const float* mw = (const float*)d_in[7];
    const float* mk = (const float*)d_in[8];
    const float* mv = (const float*)d_in[9];
    const float* ma = (const float*)d_in[10];
    const float* mg = (const float*)d_in[11];
    const float* w0 = (const float*)d_in[12];
    const float* w1 = (const float*)d_in[13];
    const float* w2 = (const float*)d_in[14];
    const float* a0 = (const float*)d_in[15];
    const float* a1 = (const float*)d_in[16];
    const float* a2 = (const float*)d_in[17];
    const float* v0 = (const float*)d_in[18];
    const float* v1 = (const float*)d_in[19];
    const float* v2 = (const float*)d_in[20];
    const float* g1 = (const float*)d_in[21];
    const float* g2 = (const float*)d_in[22];
    const float* k_k = (const float*)d_in[23];
    const float* k_a = (const float*)d_in[24];
    const float* r_k = (const float*)d_in[25];
    const float* W_r = (const float*)d_in[26];
    const float* W_k = (const float*)d_in[27];
    const float* W_v = (const float*)d_in[28];
    const float* W_o = (const float*)d_in[29];
    const float* ln_w = (const float*)d_in[30];
    const float* ln_b = (const float*)d_in[31];

    float* out = (float*)d_out;
    char* wsb = (char*)d_ws;

    // ---- workspace layout (bytes); total 68,681,728 B = 65.5 MiB (proven safe) ----
    float4* pk4 = (float4*)(wsb + 0);                          // [M][C] float4 (32 MiB)
    float* b_r  = (float*)(wsb + 33554432);
    float* b_v  = (float*)(wsb + 41943040);
    float* b_o  = (float*)(wsb + 50331648);
    unsigned short* b_g = (unsigned short*)(wsb + 58720256);   // bf16 [M][C]
    float* hw = (float*)(wsb + 62914560);   // [M,64] fp32
    float* ha = (float*)(wsb + 63438848);   // [M,64]
    float* hv = (float*)(wsb + 63963136);   // [M,32]
    float* hg = (float*)(wsb + 64225280);   // [M,160]
    unsigned short* wt_a1 = (unsigned short*)(wsb + 65536000); // [64][1024]
    unsigned short* wt_v1 = (unsigned short*)(wsb + 65667072); // [32][1024]
    unsigned short* wt_g1 = (unsigned short*)(wsb + 65732608); // [160][1024]
    unsigned short* wt_a2 = (unsigned short*)(wsb + 66060288); // [1024][64]
    unsigned short* wt_v2 = (unsigned short*)(wsb + 66191360); // [1024][32]
    unsigned short* wt_g2 = (unsigned short*)(wsb + 66256896); // [1024][160]
    unsigned short* wt_big = (unsigned short*)(wsb + 66584576); // [1024][1024] slot

    const dim3 blk(256);
    const dim3 tblk(32, 8);
    auto wtr = [&](const float* W, unsigned short* WT, int K, int N) {
        wtrans_kernel<<<dim3((N + 31) / 32, (K + 31) / 32), tblk, 0, stream>>>(W, WT, K, N);
    };
    auto mgemm = [&](const float* X, const float* mx, const unsigned short* WT,
                     const float* add, float* O, int K, int Nc, int preop, int ostride) {
        dim3 grid((Nc + GBN - 1) / GBN, M_ROWS / GBM);
        gemm_mfma_kernel<false><<<grid, blk, 0, stream>>>(X, mx, WT, add, (void*)O, K, Nc, preop, ostride);
    };
    auto mgemm_bf = [&](const float* X, const float* mx, const unsigned short* WT,
                        unsigned short* O, int K, int Nc, int preop) {
        dim3 grid((Nc + GBN - 1) / GBN, M_ROWS / GBM);
        gemm_mfma_kernel<true><<<grid, blk, 0, stream>>>(X, mx, WT, nullptr, (void*)O, K, Nc, preop, 1);
    };
    auto fgemm = [&](const float* X, const float* mx, const float* W,
                     float* O, int M, int K, int Nc, int preop, int ostride) {
        dim3 grid((Nc + BN - 1) / BN, M / BM);
        gemm_kernel<<<grid, blk, 0, stream>>>(X, mx, W, O, M, K, Nc, preop, ostride);
    };

    float* pk_f = (float*)pk4;

    // Stage 0: small weights converted once
    wtr(a1, wt_a1, C_DIM, 64);
    wtr(v1, wt_v1, C_DIM, 32);
    wtr(g1, wt_g1, C_DIM, 160);
    wtr(a2, wt_a2, 64, C_DIM);
    wtr(v2, wt_v2, 32, C_DIM);
    wtr(g2, wt_g2, 160, C_DIM);

    // Stage 1: projections (big weights ping-pong through wt_big)
    wtr(W_r, wt_big, C_DIM, C_DIM);
    mgemm(x, mr, wt_big, nullptr, b_r, C_DIM, C_DIM, 0, 1);
    wtr(W_k, wt_big, C_DIM, C_DIM);
    mgemm(x, mk, wt_big, nullptr, pk_f + 1, C_DIM, C_DIM, 0, 4);   // k_lin -> pk4.y
    wtr(W_v, wt_big, C_DIM, C_DIM);
    mgemm(x, mv, wt_big, nullptr, b_v, C_DIM, C_DIM, 0, 1);        // v_lin
    fgemm(x, mw, w1, hw, M_ROWS, C_DIM, 64, 0, 1);                 // fp32 decay path
    mgemm(x, ma, wt_a1, nullptr, ha, C_DIM, 64, 0, 1);
    mgemm(x, mv, wt_v1, nullptr, hv, C_DIM, 32, 0, 1);
    mgemm(x, mg, wt_g1, nullptr, hg, C_DIM, 160, 0, 1);

    // Stage 2: LoRA second matmuls
    fgemm(hw, nullptr, w2, pk_f + 0, M_ROWS, 64, C_DIM, 1, 4);     // tanh -> pk4.x
    mgemm(ha, nullptr, wt_a2, nullptr, pk_f + 2, 64, C_DIM, 0, 4); // a_lora -> pk4.z
    mgemm(hv, nullptr, wt_v2, nullptr, pk_f + 3, 32, C_DIM, 0, 4); // v_gate -> pk4.w
    mgemm_bf(hg, nullptr, wt_g2, b_g, 160, C_DIM, 2);              // sigmoid, bf16 out

    // Stage 3: elementwise prep (pk4 & b_v transformed in place)
    stage3_kernel<<<dim3((M_ROWS * H_DIM * 64) / 256), blk, 0, stream>>>(
        pk4, b_v, v_first, w0, a0, v0, k_k, k_a);

    // Stage 4: sequential scan
    scan_kernel<<<dim3((B_DIM * H_DIM * N_DIM * 64) / 256), blk, 0, stream>>>(
        pk4, b_r, b_v, b_o);

    // Stage 5: groupnorm + bonus + gate
    post_kernel<<<dim3((M_ROWS * H_DIM * 64) / 256), blk, 0, stream>>>(
        b_o, b_r, pk4, b_v, b_g, r_k, ln_w, ln_b, b_o);

    // Stage 6: output projection + residual
    wtr(W_o, wt_big, C_DIM, C_DIM);
    mgemm(b_o, nullptr, wt_big, residual, out, C_DIM, C_DIM, 0, 1);
}

// Round 6
// 591.015 us; speedup vs baseline: 2.2640x; 1.1739x over previous
//
#include <hip/hip_runtime.h>
#include <math.h>

// Problem constants
#define B_DIM 2
#define T_SEQ 1024
#define C_DIM 1024
#define H_DIM 16
#define N_DIM 64
#define M_ROWS (B_DIM * T_SEQ)   // 2048
#define NBLK 512                 // T/2 two-step blocks

// fp32 GEMM tiling (kept for the sensitive w-LoRA path)
#define BM 64
#define BN 64
#define BK 16
#define LDPAD 72

// MFMA GEMM tiling
#define GBM 64
#define GBN 64
#define GBK 64
#define LDK 88

typedef __attribute__((ext_vector_type(8))) short bf16x8;
typedef __attribute__((ext_vector_type(4))) float f32x4;
typedef unsigned short ushortx4 __attribute__((ext_vector_type(4)));
typedef unsigned short ushortx8 __attribute__((ext_vector_type(8)));

__device__ __forceinline__ unsigned short f2bf(float f) {
    unsigned int u = __float_as_uint(f);
    u = (u + 0x7FFFu + ((u >> 16) & 1u)) >> 16;   // RNE
    return (unsigned short)u;
}
__device__ __forceinline__ float bf2f(unsigned short h) {
    return __uint_as_float(((unsigned int)h) << 16);
}

__device__ __forceinline__ float preop_apply(float v, int preop) {
    if (preop == 1) return tanhf(v);
    if (preop == 2) return 1.0f / (1.0f + expf(-v));
    return v;
}

__device__ __forceinline__ float wred64(float v) {
#pragma unroll
    for (int m = 32; m; m >>= 1) v += __shfl_xor(v, m);
    return v;
}

// DPP wave-64 sum network: after 6 adds the FULL sum is in lane 63. old=0.
#define DPPADD(v, ctrl)                                                        \
    v += __int_as_float(__builtin_amdgcn_update_dpp(                           \
        0, __float_as_int(v), (ctrl), 0xF, 0xF, false))

// 4-way interleaved full network
#define DPP6X4(a, b, c, d)                                                     \
    do {                                                                       \
        DPPADD(a, 0x111); DPPADD(b, 0x111); DPPADD(c, 0x111); DPPADD(d, 0x111);\
        DPPADD(a, 0x112); DPPADD(b, 0x112); DPPADD(c, 0x112); DPPADD(d, 0x112);\
        DPPADD(a, 0x114); DPPADD(b, 0x114); DPPADD(c, 0x114); DPPADD(d, 0x114);\
        DPPADD(a, 0x118); DPPADD(b, 0x118); DPPADD(c, 0x118); DPPADD(d, 0x118);\
        DPPADD(a, 0x142); DPPADD(b, 0x142); DPPADD(c, 0x142); DPPADD(d, 0x142);\
        DPPADD(a, 0x143); DPPADD(b, 0x143); DPPADD(c, 0x143); DPPADD(d, 0x143);\
    } while (0)

__device__ __forceinline__ float rdl63(float v) {
    return __int_as_float(__builtin_amdgcn_readlane(__float_as_int(v), 63));
}

// ---------------- weight transpose + fp32->bf16 convert ----------------
__global__ __launch_bounds__(256) void wtrans_kernel(
    const float* __restrict__ W, unsigned short* __restrict__ WT, int K, int N)
{
    __shared__ float tile[32][33];
    const int tx = threadIdx.x, ty = threadIdx.y;
    const int n0 = blockIdx.x * 32, k0 = blockIdx.y * 32;
#pragma unroll
    for (int i = 0; i < 4; ++i) {
        int k = k0 + ty + i * 8, n = n0 + tx;
        if (k < K && n < N) tile[ty + i * 8][tx] = W[(size_t)k * N + n];
    }
    __syncthreads();
#pragma unroll
    for (int i = 0; i < 4; ++i) {
        int n = n0 + ty + i * 8, k = k0 + tx;
        if (n < N && k < K) WT[(size_t)n * K + k] = f2bf(tile[tx][ty + i * 8]);
    }
}

// ---------------- bf16 MFMA GEMM ----------------
template <bool OUTBF16>
__global__ __launch_bounds__(256) void gemm_mfma_kernel(
    const float* __restrict__ X, const float* __restrict__ mixv,
    const unsigned short* __restrict__ WT, const float* __restrict__ addend,
    void* __restrict__ outp, int K, int Nc, int preop, int ostride)
{
    __shared__ unsigned short As[GBM][LDK];
    __shared__ unsigned short Bs[GBN][LDK];

    const int tid = threadIdx.x;
    const int lane = tid & 63;
    const int wid = tid >> 6;
    const int wr = wid >> 1, wc = wid & 1;
    const int l15 = lane & 15, l4 = lane >> 4;

    const int bm0 = blockIdx.y * GBM;
    const int bn0 = blockIdx.x * GBN;

    const int ar = tid >> 2;
    const int as = (tid & 3) << 4;
    const int row = bm0 + ar;
    const int t_in = row & (T_SEQ - 1);

    const int brn = tid >> 2;
    const int bks = (tid & 3) << 4;
    const bool bn_ok = (bn0 + brn) < Nc;

    f32x4 acc[2][2] = {};

    for (int k0 = 0; k0 < K; k0 += GBK) {
#pragma unroll
        for (int i = 0; i < 4; ++i) {
            const int kg = k0 + as + 4 * i;
            float4 xa = make_float4(0.f, 0.f, 0.f, 0.f);
            if (kg < K) {
                const float* xp = X + (size_t)row * K + kg;
                xa = *(const float4*)xp;
                if (mixv) {
                    float4 xp4 = make_float4(0.f, 0.f, 0.f, 0.f);
                    if (t_in > 0) xp4 = *(const float4*)(xp - K);
                    const float4 m4 = *(const float4*)(mixv + kg);
                    xa.x += (xp4.x - xa.x) * m4.x;
                    xa.y += (xp4.y - xa.y) * m4.y;
                    xa.z += (xp4.z - xa.z) * m4.z;
                    xa.w += (xp4.w - xa.w) * m4.w;
                }
                if (preop) {
                    xa.x = preop_apply(xa.x, preop);
                    xa.y = preop_apply(xa.y, preop);
                    xa.z = preop_apply(xa.z, preop);
                    xa.w = preop_apply(xa.w, preop);
                }
            }
            ushortx4 pk;
            pk.x = f2bf(xa.x); pk.y = f2bf(xa.y); pk.z = f2bf(xa.z); pk.w = f2bf(xa.w);
            *(ushortx4*)&As[ar][as + 4 * i] = pk;
        }
#pragma unroll
        for (int i = 0; i < 2; ++i) {
            const int kk = bks + 8 * i;
            const int kg = k0 + kk;
            ushortx8 bv = {0, 0, 0, 0, 0, 0, 0, 0};
            if (bn_ok && kg < K)
                bv = *(const ushortx8*)(WT + (size_t)(bn0 + brn) * K + kg);
            *(ushortx8*)&Bs[brn][kk] = bv;
        }
        __syncthreads();

#pragma unroll
        for (int ks = 0; ks < 2; ++ks) {
            bf16x8 af0 = *(const bf16x8*)&As[wr * 32 +      l15][ks * 32 + l4 * 8];
            bf16x8 af1 = *(const bf16x8*)&As[wr * 32 + 16 + l15][ks * 32 + l4 * 8];
            bf16x8 bg0 = *(const bf16x8*)&Bs[wc * 32 +      l15][ks * 32 + l4 * 8];
            bf16x8 bg1 = *(const bf16x8*)&Bs[wc * 32 + 16 + l15][ks * 32 + l4 * 8];
            acc[0][0] = __builtin_amdgcn_mfma_f32_16x16x32_bf16(af0, bg0, acc[0][0], 0, 0, 0);
            acc[0][1] = __builtin_amdgcn_mfma_f32_16x16x32_bf16(af0, bg1, acc[0][1], 0, 0, 0);
            acc[1][0] = __builtin_amdgcn_mfma_f32_16x16x32_bf16(af1, bg0, acc[1][0], 0, 0, 0);
            acc[1][1] = __builtin_amdgcn_mfma_f32_16x16x32_bf16(af1, bg1, acc[1][1], 0, 0, 0);
        }
        __syncthreads();
    }

#pragma unroll
    for (int fi = 0; fi < 2; ++fi)
#pragma unroll
        for (int fj = 0; fj < 2; ++fj) {
            const int ocol = bn0 + wc * 32 + fj * 16 + l15;
            if (ocol < Nc) {
#pragma unroll
                for (int p = 0; p < 4; ++p) {
                    const int orow = bm0 + wr * 32 + fi * 16 + l4 * 4 + p;
                    float v = acc[fi][fj][p];
                    if (addend) v += addend[(size_t)orow * Nc + ocol];
                    if (OUTBF16)
                        ((unsigned short*)outp)[(size_t)orow * Nc + ocol] = f2bf(v);
                    else
                        ((float*)outp)[((size_t)orow * Nc + ocol) * ostride] = v;
                }
            }
        }
}

// ---------------- fp32 GEMM (w-LoRA path only) ----------------
__global__ __launch_bounds__(256) void gemm_kernel(
    const float* __restrict__ X, const float* __restrict__ mixv,
    const float* __restrict__ W, float* __restrict__ out,
    int M, int K, int Nc, int preop, int ostride)
{
    __shared__ float As[BK][LDPAD];
    __shared__ float Bs[BK][LDPAD];

    const int tid = threadIdx.x;
    const int bm0 = blockIdx.y * BM;
    const int bn0 = blockIdx.x * BN;

    const int a_row = tid >> 2;
    const int a_col = (tid & 3) << 2;
    const int b_row = tid >> 4;
    const int b_col = (tid & 15) << 2;
    const int tr = (tid >> 4) << 2;
    const int tc = (tid & 15) << 2;

    const int row = bm0 + a_row;
    const int t_in = row & (T_SEQ - 1);

    float acc[4][4];
#pragma unroll
    for (int i = 0; i < 4; ++i)
#pragma unroll
        for (int j = 0; j < 4; ++j) acc[i][j] = 0.0f;

    for (int k0 = 0; k0 < K; k0 += BK) {
        {
            const float* xp = X + (size_t)row * K + (k0 + a_col);
            float4 xa = *(const float4*)xp;
            if (mixv) {
                float4 x_prev = make_float4(0.f, 0.f, 0.f, 0.f);
                if (t_in > 0) x_prev = *(const float4*)(xp - K);
                const float4 m4 = *(const float4*)(mixv + k0 + a_col);
                xa.x += (x_prev.x - xa.x) * m4.x;
                xa.y += (x_prev.y - xa.y) * m4.y;
                xa.z += (x_prev.z - xa.z) * m4.z;
                xa.w += (x_prev.w - xa.w) * m4.w;
            }
            if (preop) {
                xa.x = preop_apply(xa.x, preop);
                xa.y = preop_apply(xa.y, preop);
                xa.z = preop_apply(xa.z, preop);
                xa.w = preop_apply(xa.w, preop);
            }
            As[a_col + 0][a_row] = xa.x;
            As[a_col + 1][a_row] = xa.y;
            As[a_col + 2][a_row] = xa.z;
            As[a_col + 3][a_row] = xa.w;
        }
        {
            const int wr = k0 + b_row;
            const int wc = bn0 + b_col;
            float4 bv = make_float4(0.f, 0.f, 0.f, 0.f);
            const float* wp = W + (size_t)wr * Nc;
            if (wc + 3 < Nc) {
                bv = *(const float4*)(wp + wc);
            } else {
                if (wc     < Nc) bv.x = wp[wc];
                if (wc + 1 < Nc) bv.y = wp[wc + 1];
                if (wc + 2 < Nc) bv.z = wp[wc + 2];
            }
            *(float4*)&Bs[b_row][b_col] = bv;
        }
        __syncthreads();
#pragma unroll
        for (int kk = 0; kk < BK; ++kk) {
            const float4 av = *(const float4*)&As[kk][tr];
            const float4 bw = *(const float4*)&Bs[kk][tc];
            acc[0][0] += av.x * bw.x; acc[0][1] += av.x * bw.y;
            acc[0][2] += av.x * bw.z; acc[0][3] += av.x * bw.w;
            acc[1][0] += av.y * bw.x; acc[1][1] += av.y * bw.y;
            acc[1][2] += av.y * bw.z; acc[1][3] += av.y * bw.w;
            acc[2][0] += av.z * bw.x; acc[2][1] += av.z * bw.y;
            acc[2][2] += av.z * bw.z; acc[2][3] += av.z * bw.w;
            acc[3][0] += av.w * bw.x; acc[3][1] += av.w * bw.y;
            acc[3][2] += av.w * bw.z; acc[3][3] += av.w * bw.w;
        }
        __syncthreads();
    }

#pragma unroll
    for (int i = 0; i < 4; ++i) {
        const int orow = bm0 + tr + i;
#pragma unroll
        for (int j = 0; j < 4; ++j) {
            const int oc = bn0 + tc + j;
            if (oc < Nc)
                out[((size_t)orow * Nc + oc) * ostride] = acc[i][j];
        }
    }
}

// ---------------- elementwise prep ----------------
// pk4[idx]: raw (w_lora, k_lin, a_lora, v_gate) -> (ew, k, aa, bb). b_v: v_lin -> v.
__global__ __launch_bounds__(256) void stage3_kernel(
    float4* pk4, float* v_io, const float* v_first,
    const float* w0, const float* a0, const float* v0,
    const float* k_k, const float* k_a)
{
    const int gw = (blockIdx.x * blockDim.x + threadIdx.x) >> 6; // (b*T+t)*H + h
    const int lane = threadIdx.x & 63;
    const int row = gw >> 4;
    const int h = gw & 15;
    const int c = h * N_DIM + lane;
    const size_t idx = (size_t)row * C_DIM + c;

    const float4 raw = pk4[idx];
    const float w_lora = raw.x, kl = raw.y, a_lora = raw.z, v_gate = raw.w;

    float kk = kl * k_k[c];
    float ss = wred64(kk * kk);
    const float nrm = fmaxf(sqrtf(ss), 1e-12f);
    const float kkn = kk / nrm;

    const float a = 1.0f / (1.0f + expf(-(a0[c] + a_lora)));

    const float u = w0[c] + w_lora;
    const float lnw = -log1pf(expf(-u)) - 0.5f;
    const float ew = expf(-expf(lnw));

    const float sv = 1.0f / (1.0f + expf(-(v0[c] + v_gate)));
    const float vl = v_io[idx];
    const float v = vl + (v_first[idx] - vl) * sv;

    const float ko = kl * (1.0f + (a - 1.0f) * k_a[c]);

    pk4[idx] = make_float4(ew, ko, -kkn, kkn * a);
    v_io[idx] = v;
}

// ---------------- per-(bh, 2-step block) input dot products ----------------
// cd[bh*NBLK+j] = ( bb1·aa2, kk1·aa2, bb1·rr1, kk1·rr1 )  for t1=2j, t2=2j+1
__global__ __launch_bounds__(256) void dots_kernel(
    const float4* __restrict__ pk4, const float* __restrict__ r,
    float4* __restrict__ cd)
{
    const int gw = (blockIdx.x * blockDim.x + threadIdx.x) >> 6; // bh*NBLK + j
    const int lane = threadIdx.x & 63;
    const int j = gw & (NBLK - 1);
    const int bh = gw >> 9;
    const int b = bh >> 4, h = bh & 15;
    const int base0 = b * T_SEQ * C_DIM + h * N_DIM;
    const int i1 = base0 + (2 * j) * C_DIM + lane;

    const float4 P1 = pk4[i1];
    const float4 P2 = pk4[i1 + C_DIM];
    const float R1 = r[i1];

    float ca = P1.w * P2.z;   // bb1*aa2
    float ck = P1.y * P2.z;   // kk1*aa2
    float cb = P1.w * R1;     // bb1*rr1
    float cr = P1.y * R1;     // kk1*rr1
    DPP6X4(ca, ck, cb, cr);
    if (lane == 63)
        cd[gw] = make_float4(ca, ck, cb, cr);
}

// ---------------- sequential scan: 2-step blocked, DPP reduce ----------------
// wave per (b,h,v); lane = k.  Per 2-step block: 4 interleaved reductions over
// the incoming state, scalar stitching via precomputed dots, fused 2-step update.
#define LOAD_BLK(P1, P2, R1, R2, V1, V2, CD, j)                                \
    do {                                                                       \
        const int jc_ = ((j) < NBLK) ? (j) : (NBLK - 1);                       \
        const int o1_ = jc_ * 2048;                                            \
        P1 = pkp[o1_];  P2 = pkp[o1_ + 1024];                                  \
        R1 = rp[o1_];   R2 = rp[o1_ + 1024];                                   \
        V1 = vp[o1_];   V2 = vp[o1_ + 1024];                                   \
        CD = cdp[jc_];                                                         \
    } while (0)

#define COMP_BLK(P1, P2, R1, R2, V1, V2, CD, jblk)                             \
    do {                                                                       \
        const float ewaa_ = P1.x * P2.z;                                       \
        const float ewrr_ = P1.x * R1;                                         \
        float p1_ = s * P1.z;                                                  \
        float u_  = s * ewaa_;                                                 \
        float w_  = s * ewrr_;                                                 \
        float q_  = s * r_prev;                                                \
        DPP6X4(p1_, u_, w_, q_);                                               \
        const float ps1_ = rdl63(p1_);                                         \
        const float us_  = rdl63(u_);                                          \
        const float p2_ = fmaf(V1, CD.y, fmaf(ps1_, CD.x, us_));               \
        if (lane == 63) {                                                      \
            const int tb_ = (jblk) * 2048;                                     \
            if ((jblk) > 0) op[tb_ - 1024] = q_;                               \
            op[tb_] = fmaf(V1, CD.w, fmaf(ps1_, CD.z, w_));                    \
        }                                                                      \
        const float ew12_ = P1.x * P2.x;                                       \
        const float bbew_ = P1.w * P2.x;                                       \
        const float kkew_ = P1.y * P2.x;                                       \
        const float x1_ = fmaf(s, ew12_, ps1_ * bbew_);                        \
        const float x2_ = fmaf(V1, kkew_, p2_ * P2.w);                         \
        const float x3_ = V2 * P2.y;                                           \
        s = x1_ + x2_ + x3_;                                                   \
        r_prev = R2;                                                           \
    } while (0)

__global__ __launch_bounds__(256) void scan_kernel(
    const float4* __restrict__ pk4, const float* __restrict__ r,
    const float* __restrict__ v, const float4* __restrict__ cdots,
    float* __restrict__ o)
{
    const int gw = (blockIdx.x * blockDim.x + threadIdx.x) >> 6; // (b*H+h)*N + vi
    const int lane = threadIdx.x & 63;
    const int vi = gw & 63;
    const int bh = gw >> 6;
    const int b = bh >> 4;
    const int h = bh & 15;

    const int base0 = b * T_SEQ * C_DIM + h * N_DIM;
    const float4* pkp = pk4 + base0 + lane;
    const float*  rp  = r + base0 + lane;
    const float*  vp  = v + base0 + vi;
    const float4* cdp = cdots + bh * NBLK;
    float*        op  = o + base0 + vi;

    float s = 0.0f, r_prev = 0.0f;

    float4 pA1, pA2, cdA; float rA1, rA2, vA1, vA2;
    float4 pB1, pB2, cdB; float rB1, rB2, vB1, vB2;
    float4 pC1, pC2, cdC; float rC1, rC2, vC1, vC2;
    float4 pD1, pD2, cdD; float rD1, rD2, vD1, vD2;

    LOAD_BLK(pA1, pA2, rA1, rA2, vA1, vA2, cdA, 0);
    LOAD_BLK(pB1, pB2, rB1, rB2, vB1, vB2, cdB, 1);

    for (int j = 0; j < NBLK; j += 4) {
        LOAD_BLK(pC1, pC2, rC1, rC2, vC1, vC2, cdC, j + 2);
        COMP_BLK(pA1, pA2, rA1, rA2, vA1, vA2, cdA, j);
        LOAD_BLK(pD1, pD2, rD1, rD2, vD1, vD2, cdD, j + 3);
        COMP_BLK(pB1, pB2, rB1, rB2, vB1, vB2, cdB, j + 1);
        LOAD_BLK(pA1, pA2, rA1, rA2, vA1, vA2, cdA, j + 4);
        COMP_BLK(pC1, pC2, rC1, rC2, vC1, vC2, cdC, j + 2);
        LOAD_BLK(pB1, pB2, rB1, rB2, vB1, vB2, cdB, j + 5);
        COMP_BLK(pD1, pD2, rD1, rD2, vD1, vD2, cdD, j + 3);
    }

    // final pending output: o_{T-1} = sum_k s * r_{T-1}
    float q = s * r_prev;
    DPPADD(q, 0x111); DPPADD(q, 0x112); DPPADD(q, 0x114);
    DPPADD(q, 0x118); DPPADD(q, 0x142); DPPADD(q, 0x143);
    if (lane == 63)
        op[(T_SEQ - 1) * C_DIM] = q;
}

// ---------------- groupnorm + bonus + gate ----------------
__global__ __launch_bounds__(256) void post_kernel(
    const float* o, const float* r, const float4* pk4, const float* v,
    const unsigned short* g,
    const float* r_k, const float* ln_w, const float* ln_b,
    float* y)
{
    const int gw = (blockIdx.x * blockDim.x + threadIdx.x) >> 6;
    const int lane = threadIdx.x & 63;
    const int row = gw >> 4;
    const int h = gw & 15;
    const int c = h * N_DIM + lane;
    const size_t idx = (size_t)row * C_DIM + c;

    const float oo = o[idx];
    float s1 = oo, s2 = oo * oo;
#pragma unroll
    for (int m = 32; m; m >>= 1) {
        s1 += __shfl_xor(s1, m);
        s2 += __shfl_xor(s2, m);
    }
    const float mu = s1 * (1.0f / 64.0f);
    const float var = s2 * (1.0f / 64.0f) - mu * mu;
    float yv = (oo - mu) * rsqrtf(var + 0.00064f);
    yv = yv * ln_w[c] + ln_b[c];

    const float kt = pk4[idx].y;
    const float t3 = wred64(r[idx] * kt * r_k[c]);
    yv += t3 * v[idx];
    y[idx] = yv * bf2f(g[idx]);
}

extern "C" void kernel_launch(void* const* d_in, const int* in_sizes, int n_in,
                              void* d_out, int out_size, void* d_ws, size_t ws_size,
                              hipStream_t stream) {
    (void)in_sizes; (void)n_in; (void)out_size; (void)ws_size;

    const float* residual = (const float*)d_in[0];
    const float* x        = (const float*)d_in[1];
    const float* v_first  = (const float*)d_in[2];
    const float* mr = (const float*)d_in[6];
    const float* mw = (const float*)d_in[7];
    const float* mk = (const float*)d_in[8];
    const float* mv = (const float*)d_in[9];
    const float* ma = (const float*)d_in[10];
    const float* mg = (const float*)d_in[11];
    const float* w0 = (const float*)d_in[12];
    const float* w1 = (const float*)d_in[13];
    const float* w2 = (const float*)d_in[14];
    const float* a0 = (const float*)d_in[15];
    const float* a1 = (const float*)d_in[16];
    const float* a2 = (const float*)d_in[17];
    const float* v0 = (const float*)d_in[18];
    const float* v1 = (const float*)d_in[19];
    const float* v2 = (const float*)d_in[20];
    const float* g1 = (const float*)d_in[21];
    const float* g2 = (const float*)d_in[22];
    const float* k_k = (const float*)d_in[23];
    const float* k_a = (const float*)d_in[24];
    const float* r_k = (const float*)d_in[25];
    const float* W_r = (const float*)d_in[26];
    const float* W_k = (const float*)d_in[27];
    const float* W_v = (const float*)d_in[28];
    const float* W_o = (const float*)d_in[29];
    const float* ln_w = (const float*)d_in[30];
    const float* ln_b = (const float*)d_in[31];

    float* out = (float*)d_out;
    char* wsb = (char*)d_ws;

    // ---- workspace layout (bytes); ends at 68,943,872 B < 69.7 MB proven safe ----
    float4* pk4 = (float4*)(wsb + 0);                          // [M][C] float4 (32 MiB)
    float* b_r  = (float*)(wsb + 33554432);
    float* b_v  = (float*)(wsb + 41943040);
    float* b_o  = (float*)(wsb + 50331648);
    unsigned short* b_g = (unsigned short*)(wsb + 58720256);   // bf16 [M][C]
    float* hw = (float*)(wsb + 62914560);   // [M,64] fp32
    float* ha = (float*)(wsb + 63438848);   // [M,64]
    float* hv = (float*)(wsb + 63963136);   // [M,32]
    float* hg = (float*)(wsb + 64225280);   // [M,160]
    unsigned short* wt_a1 = (unsigned short*)(wsb + 65536000); // [64][1024]
    unsigned short* wt_v1 = (unsigned short*)(wsb + 65667072); // [32][1024]
    unsigned short* wt_g1 = (unsigned short*)(wsb + 65732608); // [160][1024]
    unsigned short* wt_a2 = (unsigned short*)(wsb + 66060288); // [1024][64]
    unsigned short* wt_v2 = (unsigned short*)(wsb + 66191360); // [1024][32]
    unsigned short* wt_g2 = (unsigned short*)(wsb + 66256896); // [1024][160]
    unsigned short* wt_big = (unsigned short*)(wsb + 66584576); // [1024][1024] slot
    float4* cdots = (float4*)(wsb + 68681728);                 // [32][512] float4

    const dim3 blk(256);
    const dim3 tblk(32, 8);
    auto wtr = [&](const float* W, unsigned short* WT, int K, int N) {
        wtrans_kernel<<<dim3((N + 31) / 32, (K + 31) / 32), tblk, 0, stream>>>(W, WT, K, N);
    };
    auto mgemm = [&](const float* X, const float* mx, const unsigned short* WT,
                     const float* add, float* O, int K, int Nc, int preop, int ostride) {
        dim3 grid((Nc + GBN - 1) / GBN, M_ROWS / GBM);
        gemm_mfma_kernel<false><<<grid, blk, 0, stream>>>(X, mx, WT, add, (void*)O, K, Nc, preop, ostride);
    };
    auto mgemm_bf = [&](const float* X, const float* mx, const unsigned short* WT,
                        unsigned short* O, int K, int Nc, int preop) {
        dim3 grid((Nc + GBN - 1) / GBN, M_ROWS / GBM);
        gemm_mfma_kernel<true><<<grid, blk, 0, stream>>>(X, mx, WT, nullptr, (void*)O, K, Nc, preop, 1);
    };
    auto fgemm = [&](const float* X, const float* mx, const float* W,
                     float* O, int M, int K, int Nc, int preop, int ostride) {
        dim3 grid((Nc + BN - 1) / BN, M / BM);
        gemm_kernel<<<grid, blk, 0, stream>>>(X, mx, W, O, M, K, Nc, preop, ostride);
    };

    float* pk_f = (float*)pk4;

    // Stage 0: small weights converted once
    wtr(a1, wt_a1, C_DIM, 64);
    wtr(v1, wt_v1, C_DIM, 32);
    wtr(g1, wt_g1, C_DIM, 160);
    wtr(a2, wt_a2, 64, C_DIM);
    wtr(v2, wt_v2, 32, C_DIM);
    wtr(g2, wt_g2, 160, C_DIM);

    // Stage 1: projections (big weights ping-pong through wt_big)
    wtr(W_r, wt_big, C_DIM, C_DIM);
    mgemm(x, mr, wt_big, nullptr, b_r, C_DIM, C_DIM, 0, 1);
    wtr(W_k, wt_big, C_DIM, C_DIM);
    mgemm(x, mk, wt_big, nullptr, pk_f + 1, C_DIM, C_DIM, 0, 4);   // k_lin -> pk4.y
    wtr(W_v, wt_big, C_DIM, C_DIM);
    mgemm(x, mv, wt_big, nullptr, b_v, C_DIM, C_DIM, 0, 1);        // v_lin
    fgemm(x, mw, w1, hw, M_ROWS, C_DIM, 64, 0, 1);                 // fp32 decay path
    mgemm(x, ma, wt_a1, nullptr, ha, C_DIM, 64, 0, 1);
    mgemm(x, mv, wt_v1, nullptr, hv, C_DIM, 32, 0, 1);
    mgemm(x, mg, wt_g1, nullptr, hg, C_DIM, 160, 0, 1);

    // Stage 2: LoRA second matmuls
    fgemm(hw, nullptr, w2, pk_f + 0, M_ROWS, 64, C_DIM, 1, 4);     // tanh -> pk4.x
    mgemm(ha, nullptr, wt_a2, nullptr, pk_f + 2, 64, C_DIM, 0, 4); // a_lora -> pk4.z
    mgemm(hv, nullptr, wt_v2, nullptr, pk_f + 3, 32, C_DIM, 0, 4); // v_gate -> pk4.w
    mgemm_bf(hg, nullptr, wt_g2, b_g, 160, C_DIM, 2);              // sigmoid, bf16 out

    // Stage 3: elementwise prep (pk4 & b_v transformed in place)
    stage3_kernel<<<dim3((M_ROWS * H_DIM * 64) / 256), blk, 0, stream>>>(
        pk4, b_v, v_first, w0, a0, v0, k_k, k_a);

    // Stage 3b: per-block input dot products
    dots_kernel<<<dim3((B_DIM * H_DIM * NBLK) / 4), blk, 0, stream>>>(
        pk4, b_r, cdots);

    // Stage 4: sequential scan (2-step blocked)
    scan_kernel<<<dim3((B_DIM * H_DIM * N_DIM * 64) / 256), blk, 0, stream>>>(
        pk4, b_r, b_v, cdots, b_o);

    // Stage 5: groupnorm + bonus + gate
    post_kernel<<<dim3((M_ROWS * H_DIM * 64) / 256), blk, 0, stream>>>(
        b_o, b_r, pk4, b_v, b_g, r_k, ln_w, ln_b, b_o);

    // Stage 6: output projection + residual
    wtr(W_o, wt_big, C_DIM, C_DIM);
    mgemm(b_o, nullptr, wt_big, residual, out, C_DIM, C_DIM, 0, 1);
}

// Round 7
// 344.922 us; speedup vs baseline: 3.8794x; 1.7135x over previous
//
#include <hip/hip_runtime.h>
#include <math.h>

// Problem constants
#define B_DIM 2
#define T_SEQ 1024
#define C_DIM 1024
#define H_DIM 16
#define N_DIM 64
#define M_ROWS (B_DIM * T_SEQ)   // 2048
#define NBLK 512                 // T/2 two-step blocks

// MFMA GEMM tiling
#define GBM 64
#define GBN 64
#define GBK 64
#define LDK 88

typedef __attribute__((ext_vector_type(8))) short bf16x8;
typedef __attribute__((ext_vector_type(4))) float f32x4;
typedef unsigned short ushortx4 __attribute__((ext_vector_type(4)));
typedef unsigned short ushortx8 __attribute__((ext_vector_type(8)));

__device__ __forceinline__ unsigned short f2bf(float f) {
    unsigned int u = __float_as_uint(f);
    u = (u + 0x7FFFu + ((u >> 16) & 1u)) >> 16;   // RNE
    return (unsigned short)u;
}
__device__ __forceinline__ float bf2f(unsigned short h) {
    return __uint_as_float(((unsigned int)h) << 16);
}

__device__ __forceinline__ float wred64(float v) {
#pragma unroll
    for (int m = 32; m; m >>= 1) v += __shfl_xor(v, m);
    return v;
}

// DPP wave-64 sum network: after 6 adds the FULL sum is in lane 63. old=0.
#define DPPADD(v, ctrl)                                                        \
    v += __int_as_float(__builtin_amdgcn_update_dpp(                           \
        0, __float_as_int(v), (ctrl), 0xF, 0xF, false))

#define DPP6X4(a, b, c, d)                                                     \
    do {                                                                       \
        DPPADD(a, 0x111); DPPADD(b, 0x111); DPPADD(c, 0x111); DPPADD(d, 0x111);\
        DPPADD(a, 0x112); DPPADD(b, 0x112); DPPADD(c, 0x112); DPPADD(d, 0x112);\
        DPPADD(a, 0x114); DPPADD(b, 0x114); DPPADD(c, 0x114); DPPADD(d, 0x114);\
        DPPADD(a, 0x118); DPPADD(b, 0x118); DPPADD(c, 0x118); DPPADD(d, 0x118);\
        DPPADD(a, 0x142); DPPADD(b, 0x142); DPPADD(c, 0x142); DPPADD(d, 0x142);\
        DPPADD(a, 0x143); DPPADD(b, 0x143); DPPADD(c, 0x143); DPPADD(d, 0x143);\
    } while (0)

__device__ __forceinline__ float rdl63(float v) {
    return __int_as_float(__builtin_amdgcn_readlane(__float_as_int(v), 63));
}

// ---------------- single weight transpose (W_r / W_o, 1024x1024) ----------------
__global__ __launch_bounds__(256) void wtrans_kernel(
    const float* __restrict__ W, unsigned short* __restrict__ WT)
{
    __shared__ float tile[32][33];
    const int tx = threadIdx.x, ty = threadIdx.y;
    const int n0 = blockIdx.x * 32, k0 = blockIdx.y * 32;
#pragma unroll
    for (int i = 0; i < 4; ++i)
        tile[ty + i * 8][tx] = W[(size_t)(k0 + ty + i * 8) * 1024 + n0 + tx];
    __syncthreads();
#pragma unroll
    for (int i = 0; i < 4; ++i)
        WT[(size_t)(n0 + ty + i * 8) * 1024 + k0 + tx] = f2bf(tile[tx][ty + i * 8]);
}

// ---------------- batched transpose+convert for all other weights ----------------
// jobs (tile ranges hardcoded): W_k->wtA, W_v->wtB, w1,a1,v1,g1,a2,v2,g2,w2
__global__ __launch_bounds__(256) void trans_all_kernel(
    const float* Wk, const float* Wv, const float* w1p, const float* a1p,
    const float* v1p, const float* g1p, const float* a2p, const float* v2p,
    const float* g2p, const float* w2p,
    unsigned short* wtA, unsigned short* wtB, unsigned short* wt_w1,
    unsigned short* wt_a1, unsigned short* wt_v1, unsigned short* wt_g1,
    unsigned short* wt_a2, unsigned short* wt_v2, unsigned short* wt_g2,
    unsigned short* wt_w2)
{
    __shared__ float tile[32][33];
    const int bid = blockIdx.x;
    const float* W; unsigned short* WT; int K, N, t0;
    if      (bid < 1024) { W = Wk;  WT = wtA;   K = 1024; N = 1024; t0 = 0;    }
    else if (bid < 2048) { W = Wv;  WT = wtB;   K = 1024; N = 1024; t0 = 1024; }
    else if (bid < 2112) { W = w1p; WT = wt_w1; K = 1024; N = 64;   t0 = 2048; }
    else if (bid < 2176) { W = a1p; WT = wt_a1; K = 1024; N = 64;   t0 = 2112; }
    else if (bid < 2208) { W = v1p; WT = wt_v1; K = 1024; N = 32;   t0 = 2176; }
    else if (bid < 2368) { W = g1p; WT = wt_g1; K = 1024; N = 160;  t0 = 2208; }
    else if (bid < 2432) { W = a2p; WT = wt_a2; K = 64;   N = 1024; t0 = 2368; }
    else if (bid < 2464) { W = v2p; WT = wt_v2; K = 32;   N = 1024; t0 = 2432; }
    else if (bid < 2624) { W = g2p; WT = wt_g2; K = 160;  N = 1024; t0 = 2464; }
    else                 { W = w2p; WT = wt_w2; K = 64;   N = 1024; t0 = 2624; }
    const int lt = bid - t0;
    const int ntx = N >> 5;
    const int n0 = (lt % ntx) * 32;
    const int k0 = (lt / ntx) * 32;
    const int tx = threadIdx.x, ty = threadIdx.y;
#pragma unroll
    for (int i = 0; i < 4; ++i)
        tile[ty + i * 8][tx] = W[(size_t)(k0 + ty + i * 8) * N + n0 + tx];
    __syncthreads();
#pragma unroll
    for (int i = 0; i < 4; ++i)
        WT[(size_t)(n0 + ty + i * 8) * K + k0 + tx] = f2bf(tile[tx][ty + i * 8]);
}

// ---------------- stage-1 multi-GEMM (A = mixed x, fp32->bf16; K=1024) ----------
// phase 0: nt<16 -> k-proj (wtA) -> pk_f+1 ostride4 ; nt>=16 -> v-proj (wtB) -> b_v
// phase 1: nt<16 -> r (wtA) -> b_r ; nt==16 a1->h+0 ; nt==17 v1->h+64 ;
//          nt in[18,21) g1->h+96 (sigmoid) ; nt==21 w1->h+256 (tanh)
__global__ __launch_bounds__(256) void gemm_s1_kernel(
    int phase, const float* __restrict__ X,
    const float* mr, const float* mk, const float* mv, const float* ma,
    const float* mg, const float* mw,
    const unsigned short* wtA, const unsigned short* wtB,
    const unsigned short* wt_a1, const unsigned short* wt_v1,
    const unsigned short* wt_g1, const unsigned short* wt_w1,
    float* pk_f, float* b_v, float* b_r, unsigned short* h_cat)
{
    const int nt = blockIdx.x;
    const float* mixv; const unsigned short* WT;
    float* outf = nullptr; unsigned short* outh = nullptr;
    int Nc, nb, ostride = 1, post = 0, hoff = 0;
    if (phase == 0) {
        if (nt < 16) { mixv = mk; WT = wtA; outf = pk_f + 1; ostride = 4; Nc = 1024; nb = nt; }
        else         { mixv = mv; WT = wtB; outf = b_v;      ostride = 1; Nc = 1024; nb = nt - 16; }
    } else {
        if (nt < 16)      { mixv = mr; WT = wtA;   outf = b_r; Nc = 1024; nb = nt; }
        else if (nt == 16){ mixv = ma; WT = wt_a1; outh = h_cat; hoff = 0;   Nc = 64;  nb = 0; }
        else if (nt == 17){ mixv = mv; WT = wt_v1; outh = h_cat; hoff = 64;  Nc = 32;  nb = 0; }
        else if (nt < 21) { mixv = mg; WT = wt_g1; outh = h_cat; hoff = 96;  Nc = 160; nb = nt - 18; post = 2; }
        else              { mixv = mw; WT = wt_w1; outh = h_cat; hoff = 256; Nc = 64;  nb = 0; post = 1; }
    }
    const int K = 1024;
    const int bn0 = nb * 64;
    const int bm0 = blockIdx.y * GBM;

    __shared__ unsigned short As[GBM][LDK];
    __shared__ unsigned short Bs[GBN][LDK];

    const int tid = threadIdx.x;
    const int lane = tid & 63;
    const int wid = tid >> 6;
    const int wr = wid >> 1, wc = wid & 1;
    const int l15 = lane & 15, l4 = lane >> 4;

    const int ar = tid >> 2;
    const int as = (tid & 3) << 4;
    const int row = bm0 + ar;
    const int t_in = row & (T_SEQ - 1);

    const int brn = tid >> 2;
    const int bks = (tid & 3) << 4;
    const bool bn_ok = (bn0 + brn) < Nc;

    f32x4 acc[2][2] = {};

    for (int k0 = 0; k0 < K; k0 += GBK) {
#pragma unroll
        for (int i = 0; i < 4; ++i) {
            const int kg = k0 + as + 4 * i;
            const float* xp = X + (size_t)row * K + kg;
            float4 xa = *(const float4*)xp;
            float4 xp4 = make_float4(0.f, 0.f, 0.f, 0.f);
            if (t_in > 0) xp4 = *(const float4*)(xp - K);
            const float4 m4 = *(const float4*)(mixv + kg);
            xa.x += (xp4.x - xa.x) * m4.x;
            xa.y += (xp4.y - xa.y) * m4.y;
            xa.z += (xp4.z - xa.z) * m4.z;
            xa.w += (xp4.w - xa.w) * m4.w;
            ushortx4 pk;
            pk.x = f2bf(xa.x); pk.y = f2bf(xa.y); pk.z = f2bf(xa.z); pk.w = f2bf(xa.w);
            *(ushortx4*)&As[ar][as + 4 * i] = pk;
        }
#pragma unroll
        for (int i = 0; i < 2; ++i) {
            const int kk = bks + 8 * i;
            ushortx8 bv = {0, 0, 0, 0, 0, 0, 0, 0};
            if (bn_ok)
                bv = *(const ushortx8*)(WT + (size_t)(bn0 + brn) * K + k0 + kk);
            *(ushortx8*)&Bs[brn][kk] = bv;
        }
        __syncthreads();
#pragma unroll
        for (int ks = 0; ks < 2; ++ks) {
            bf16x8 af0 = *(const bf16x8*)&As[wr * 32 +      l15][ks * 32 + l4 * 8];
            bf16x8 af1 = *(const bf16x8*)&As[wr * 32 + 16 + l15][ks * 32 + l4 * 8];
            bf16x8 bg0 = *(const bf16x8*)&Bs[wc * 32 +      l15][ks * 32 + l4 * 8];
            bf16x8 bg1 = *(const bf16x8*)&Bs[wc * 32 + 16 + l15][ks * 32 + l4 * 8];
            acc[0][0] = __builtin_amdgcn_mfma_f32_16x16x32_bf16(af0, bg0, acc[0][0], 0, 0, 0);
            acc[0][1] = __builtin_amdgcn_mfma_f32_16x16x32_bf16(af0, bg1, acc[0][1], 0, 0, 0);
            acc[1][0] = __builtin_amdgcn_mfma_f32_16x16x32_bf16(af1, bg0, acc[1][0], 0, 0, 0);
            acc[1][1] = __builtin_amdgcn_mfma_f32_16x16x32_bf16(af1, bg1, acc[1][1], 0, 0, 0);
        }
        __syncthreads();
    }

#pragma unroll
    for (int fi = 0; fi < 2; ++fi)
#pragma unroll
        for (int fj = 0; fj < 2; ++fj) {
            const int ocol = bn0 + wc * 32 + fj * 16 + l15;
            if (ocol < Nc) {
#pragma unroll
                for (int p = 0; p < 4; ++p) {
                    const int orow = bm0 + wr * 32 + fi * 16 + l4 * 4 + p;
                    float v = acc[fi][fj][p];
                    if (post == 1) v = tanhf(v);
                    else if (post == 2) v = 1.0f / (1.0f + expf(-v));
                    if (outh)
                        outh[(size_t)orow * 320 + hoff + ocol] = f2bf(v);
                    else
                        outf[((size_t)orow * 1024 + ocol) * ostride] = v;
                }
            }
        }
}

// ---------------- stage-2 multi-GEMM (A = h_cat bf16 [M][320]; N=1024) ----------
// nt>>4: 0 a2(K=64,off0)->pk.z  1 v2(K=32,off64)->pk.w  2 g2(K=160,off96)->b_g  3 w2(K=64,off256)->pk.x
__global__ __launch_bounds__(256) void gemm_s2_kernel(
    const unsigned short* __restrict__ h_cat,
    const unsigned short* wt_a2, const unsigned short* wt_v2,
    const unsigned short* wt_g2, const unsigned short* wt_w2,
    float* pk_f, unsigned short* b_g)
{
    const int g = blockIdx.x >> 4;
    const int nb = blockIdx.x & 15;
    const unsigned short* WT;
    float* outf = nullptr; unsigned short* outh = nullptr;
    int K, aoff;
    if      (g == 0) { WT = wt_a2; K = 64;  aoff = 0;   outf = pk_f + 2; }
    else if (g == 1) { WT = wt_v2; K = 32;  aoff = 64;  outf = pk_f + 3; }
    else if (g == 2) { WT = wt_g2; K = 160; aoff = 96;  outh = b_g; }
    else             { WT = wt_w2; K = 64;  aoff = 256; outf = pk_f + 0; }

    const int bn0 = nb * 64;
    const int bm0 = blockIdx.y * GBM;

    __shared__ unsigned short As[GBM][LDK];
    __shared__ unsigned short Bs[GBN][LDK];

    const int tid = threadIdx.x;
    const int lane = tid & 63;
    const int wid = tid >> 6;
    const int wr = wid >> 1, wc = wid & 1;
    const int l15 = lane & 15, l4 = lane >> 4;

    const int ar = tid >> 2;
    const int as = (tid & 3) << 4;
    const int brn = tid >> 2;
    const int bks = (tid & 3) << 4;

    f32x4 acc[2][2] = {};

    for (int k0 = 0; k0 < K; k0 += GBK) {
#pragma unroll
        for (int i = 0; i < 2; ++i) {
            const int kk = as + 8 * i;
            ushortx8 av = {0, 0, 0, 0, 0, 0, 0, 0};
            if (k0 + kk < K)
                av = *(const ushortx8*)(h_cat + (size_t)(bm0 + ar) * 320 + aoff + k0 + kk);
            *(ushortx8*)&As[ar][kk] = av;
        }
#pragma unroll
        for (int i = 0; i < 2; ++i) {
            const int kk = bks + 8 * i;
            ushortx8 bv = {0, 0, 0, 0, 0, 0, 0, 0};
            if (k0 + kk < K)
                bv = *(const ushortx8*)(WT + (size_t)(bn0 + brn) * K + k0 + kk);
            *(ushortx8*)&Bs[brn][kk] = bv;
        }
        __syncthreads();
#pragma unroll
        for (int ks = 0; ks < 2; ++ks) {
            bf16x8 af0 = *(const bf16x8*)&As[wr * 32 +      l15][ks * 32 + l4 * 8];
            bf16x8 af1 = *(const bf16x8*)&As[wr * 32 + 16 + l15][ks * 32 + l4 * 8];
            bf16x8 bg0 = *(const bf16x8*)&Bs[wc * 32 +      l15][ks * 32 + l4 * 8];
            bf16x8 bg1 = *(const bf16x8*)&Bs[wc * 32 + 16 + l15][ks * 32 + l4 * 8];
            acc[0][0] = __builtin_amdgcn_mfma_f32_16x16x32_bf16(af0, bg0, acc[0][0], 0, 0, 0);
            acc[0][1] = __builtin_amdgcn_mfma_f32_16x16x32_bf16(af0, bg1, acc[0][1], 0, 0, 0);
            acc[1][0] = __builtin_amdgcn_mfma_f32_16x16x32_bf16(af1, bg0, acc[1][0], 0, 0, 0);
            acc[1][1] = __builtin_amdgcn_mfma_f32_16x16x32_bf16(af1, bg1, acc[1][1], 0, 0, 0);
        }
        __syncthreads();
    }

#pragma unroll
    for (int fi = 0; fi < 2; ++fi)
#pragma unroll
        for (int fj = 0; fj < 2; ++fj) {
            const int ocol = bn0 + wc * 32 + fj * 16 + l15;
#pragma unroll
            for (int p = 0; p < 4; ++p) {
                const int orow = bm0 + wr * 32 + fi * 16 + l4 * 4 + p;
                const float v = acc[fi][fj][p];
                if (outh)
                    outh[(size_t)orow * 1024 + ocol] = f2bf(v);
                else
                    outf[((size_t)orow * 1024 + ocol) * 4] = v;
            }
        }
}

// ---------------- final GEMM (A=b_o fp32, W_o^T, +residual) ----------------
__global__ __launch_bounds__(256) void gemm_final_kernel(
    const float* __restrict__ X, const unsigned short* __restrict__ WT,
    const float* __restrict__ addend, float* __restrict__ out)
{
    const int K = 1024, Nc = 1024;
    __shared__ unsigned short As[GBM][LDK];
    __shared__ unsigned short Bs[GBN][LDK];

    const int tid = threadIdx.x;
    const int lane = tid & 63;
    const int wid = tid >> 6;
    const int wr = wid >> 1, wc = wid & 1;
    const int l15 = lane & 15, l4 = lane >> 4;

    const int bm0 = blockIdx.y * GBM;
    const int bn0 = blockIdx.x * GBN;
    const int ar = tid >> 2;
    const int as = (tid & 3) << 4;
    const int row = bm0 + ar;
    const int brn = tid >> 2;
    const int bks = (tid & 3) << 4;

    f32x4 acc[2][2] = {};

    for (int k0 = 0; k0 < K; k0 += GBK) {
#pragma unroll
        for (int i = 0; i < 4; ++i) {
            const int kg = k0 + as + 4 * i;
            const float4 xa = *(const float4*)(X + (size_t)row * K + kg);
            ushortx4 pk;
            pk.x = f2bf(xa.x); pk.y = f2bf(xa.y); pk.z = f2bf(xa.z); pk.w = f2bf(xa.w);
            *(ushortx4*)&As[ar][as + 4 * i] = pk;
        }
#pragma unroll
        for (int i = 0; i < 2; ++i) {
            const int kk = bks + 8 * i;
            *(ushortx8*)&Bs[brn][kk] =
                *(const ushortx8*)(WT + (size_t)(bn0 + brn) * K + k0 + kk);
        }
        __syncthreads();
#pragma unroll
        for (int ks = 0; ks < 2; ++ks) {
            bf16x8 af0 = *(const bf16x8*)&As[wr * 32 +      l15][ks * 32 + l4 * 8];
            bf16x8 af1 = *(const bf16x8*)&As[wr * 32 + 16 + l15][ks * 32 + l4 * 8];
            bf16x8 bg0 = *(const bf16x8*)&Bs[wc * 32 +      l15][ks * 32 + l4 * 8];
            bf16x8 bg1 = *(const bf16x8*)&Bs[wc * 32 + 16 + l15][ks * 32 + l4 * 8];
            acc[0][0] = __builtin_amdgcn_mfma_f32_16x16x32_bf16(af0, bg0, acc[0][0], 0, 0, 0);
            acc[0][1] = __builtin_amdgcn_mfma_f32_16x16x32_bf16(af0, bg1, acc[0][1], 0, 0, 0);
            acc[1][0] = __builtin_amdgcn_mfma_f32_16x16x32_bf16(af1, bg0, acc[1][0], 0, 0, 0);
            acc[1][1] = __builtin_amdgcn_mfma_f32_16x16x32_bf16(af1, bg1, acc[1][1], 0, 0, 0);
        }
        __syncthreads();
    }

#pragma unroll
    for (int fi = 0; fi < 2; ++fi)
#pragma unroll
        for (int fj = 0; fj < 2; ++fj) {
            const int ocol = bn0 + wc * 32 + fj * 16 + l15;
#pragma unroll
            for (int p = 0; p < 4; ++p) {
                const int orow = bm0 + wr * 32 + fi * 16 + l4 * 4 + p;
                out[(size_t)orow * Nc + ocol] =
                    acc[fi][fj][p] + addend[(size_t)orow * Nc + ocol];
            }
        }
}

// ---------------- fused stage3 + dots ----------------
// block = 4 waves = 4 consecutive timesteps of one (b,h). Wave does stage3 for
// its t (pk4/v rewritten in place), stashes (ew,ko,aa,bb,r) in LDS; waves 0/2
// then compute the pair dot products for the 2-step-blocked scan.
__global__ __launch_bounds__(256) void stage3_dots_kernel(
    float4* pk4, float* v_io, const float* __restrict__ v_first,
    const float* __restrict__ b_r,
    const float* w0, const float* a0, const float* v0,
    const float* k_k, const float* k_a, float4* __restrict__ cd)
{
    __shared__ float lds[4][64][6];
    const int tid = threadIdx.x;
    const int w = tid >> 6, lane = tid & 63;
    const int bh = blockIdx.x >> 8;
    const int j4 = blockIdx.x & 255;
    const int b = bh >> 4, h = bh & 15;
    const int t = j4 * 4 + w;
    const int row = b * T_SEQ + t;
    const int c = h * N_DIM + lane;
    const size_t idx = (size_t)row * C_DIM + c;

    const float4 raw = pk4[idx];
    const float w_lora = raw.x, kl = raw.y, a_lora = raw.z, v_gate = raw.w;

    float kk = kl * k_k[c];
    float ss = wred64(kk * kk);
    const float nrm = fmaxf(sqrtf(ss), 1e-12f);
    const float kkn = kk / nrm;

    const float a = 1.0f / (1.0f + expf(-(a0[c] + a_lora)));

    const float u = w0[c] + w_lora;
    const float lnw = -log1pf(expf(-u)) - 0.5f;
    const float ew = expf(-expf(lnw));

    const float sv = 1.0f / (1.0f + expf(-(v0[c] + v_gate)));
    const float vl = v_io[idx];
    const float v = vl + (v_first[idx] - vl) * sv;

    const float ko = kl * (1.0f + (a - 1.0f) * k_a[c]);
    const float aa = -kkn;
    const float bb = kkn * a;

    pk4[idx] = make_float4(ew, ko, aa, bb);
    v_io[idx] = v;

    lds[w][lane][0] = ko;   // kk1
    lds[w][lane][1] = aa;
    lds[w][lane][2] = bb;
    lds[w][lane][3] = b_r[idx];
    __syncthreads();

    if ((w & 1) == 0) {
        const float bb1 = lds[w][lane][2];
        const float kk1 = lds[w][lane][0];
        const float aa2 = lds[w + 1][lane][1];
        const float R1  = lds[w][lane][3];
        float ca = bb1 * aa2;
        float ck = kk1 * aa2;
        float cb = bb1 * R1;
        float cr = kk1 * R1;
        DPP6X4(ca, ck, cb, cr);
        if (lane == 63)
            cd[bh * NBLK + j4 * 2 + (w >> 1)] = make_float4(ca, ck, cb, cr);
    }
}

// ---------------- sequential scan: 2-step blocked, DPP reduce ----------------
#define LOAD_BLK(P1, P2, R1, R2, V1, V2, CD, j)                                \
    do {                                                                       \
        const int jc_ = ((j) < NBLK) ? (j) : (NBLK - 1);                       \
        const int o1_ = jc_ * 2048;                                            \
        P1 = pkp[o1_];  P2 = pkp[o1_ + 1024];                                  \
        R1 = rp[o1_];   R2 = rp[o1_ + 1024];                                   \
        V1 = vp[o1_];   V2 = vp[o1_ + 1024];                                   \
        CD = cdp[jc_];                                                         \
    } while (0)

#define COMP_BLK(P1, P2, R1, R2, V1, V2, CD, jblk)                             \
    do {                                                                       \
        const float ewaa_ = P1.x * P2.z;                                       \
        const float ewrr_ = P1.x * R1;                                         \
        float p1_ = s * P1.z;                                                  \
        float u_  = s * ewaa_;                                                 \
        float w_  = s * ewrr_;                                                 \
        float q_  = s * r_prev;                                                \
        DPP6X4(p1_, u_, w_, q_);                                               \
        const float ps1_ = rdl63(p1_);                                         \
        const float us_  = rdl63(u_);                                          \
        const float p2_ = fmaf(V1, CD.y, fmaf(ps1_, CD.x, us_));               \
        if (lane == 63) {                                                      \
            const int tb_ = (jblk) * 2048;                                     \
            if ((jblk) > 0) op[tb_ - 1024] = q_;                               \
            op[tb_] = fmaf(V1, CD.w, fmaf(ps1_, CD.z, w_));                    \
        }                                                                      \
        const float ew12_ = P1.x * P2.x;                                       \
        const float bbew_ = P1.w * P2.x;                                       \
        const float kkew_ = P1.y * P2.x;                                       \
        const float x1_ = fmaf(s, ew12_, ps1_ * bbew_);                        \
        const float x2_ = fmaf(V1, kkew_, p2_ * P2.w);                         \
        const float x3_ = V2 * P2.y;                                           \
        s = x1_ + x2_ + x3_;                                                   \
        r_prev = R2;                                                           \
    } while (0)

__global__ __launch_bounds__(256) void scan_kernel(
    const float4* __restrict__ pk4, const float* __restrict__ r,
    const float* __restrict__ v, const float4* __restrict__ cdots,
    float* __restrict__ o)
{
    const int gw = (blockIdx.x * blockDim.x + threadIdx.x) >> 6;
    const int lane = threadIdx.x & 63;
    const int vi = gw & 63;
    const int bh = gw >> 6;
    const int b = bh >> 4;
    const int h = bh & 15;

    const int base0 = b * T_SEQ * C_DIM + h * N_DIM;
    const float4* pkp = pk4 + base0 + lane;
    const float*  rp  = r + base0 + lane;
    const float*  vp  = v + base0 + vi;
    const float4* cdp = cdots + bh * NBLK;
    float*        op  = o + base0 + vi;

    float s = 0.0f, r_prev = 0.0f;

    float4 pA1, pA2, cdA; float rA1, rA2, vA1, vA2;
    float4 pB1, pB2, cdB; float rB1, rB2, vB1, vB2;
    float4 pC1, pC2, cdC; float rC1, rC2, vC1, vC2;
    float4 pD1, pD2, cdD; float rD1, rD2, vD1, vD2;

    LOAD_BLK(pA1, pA2, rA1, rA2, vA1, vA2, cdA, 0);
    LOAD_BLK(pB1, pB2, rB1, rB2, vB1, vB2, cdB, 1);

    for (int j = 0; j < NBLK; j += 4) {
        LOAD_BLK(pC1, pC2, rC1, rC2, vC1, vC2, cdC, j + 2);
        COMP_BLK(pA1, pA2, rA1, rA2, vA1, vA2, cdA, j);
        LOAD_BLK(pD1, pD2, rD1, rD2, vD1, vD2, cdD, j + 3);
        COMP_BLK(pB1, pB2, rB1, rB2, vB1, vB2, cdB, j + 1);
        LOAD_BLK(pA1, pA2, rA1, rA2, vA1, vA2, cdA, j + 4);
        COMP_BLK(pC1, pC2, rC1, rC2, vC1, vC2, cdC, j + 2);
        LOAD_BLK(pB1, pB2, rB1, rB2, vB1, vB2, cdB, j + 5);
        COMP_BLK(pD1, pD2, rD1, rD2, vD1, vD2, cdD, j + 3);
    }

    float q = s * r_prev;
    DPPADD(q, 0x111); DPPADD(q, 0x112); DPPADD(q, 0x114);
    DPPADD(q, 0x118); DPPADD(q, 0x142); DPPADD(q, 0x143);
    if (lane == 63)
        op[(T_SEQ - 1) * C_DIM] = q;
}

// ---------------- groupnorm + bonus + gate ----------------
__global__ __launch_bounds__(256) void post_kernel(
    const float* o, const float* r, const float4* pk4, const float* v,
    const unsigned short* g,
    const float* r_k, const float* ln_w, const float* ln_b,
    float* y)
{
    const int gw = (blockIdx.x * blockDim.x + threadIdx.x) >> 6;
    const int lane = threadIdx.x & 63;
    const int row = gw >> 4;
    const int h = gw & 15;
    const int c = h * N_DIM + lane;
    const size_t idx = (size_t)row * C_DIM + c;

    const float oo = o[idx];
    float s1 = oo, s2 = oo * oo;
#pragma unroll
    for (int m = 32; m; m >>= 1) {
        s1 += __shfl_xor(s1, m);
        s2 += __shfl_xor(s2, m);
    }
    const float mu = s1 * (1.0f / 64.0f);
    const float var = s2 * (1.0f / 64.0f) - mu * mu;
    float yv = (oo - mu) * rsqrtf(var + 0.00064f);
    yv = yv * ln_w[c] + ln_b[c];

    const float kt = pk4[idx].y;
    const float t3 = wred64(r[idx] * kt * r_k[c]);
    yv += t3 * v[idx];
    y[idx] = yv * bf2f(g[idx]);
}

extern "C" void kernel_launch(void* const* d_in, const int* in_sizes, int n_in,
                              void* d_out, int out_size, void* d_ws, size_t ws_size,
                              hipStream_t stream) {
    (void)in_sizes; (void)n_in; (void)out_size; (void)ws_size;

    const float* residual = (const float*)d_in[0];
    const float* x        = (const float*)d_in[1];
    const float* v_first  = (const float*)d_in[2];
    const float* mr = (const float*)d_in[6];
    const float* mw = (const float*)d_in[7];
    const float* mk = (const float*)d_in[8];
    const float* mv = (const float*)d_in[9];
    const float* ma = (const float*)d_in[10];
    const float* mg = (const float*)d_in[11];
    const float* w0 = (const float*)d_in[12];
    const float* w1 = (const float*)d_in[13];
    const float* w2 = (const float*)d_in[14];
    const float* a0 = (const float*)d_in[15];
    const float* a1 = (const float*)d_in[16];
    const float* a2 = (const float*)d_in[17];
    const float* v0 = (const float*)d_in[18];
    const float* v1 = (const float*)d_in[19];
    const float* v2 = (const float*)d_in[20];
    const float* g1 = (const float*)d_in[21];
    const float* g2 = (const float*)d_in[22];
    const float* k_k = (const float*)d_in[23];
    const float* k_a = (const float*)d_in[24];
    const float* r_k = (const float*)d_in[25];
    const float* W_r = (const float*)d_in[26];
    const float* W_k = (const float*)d_in[27];
    const float* W_v = (const float*)d_in[28];
    const float* W_o = (const float*)d_in[29];
    const float* ln_w = (const float*)d_in[30];
    const float* ln_b = (const float*)d_in[31];

    float* out = (float*)d_out;
    char* wsb = (char*)d_ws;

    // ---- workspace layout (bytes); END = 69,730,304 == round-2-proven size ----
    float4* pk4 = (float4*)(wsb + 0);                           // 33,554,432
    float* b_r  = (float*)(wsb + 33554432);                     //  8,388,608
    float* b_v  = (float*)(wsb + 41943040);                     //  8,388,608
    float* b_o  = (float*)(wsb + 50331648);                     //  8,388,608
    unsigned short* b_g = (unsigned short*)(wsb + 58720256);    //  4,194,304
    unsigned short* h_cat = (unsigned short*)(wsb + 62914560);  //  1,310,720 [2048][320]
    float4* cdots = (float4*)(wsb + 62914560);                  //  overlays h_cat (dead by then)
    unsigned short* wt_a1 = (unsigned short*)(wsb + 64225280);  //    131,072
    unsigned short* wt_v1 = (unsigned short*)(wsb + 64356352);  //     65,536
    unsigned short* wt_g1 = (unsigned short*)(wsb + 64421888);  //    327,680
    unsigned short* wt_a2 = (unsigned short*)(wsb + 64749568);  //    131,072
    unsigned short* wt_v2 = (unsigned short*)(wsb + 64880640);  //     65,536
    unsigned short* wt_g2 = (unsigned short*)(wsb + 64946176);  //    327,680
    unsigned short* wt_w1 = (unsigned short*)(wsb + 65273856);  //    131,072
    unsigned short* wt_w2 = (unsigned short*)(wsb + 65404928);  //    131,072
    unsigned short* wtA   = (unsigned short*)(wsb + 65536000);  //  2,097,152
    unsigned short* wtB   = (unsigned short*)(wsb + 67633152);  //  2,097,152  (end 69,730,304)

    float* pk_f = (float*)pk4;
    const dim3 blk(256);
    const dim3 tblk(32, 8);

    // 1) all weight transposes except W_r/W_o (wtA=W_k, wtB=W_v)
    trans_all_kernel<<<dim3(2688), tblk, 0, stream>>>(
        W_k, W_v, w1, a1, v1, g1, a2, v2, g2, w2,
        wtA, wtB, wt_w1, wt_a1, wt_v1, wt_g1, wt_a2, wt_v2, wt_g2, wt_w2);

    // 2) stage-1 phase 0: k, v projections
    gemm_s1_kernel<<<dim3(32, 32), blk, 0, stream>>>(
        0, x, mr, mk, mv, ma, mg, mw, wtA, wtB,
        wt_a1, wt_v1, wt_g1, wt_w1, pk_f, b_v, b_r, h_cat);

    // 3) W_r -> wtA (WAR on wtA after phase 0, stream-ordered)
    wtrans_kernel<<<dim3(32, 32), tblk, 0, stream>>>(W_r, wtA);

    // 4) stage-1 phase 1: r + the four LoRA-in GEMMs
    gemm_s1_kernel<<<dim3(22, 32), blk, 0, stream>>>(
        1, x, mr, mk, mv, ma, mg, mw, wtA, wtB,
        wt_a1, wt_v1, wt_g1, wt_w1, pk_f, b_v, b_r, h_cat);

    // 5) W_o -> wtB (WAR on wtB after phase 0)
    wtrans_kernel<<<dim3(32, 32), tblk, 0, stream>>>(W_o, wtB);

    // 6) stage-2: a2, v2, g2, w2
    gemm_s2_kernel<<<dim3(64, 32), blk, 0, stream>>>(
        h_cat, wt_a2, wt_v2, wt_g2, wt_w2, pk_f, b_g);

    // 7) fused stage3 + dots
    stage3_dots_kernel<<<dim3(32 * 256), blk, 0, stream>>>(
        pk4, b_v, v_first, b_r, w0, a0, v0, k_k, k_a, cdots);

    // 8) sequential scan (2-step blocked)
    scan_kernel<<<dim3((B_DIM * H_DIM * N_DIM * 64) / 256), blk, 0, stream>>>(
        pk4, b_r, b_v, cdots, b_o);

    // 9) groupnorm + bonus + gate
    post_kernel<<<dim3((M_ROWS * H_DIM * 64) / 256), blk, 0, stream>>>(
        b_o, b_r, pk4, b_v, b_g, r_k, ln_w, ln_b, b_o);

    // 10) output projection + residual
    gemm_final_kernel<<<dim3(16, 32), blk, 0, stream>>>(b_o, wtB, residual, out);
}

// Round 8
// 289.191 us; speedup vs baseline: 4.6270x; 1.1927x over previous
//
#include <hip/hip_runtime.h>
#include <math.h>

// Problem constants
#define B_DIM 2
#define T_SEQ 1024
#define C_DIM 1024
#define H_DIM 16
#define N_DIM 64
#define M_ROWS (B_DIM * T_SEQ)   // 2048
#define NBLK 512                 // T/2 two-step blocks

// MFMA GEMM tiling
#define GBM 64
#define GBN 64
#define GBK 64
#define LDK 88

typedef __attribute__((ext_vector_type(8))) short bf16x8;
typedef __attribute__((ext_vector_type(4))) float f32x4;
typedef unsigned short ushortx4 __attribute__((ext_vector_type(4)));
typedef unsigned short ushortx8 __attribute__((ext_vector_type(8)));

__device__ __forceinline__ unsigned short f2bf(float f) {
    unsigned int u = __float_as_uint(f);
    u = (u + 0x7FFFu + ((u >> 16) & 1u)) >> 16;   // RNE
    return (unsigned short)u;
}
__device__ __forceinline__ float bf2f(unsigned short h) {
    return __uint_as_float(((unsigned int)h) << 16);
}
__device__ __forceinline__ float bflo(unsigned int u) {   // low bf16 of packed pair
    return __uint_as_float(u << 16);
}
__device__ __forceinline__ float bfhi(unsigned int u) {   // high bf16 of packed pair
    return __uint_as_float(u & 0xFFFF0000u);
}

__device__ __forceinline__ float wred64(float v) {
#pragma unroll
    for (int m = 32; m; m >>= 1) v += __shfl_xor(v, m);
    return v;
}

// DPP wave-64 sum network: after 6 adds the FULL sum is in lane 63. old=0.
#define DPPADD(v, ctrl)                                                        \
    v += __int_as_float(__builtin_amdgcn_update_dpp(                           \
        0, __float_as_int(v), (ctrl), 0xF, 0xF, false))

#define DPP6X4(a, b, c, d)                                                     \
    do {                                                                       \
        DPPADD(a, 0x111); DPPADD(b, 0x111); DPPADD(c, 0x111); DPPADD(d, 0x111);\
        DPPADD(a, 0x112); DPPADD(b, 0x112); DPPADD(c, 0x112); DPPADD(d, 0x112);\
        DPPADD(a, 0x114); DPPADD(b, 0x114); DPPADD(c, 0x114); DPPADD(d, 0x114);\
        DPPADD(a, 0x118); DPPADD(b, 0x118); DPPADD(c, 0x118); DPPADD(d, 0x118);\
        DPPADD(a, 0x142); DPPADD(b, 0x142); DPPADD(c, 0x142); DPPADD(d, 0x142);\
        DPPADD(a, 0x143); DPPADD(b, 0x143); DPPADD(c, 0x143); DPPADD(d, 0x143);\
    } while (0)

__device__ __forceinline__ float rdl63(float v) {
    return __int_as_float(__builtin_amdgcn_readlane(__float_as_int(v), 63));
}

// ---------------- premix: all six token-shift mixes, fp32 -> bf16 ----------------
__global__ __launch_bounds__(256) void premix_kernel(
    const float* __restrict__ x,
    const float* mr, const float* mk, const float* mv,
    const float* mw, const float* ma, const float* mg,
    unsigned short* xr, unsigned short* xk, unsigned short* xv,
    unsigned short* xw, unsigned short* xa, unsigned short* xg)
{
    const int g = blockIdx.x * 256 + threadIdx.x;
    const size_t base = (size_t)g * 8;
    const int row = (int)(base >> 10);
    const int col = (int)(base & 1023);
    const int t_in = row & (T_SEQ - 1);

    const float* xp = x + (size_t)row * C_DIM + col;
    float4 a0 = *(const float4*)xp;
    float4 a1 = *(const float4*)(xp + 4);
    float4 p0 = make_float4(0.f, 0.f, 0.f, 0.f), p1 = p0;
    if (t_in > 0) {
        p0 = *(const float4*)(xp - C_DIM);
        p1 = *(const float4*)(xp - C_DIM + 4);
    }
    // deltas
    const float d0x = p0.x - a0.x, d0y = p0.y - a0.y, d0z = p0.z - a0.z, d0w = p0.w - a0.w;
    const float d1x = p1.x - a1.x, d1y = p1.y - a1.y, d1z = p1.z - a1.z, d1w = p1.w - a1.w;

    const float* ms[6] = {mr, mk, mv, mw, ma, mg};
    unsigned short* outs[6] = {xr, xk, xv, xw, xa, xg};
#pragma unroll
    for (int i = 0; i < 6; ++i) {
        const float4 m0 = *(const float4*)(ms[i] + col);
        const float4 m1 = *(const float4*)(ms[i] + col + 4);
        ushortx8 o;
        o[0] = f2bf(fmaf(d0x, m0.x, a0.x));
        o[1] = f2bf(fmaf(d0y, m0.y, a0.y));
        o[2] = f2bf(fmaf(d0z, m0.z, a0.z));
        o[3] = f2bf(fmaf(d0w, m0.w, a0.w));
        o[4] = f2bf(fmaf(d1x, m1.x, a1.x));
        o[5] = f2bf(fmaf(d1y, m1.y, a1.y));
        o[6] = f2bf(fmaf(d1z, m1.z, a1.z));
        o[7] = f2bf(fmaf(d1w, m1.w, a1.w));
        *(ushortx8*)(outs[i] + base) = o;
    }
}

// ---------------- single weight transpose (W_o, 1024x1024) ----------------
__global__ __launch_bounds__(256) void wtrans_kernel(
    const float* __restrict__ W, unsigned short* __restrict__ WT)
{
    __shared__ float tile[32][33];
    const int tx = threadIdx.x, ty = threadIdx.y;
    const int n0 = blockIdx.x * 32, k0 = blockIdx.y * 32;
#pragma unroll
    for (int i = 0; i < 4; ++i)
        tile[ty + i * 8][tx] = W[(size_t)(k0 + ty + i * 8) * 1024 + n0 + tx];
    __syncthreads();
#pragma unroll
    for (int i = 0; i < 4; ++i)
        WT[(size_t)(n0 + ty + i * 8) * 1024 + k0 + tx] = f2bf(tile[tx][ty + i * 8]);
}

// ---------------- batched transpose+convert: W_k, W_v, W_r + 8 small ----------------
__global__ __launch_bounds__(256) void trans_all_kernel(
    const float* Wk, const float* Wv, const float* Wr,
    const float* w1p, const float* a1p, const float* v1p, const float* g1p,
    const float* a2p, const float* v2p, const float* g2p, const float* w2p,
    unsigned short* wtA, unsigned short* wtB, unsigned short* wtC,
    unsigned short* wt_w1, unsigned short* wt_a1, unsigned short* wt_v1,
    unsigned short* wt_g1, unsigned short* wt_a2, unsigned short* wt_v2,
    unsigned short* wt_g2, unsigned short* wt_w2)
{
    __shared__ float tile[32][33];
    const int bid = blockIdx.x;
    const float* W; unsigned short* WT; int K, N, t0;
    if      (bid < 1024) { W = Wk;  WT = wtA;   K = 1024; N = 1024; t0 = 0;    }
    else if (bid < 2048) { W = Wv;  WT = wtB;   K = 1024; N = 1024; t0 = 1024; }
    else if (bid < 3072) { W = Wr;  WT = wtC;   K = 1024; N = 1024; t0 = 2048; }
    else if (bid < 3136) { W = w1p; WT = wt_w1; K = 1024; N = 64;   t0 = 3072; }
    else if (bid < 3200) { W = a1p; WT = wt_a1; K = 1024; N = 64;   t0 = 3136; }
    else if (bid < 3232) { W = v1p; WT = wt_v1; K = 1024; N = 32;   t0 = 3200; }
    else if (bid < 3392) { W = g1p; WT = wt_g1; K = 1024; N = 160;  t0 = 3232; }
    else if (bid < 3456) { W = a2p; WT = wt_a2; K = 64;   N = 1024; t0 = 3392; }
    else if (bid < 3488) { W = v2p; WT = wt_v2; K = 32;   N = 1024; t0 = 3456; }
    else if (bid < 3648) { W = g2p; WT = wt_g2; K = 160;  N = 1024; t0 = 3488; }
    else                 { W = w2p; WT = wt_w2; K = 64;   N = 1024; t0 = 3648; }
    const int lt = bid - t0;
    const int ntx = N >> 5;
    const int n0 = (lt % ntx) * 32;
    const int k0 = (lt / ntx) * 32;
    const int tx = threadIdx.x, ty = threadIdx.y;
#pragma unroll
    for (int i = 0; i < 4; ++i)
        tile[ty + i * 8][tx] = W[(size_t)(k0 + ty + i * 8) * N + n0 + tx];
    __syncthreads();
#pragma unroll
    for (int i = 0; i < 4; ++i)
        WT[(size_t)(n0 + ty + i * 8) * K + k0 + tx] = f2bf(tile[tx][ty + i * 8]);
}

// ---------------- generic MFMA GEMM core (bf16 A [M][K=1024-row], bf16 B^T) -------
// Writes either to h_cat (row-stride 320, +hoff, optional activation) or to a
// strided ushort target: outp[(orow*1024+ocol)*ostr + ooff].
__device__ __forceinline__ void gemm_core(
    const unsigned short* __restrict__ Aarr, int arow_stride,
    const unsigned short* __restrict__ WT, int K, int Nc, int bn0, int bm0,
    unsigned short* outp, int ostr, int ooff,
    unsigned short* outh, int hoff, int post)
{
    __shared__ unsigned short As[GBM][LDK];
    __shared__ unsigned short Bs[GBN][LDK];

    const int tid = threadIdx.x;
    const int lane = tid & 63;
    const int wid = tid >> 6;
    const int wr = wid >> 1, wc = wid & 1;
    const int l15 = lane & 15, l4 = lane >> 4;

    const int ar = tid >> 2;
    const int as = (tid & 3) << 4;
    const int row = bm0 + ar;
    const int brn = tid >> 2;
    const int bks = (tid & 3) << 4;
    const bool bn_ok = (bn0 + brn) < Nc;

    f32x4 acc[2][2] = {};

    for (int k0 = 0; k0 < K; k0 += GBK) {
#pragma unroll
        for (int i = 0; i < 2; ++i) {
            const int kk = as + 8 * i;
            ushortx8 av = {0, 0, 0, 0, 0, 0, 0, 0};
            if (k0 + kk < K)
                av = *(const ushortx8*)(Aarr + (size_t)row * arow_stride + k0 + kk);
            *(ushortx8*)&As[ar][kk] = av;
        }
#pragma unroll
        for (int i = 0; i < 2; ++i) {
            const int kk = bks + 8 * i;
            ushortx8 bv = {0, 0, 0, 0, 0, 0, 0, 0};
            if (bn_ok && (k0 + kk < K))
                bv = *(const ushortx8*)(WT + (size_t)(bn0 + brn) * K + k0 + kk);
            *(ushortx8*)&Bs[brn][kk] = bv;
        }
        __syncthreads();
#pragma unroll
        for (int ks = 0; ks < 2; ++ks) {
            bf16x8 af0 = *(const bf16x8*)&As[wr * 32 +      l15][ks * 32 + l4 * 8];
            bf16x8 af1 = *(const bf16x8*)&As[wr * 32 + 16 + l15][ks * 32 + l4 * 8];
            bf16x8 bg0 = *(const bf16x8*)&Bs[wc * 32 +      l15][ks * 32 + l4 * 8];
            bf16x8 bg1 = *(const bf16x8*)&Bs[wc * 32 + 16 + l15][ks * 32 + l4 * 8];
            acc[0][0] = __builtin_amdgcn_mfma_f32_16x16x32_bf16(af0, bg0, acc[0][0], 0, 0, 0);
            acc[0][1] = __builtin_amdgcn_mfma_f32_16x16x32_bf16(af0, bg1, acc[0][1], 0, 0, 0);
            acc[1][0] = __builtin_amdgcn_mfma_f32_16x16x32_bf16(af1, bg0, acc[1][0], 0, 0, 0);
            acc[1][1] = __builtin_amdgcn_mfma_f32_16x16x32_bf16(af1, bg1, acc[1][1], 0, 0, 0);
        }
        __syncthreads();
    }

#pragma unroll
    for (int fi = 0; fi < 2; ++fi)
#pragma unroll
        for (int fj = 0; fj < 2; ++fj) {
            const int ocol = bn0 + wc * 32 + fj * 16 + l15;
            if (ocol < Nc) {
#pragma unroll
                for (int p = 0; p < 4; ++p) {
                    const int orow = bm0 + wr * 32 + fi * 16 + l4 * 4 + p;
                    float v = acc[fi][fj][p];
                    if (post == 1) v = tanhf(v);
                    else if (post == 2) v = 1.0f / (1.0f + expf(-v));
                    if (outh)
                        outh[(size_t)orow * 320 + hoff + ocol] = f2bf(v);
                    else
                        outp[((size_t)orow * 1024 + ocol) * ostr + ooff] = f2bf(v);
                }
            }
        }
}

// ---------------- stage-1: 7 GEMMs in one launch ----------------
__global__ __launch_bounds__(256) void gemm_s1_kernel(
    const unsigned short* xr, const unsigned short* xk, const unsigned short* xv,
    const unsigned short* xw, const unsigned short* xa, const unsigned short* xg,
    const unsigned short* wtA, const unsigned short* wtB, const unsigned short* wtC,
    const unsigned short* wt_a1, const unsigned short* wt_v1,
    const unsigned short* wt_g1, const unsigned short* wt_w1,
    unsigned short* b_r, unsigned short* pk_bf, unsigned short* b_v,
    unsigned short* h_cat)
{
    const int nt = blockIdx.x;
    const int bm0 = blockIdx.y * GBM;
    const unsigned short* A; const unsigned short* WT;
    unsigned short* outp = nullptr; unsigned short* outh = nullptr;
    int Nc = 1024, nb = 0, ostr = 1, ooff = 0, hoff = 0, post = 0;
    if (nt < 16)      { A = xr; WT = wtC; outp = b_r; nb = nt; }
    else if (nt < 32) { A = xk; WT = wtA; outp = pk_bf; ostr = 4; ooff = 1; nb = nt - 16; }
    else if (nt < 48) { A = xv; WT = wtB; outp = b_v; nb = nt - 32; }
    else if (nt == 48){ A = xa; WT = wt_a1; outh = h_cat; hoff = 0;   Nc = 64; }
    else if (nt == 49){ A = xv; WT = wt_v1; outh = h_cat; hoff = 64;  Nc = 32; }
    else if (nt < 53) { A = xg; WT = wt_g1; outh = h_cat; hoff = 96;  Nc = 160; nb = nt - 50; post = 2; }
    else              { A = xw; WT = wt_w1; outh = h_cat; hoff = 256; Nc = 64; post = 1; }
    gemm_core(A, 1024, WT, 1024, Nc, nb * 64, bm0, outp, ostr, ooff, outh, hoff, post);
}

// ---------------- stage-2: 4 GEMMs in one launch (A = h_cat) ----------------
__global__ __launch_bounds__(256) void gemm_s2_kernel(
    const unsigned short* __restrict__ h_cat,
    const unsigned short* wt_a2, const unsigned short* wt_v2,
    const unsigned short* wt_g2, const unsigned short* wt_w2,
    unsigned short* pk_bf, unsigned short* b_g)
{
    const int g = blockIdx.x >> 4;
    const int nb = blockIdx.x & 15;
    const int bm0 = blockIdx.y * GBM;
    const unsigned short* WT;
    unsigned short* outp; int K, aoff, ostr, ooff;
    if      (g == 0) { WT = wt_a2; K = 64;  aoff = 0;   outp = pk_bf; ostr = 4; ooff = 2; }
    else if (g == 1) { WT = wt_v2; K = 32;  aoff = 64;  outp = pk_bf; ostr = 4; ooff = 3; }
    else if (g == 2) { WT = wt_g2; K = 160; aoff = 96;  outp = b_g;   ostr = 1; ooff = 0; }
    else             { WT = wt_w2; K = 64;  aoff = 256; outp = pk_bf; ostr = 4; ooff = 0; }
    gemm_core(h_cat + aoff, 320, WT, K, 1024, nb * 64, bm0, outp, ostr, ooff, nullptr, 0, 0);
}

// ---------------- final GEMM: out = y_bf @ W_o + residual (f32 out) ----------------
__global__ __launch_bounds__(256) void gemm_final_kernel(
    const unsigned short* __restrict__ Y, const unsigned short* __restrict__ WT,
    const float* __restrict__ addend, float* __restrict__ out)
{
    const int K = 1024;
    __shared__ unsigned short As[GBM][LDK];
    __shared__ unsigned short Bs[GBN][LDK];

    const int tid = threadIdx.x;
    const int lane = tid & 63;
    const int wid = tid >> 6;
    const int wr = wid >> 1, wc = wid & 1;
    const int l15 = lane & 15, l4 = lane >> 4;
    const int bm0 = blockIdx.y * GBM;
    const int bn0 = blockIdx.x * GBN;
    const int ar = tid >> 2;
    const int as = (tid & 3) << 4;
    const int row = bm0 + ar;
    const int brn = tid >> 2;
    const int bks = (tid & 3) << 4;

    f32x4 acc[2][2] = {};

    for (int k0 = 0; k0 < K; k0 += GBK) {
#pragma unroll
        for (int i = 0; i < 2; ++i) {
            const int kk = as + 8 * i;
            *(ushortx8*)&As[ar][kk] =
                *(const ushortx8*)(Y + (size_t)row * 1024 + k0 + kk);
        }
#pragma unroll
        for (int i = 0; i < 2; ++i) {
            const int kk = bks + 8 * i;
            *(ushortx8*)&Bs[brn][kk] =
                *(const ushortx8*)(WT + (size_t)(bn0 + brn) * K + k0 + kk);
        }
        __syncthreads();
#pragma unroll
        for (int ks = 0; ks < 2; ++ks) {
            bf16x8 af0 = *(const bf16x8*)&As[wr * 32 +      l15][ks * 32 + l4 * 8];
            bf16x8 af1 = *(const bf16x8*)&As[wr * 32 + 16 + l15][ks * 32 + l4 * 8];
            bf16x8 bg0 = *(const bf16x8*)&Bs[wc * 32 +      l15][ks * 32 + l4 * 8];
            bf16x8 bg1 = *(const bf16x8*)&Bs[wc * 32 + 16 + l15][ks * 32 + l4 * 8];
            acc[0][0] = __builtin_amdgcn_mfma_f32_16x16x32_bf16(af0, bg0, acc[0][0], 0, 0, 0);
            acc[0][1] = __builtin_amdgcn_mfma_f32_16x16x32_bf16(af0, bg1, acc[0][1], 0, 0, 0);
            acc[1][0] = __builtin_amdgcn_mfma_f32_16x16x32_bf16(af1, bg0, acc[1][0], 0, 0, 0);
            acc[1][1] = __builtin_amdgcn_mfma_f32_16x16x32_bf16(af1, bg1, acc[1][1], 0, 0, 0);
        }
        __syncthreads();
    }

#pragma unroll
    for (int fi = 0; fi < 2; ++fi)
#pragma unroll
        for (int fj = 0; fj < 2; ++fj) {
            const int ocol = bn0 + wc * 32 + fj * 16 + l15;
#pragma unroll
            for (int p = 0; p < 4; ++p) {
                const int orow = bm0 + wr * 32 + fi * 16 + l4 * 4 + p;
                out[(size_t)orow * 1024 + ocol] =
                    acc[fi][fj][p] + addend[(size_t)orow * 1024 + ocol];
            }
        }
}

// ---------------- fused stage3 + scan-input repack + dots ----------------
// block = 4 waves = 4 consecutive timesteps of one (b,h).
__global__ __launch_bounds__(256) void stage3_dots_kernel(
    const unsigned short* __restrict__ pk_bf, unsigned short* b_v,
    const float* __restrict__ v_first, const unsigned short* __restrict__ b_r,
    const float* w0, const float* a0, const float* v0,
    const float* k_k, const float* k_a,
    float* __restrict__ E, unsigned int* __restrict__ K12,
    unsigned int* __restrict__ A12, unsigned int* __restrict__ B12,
    float4* __restrict__ cd)
{
    __shared__ float lds[4][64][4];
    const int tid = threadIdx.x;
    const int w = tid >> 6, lane = tid & 63;
    const int bh = blockIdx.x >> 8;
    const int j4 = blockIdx.x & 255;
    const int b = bh >> 4, h = bh & 15;
    const int t = j4 * 4 + w;
    const int j = t >> 1;
    const int half = t & 1;
    const int row = b * T_SEQ + t;
    const int c = h * N_DIM + lane;
    const size_t idx = (size_t)row * C_DIM + c;

    const ushortx4 raw = *(const ushortx4*)(pk_bf + idx * 4);
    const float w_lora = bf2f(raw.x), kl = bf2f(raw.y);
    const float a_lora = bf2f(raw.z), v_gate = bf2f(raw.w);

    float kk = kl * k_k[c];
    float ss = wred64(kk * kk);
    const float nrm = fmaxf(sqrtf(ss), 1e-12f);
    const float kkn = kk / nrm;

    const float a = 1.0f / (1.0f + expf(-(a0[c] + a_lora)));

    const float u = w0[c] + w_lora;
    const float lnw = -log1pf(expf(-u)) - 0.5f;
    const float ew = expf(-expf(lnw));

    const float sv = 1.0f / (1.0f + expf(-(v0[c] + v_gate)));
    const float vl = bf2f(b_v[idx]);
    const float v = fmaf(v_first[idx] - vl, sv, vl);

    const float ko = kl * (1.0f + (a - 1.0f) * k_a[c]);
    const float aa = -kkn;
    const float bb = kkn * a;

    b_v[idx] = f2bf(v);
    E[((size_t)(bh * NBLK + j) * 2 + half) * 64 + lane] = ew;

    lds[w][lane][0] = ko;
    lds[w][lane][1] = aa;
    lds[w][lane][2] = bb;
    __syncthreads();

    if (half == 0) {
        const float ko2 = lds[w + 1][lane][0];
        const float aa2 = lds[w + 1][lane][1];
        const float bb2 = lds[w + 1][lane][2];
        const float r1 = bf2f(b_r[idx]);
        const size_t pidx = (size_t)(bh * NBLK + j) * 64 + lane;
        K12[pidx] = (unsigned int)f2bf(ko) | ((unsigned int)f2bf(ko2) << 16);
        A12[pidx] = (unsigned int)f2bf(aa) | ((unsigned int)f2bf(aa2) << 16);
        B12[pidx] = (unsigned int)f2bf(bb) | ((unsigned int)f2bf(bb2) << 16);

        float ca = bb * aa2;
        float ck = ko * aa2;
        float cb = bb * r1;
        float cr = ko * r1;
        DPP6X4(ca, ck, cb, cr);
        if (lane == 63)
            cd[bh * NBLK + j] = make_float4(ca, ck, cb, cr);
    }
}

// ---------------- sequential scan: 2-step blocked, DPP reduce, bf16 inputs -------
#define LOAD_BLK(E1, E2, Ku, Au, Bu, R1, R2, V1, V2, CD, j)                    \
    do {                                                                       \
        const int jc_ = ((j) < NBLK) ? (j) : (NBLK - 1);                       \
        E1 = ep[jc_ * 128];  E2 = ep[jc_ * 128 + 64];                          \
        Ku = kp[jc_ * 64];   Au = apt[jc_ * 64];   Bu = bpt[jc_ * 64];         \
        R1 = bf2f(rp[jc_ * 2048]); R2 = bf2f(rp[jc_ * 2048 + 1024]);           \
        V1 = bf2f(vp[jc_ * 2048]); V2 = bf2f(vp[jc_ * 2048 + 1024]);           \
        CD = cdp[jc_];                                                         \
    } while (0)

#define COMP_BLK(E1, E2, Ku, Au, Bu, R1, R2, V1, V2, CD, jblk)                 \
    do {                                                                       \
        const float aa1_ = bflo(Au), aa2_ = bfhi(Au);                          \
        const float ewaa_ = E1 * aa2_;                                         \
        const float ewrr_ = E1 * R1;                                           \
        float p1_ = s * aa1_;                                                  \
        float u_  = s * ewaa_;                                                 \
        float w_  = s * ewrr_;                                                 \
        float q_  = s * r_prev;                                                \
        DPP6X4(p1_, u_, w_, q_);                                               \
        const float ps1_ = rdl63(p1_);                                         \
        const float us_  = rdl63(u_);                                          \
        const float p2_ = fmaf(V1, CD.y, fmaf(ps1_, CD.x, us_));               \
        if (lane == 63) {                                                      \
            const int tb_ = (jblk) * 2048;                                     \
            if ((jblk) > 0) op[tb_ - 1024] = f2bf(q_);                         \
            op[tb_] = f2bf(fmaf(V1, CD.w, fmaf(ps1_, CD.z, w_)));              \
        }                                                                      \
        const float bb1_ = bflo(Bu), bb2_ = bfhi(Bu);                          \
        const float kk1_ = bflo(Ku), kk2_ = bfhi(Ku);                          \
        const float x1_ = fmaf(s, E1 * E2, ps1_ * (bb1_ * E2));                \
        const float x2_ = fmaf(V1, kk1_ * E2, p2_ * bb2_);                     \
        s = x1_ + x2_ + V2 * kk2_;                                             \
        r_prev = R2;                                                           \
    } while (0)

__global__ __launch_bounds__(256) void scan_kernel(
    const float* __restrict__ E, const unsigned int* __restrict__ K12,
    const unsigned int* __restrict__ A12, const unsigned int* __restrict__ B12,
    const unsigned short* __restrict__ r, const unsigned short* __restrict__ v,
    const float4* __restrict__ cdots, unsigned short* __restrict__ o)
{
    const int gw = (blockIdx.x * blockDim.x + threadIdx.x) >> 6;
    const int lane = threadIdx.x & 63;
    const int vi = gw & 63;
    const int bh = gw >> 6;
    const int b = bh >> 4;
    const int h = bh & 15;

    const int base0 = b * T_SEQ * C_DIM + h * N_DIM;
    const float* ep = E + (size_t)(bh * NBLK) * 128 + lane;
    const unsigned int* kp = K12 + (size_t)(bh * NBLK) * 64 + lane;
    const unsigned int* apt = A12 + (size_t)(bh * NBLK) * 64 + lane;
    const unsigned int* bpt = B12 + (size_t)(bh * NBLK) * 64 + lane;
    const unsigned short* rp = r + base0 + lane;
    const unsigned short* vp = v + base0 + vi;
    const float4* cdp = cdots + bh * NBLK;
    unsigned short* op = o + base0 + vi;

    float s = 0.0f, r_prev = 0.0f;

    float eA1, eA2, rA1, rA2, vA1, vA2; unsigned int kA, aA, bA; float4 cdA;
    float eB1, eB2, rB1, rB2, vB1, vB2; unsigned int kB, aB, bB; float4 cdB;
    float eC1, eC2, rC1, rC2, vC1, vC2; unsigned int kC, aC, bC; float4 cdC;
    float eD1, eD2, rD1, rD2, vD1, vD2; unsigned int kD, aD, bD; float4 cdD;

    LOAD_BLK(eA1, eA2, kA, aA, bA, rA1, rA2, vA1, vA2, cdA, 0);
    LOAD_BLK(eB1, eB2, kB, aB, bB, rB1, rB2, vB1, vB2, cdB, 1);

    for (int j = 0; j < NBLK; j += 4) {
        LOAD_BLK(eC1, eC2, kC, aC, bC, rC1, rC2, vC1, vC2, cdC, j + 2);
        COMP_BLK(eA1, eA2, kA, aA, bA, rA1, rA2, vA1, vA2, cdA, j);
        LOAD_BLK(eD1, eD2, kD, aD, bD, rD1, rD2, vD1, vD2, cdD, j + 3);
        COMP_BLK(eB1, eB2, kB, aB, bB, rB1, rB2, vB1, vB2, cdB, j + 1);
        LOAD_BLK(eA1, eA2, kA, aA, bA, rA1, rA2, vA1, vA2, cdA, j + 4);
        COMP_BLK(eC1, eC2, kC, aC, bC, rC1, rC2, vC1, vC2, cdC, j + 2);
        LOAD_BLK(eB1, eB2, kB, aB, bB, rB1, rB2, vB1, vB2, cdB, j + 5);
        COMP_BLK(eD1, eD2, kD, aD, bD, rD1, rD2, vD1, vD2, cdD, j + 3);
    }

    float q = s * r_prev;
    DPPADD(q, 0x111); DPPADD(q, 0x112); DPPADD(q, 0x114);
    DPPADD(q, 0x118); DPPADD(q, 0x142); DPPADD(q, 0x143);
    if (lane == 63)
        op[(T_SEQ - 1) * C_DIM] = f2bf(q);
}

// ---------------- groupnorm + bonus + gate (bf16 in, bf16 y out) ----------------
__global__ __launch_bounds__(256) void post_kernel(
    const unsigned short* o, const unsigned short* r,
    const unsigned int* K12, const unsigned short* v, const unsigned short* g,
    const float* r_k, const float* ln_w, const float* ln_b,
    unsigned short* y)
{
    const int gw = (blockIdx.x * blockDim.x + threadIdx.x) >> 6;
    const int lane = threadIdx.x & 63;
    const int row = gw >> 4;
    const int h = gw & 15;
    const int c = h * N_DIM + lane;
    const size_t idx = (size_t)row * C_DIM + c;
    const int b = row >> 10;
    const int t = row & 1023;
    const int bh = b * 16 + h;
    const unsigned int Ku = K12[(size_t)(bh * NBLK + (t >> 1)) * 64 + lane];
    const float kt = (t & 1) ? bfhi(Ku) : bflo(Ku);

    const float oo = bf2f(o[idx]);
    float s1 = oo, s2 = oo * oo;
#pragma unroll
    for (int m = 32; m; m >>= 1) {
        s1 += __shfl_xor(s1, m);
        s2 += __shfl_xor(s2, m);
    }
    const float mu = s1 * (1.0f / 64.0f);
    const float var = s2 * (1.0f / 64.0f) - mu * mu;
    float yv = (oo - mu) * rsqrtf(var + 0.00064f);
    yv = yv * ln_w[c] + ln_b[c];

    const float t3 = wred64(bf2f(r[idx]) * kt * r_k[c]);
    yv += t3 * bf2f(v[idx]);
    y[idx] = f2bf(yv * bf2f(g[idx]));
}

extern "C" void kernel_launch(void* const* d_in, const int* in_sizes, int n_in,
                              void* d_out, int out_size, void* d_ws, size_t ws_size,
                              hipStream_t stream) {
    (void)in_sizes; (void)n_in; (void)out_size; (void)ws_size;

    const float* residual = (const float*)d_in[0];
    const float* x        = (const float*)d_in[1];
    const float* v_first  = (const float*)d_in[2];
    const float* mr = (const float*)d_in[6];
    const float* mw = (const float*)d_in[7];
    const float* mk = (const float*)d_in[8];
    const float* mv = (const float*)d_in[9];
    const float* ma = (const float*)d_in[10];
    const float* mg = (const float*)d_in[11];
    const float* w0 = (const float*)d_in[12];
    const float* w1 = (const float*)d_in[13];
    const float* w2 = (const float*)d_in[14];
    const float* a0 = (const float*)d_in[15];
    const float* a1 = (const float*)d_in[16];
    const float* a2 = (const float*)d_in[17];
    const float* v0 = (const float*)d_in[18];
    const float* v1 = (const float*)d_in[19];
    const float* v2 = (const float*)d_in[20];
    const float* g1 = (const float*)d_in[21];
    const float* g2 = (const float*)d_in[22];
    const float* k_k = (const float*)d_in[23];
    const float* k_a = (const float*)d_in[24];
    const float* r_k = (const float*)d_in[25];
    const float* W_r = (const float*)d_in[26];
    const float* W_k = (const float*)d_in[27];
    const float* W_v = (const float*)d_in[28];
    const float* W_o = (const float*)d_in[29];
    const float* ln_w = (const float*)d_in[30];
    const float* ln_b = (const float*)d_in[31];

    float* out = (float*)d_out;
    char* wsb = (char*)d_ws;

    // ---- workspace layout (bytes); top = 67,895,296 < 69,730,304 proven ----
    unsigned short* xr = (unsigned short*)(wsb + 0);            // 4 MiB each
    unsigned short* xk = (unsigned short*)(wsb + 4194304);
    unsigned short* xv = (unsigned short*)(wsb + 8388608);
    unsigned short* xw = (unsigned short*)(wsb + 12582912);
    unsigned short* xa = (unsigned short*)(wsb + 16777216);
    unsigned short* xg = (unsigned short*)(wsb + 20971520);     // ends 25,165,824
    // overlays (premix dead after stage-1):
    float*        E   = (float*)(wsb + 0);                      // 8 MiB [0,8M)
    unsigned int* K12 = (unsigned int*)(wsb + 8388608);         // 4 MiB
    unsigned int* A12 = (unsigned int*)(wsb + 12582912);        // 4 MiB
    unsigned int* B12 = (unsigned int*)(wsb + 16777216);        // 4 MiB (ends 20,971,520)
    unsigned short* wtD = (unsigned short*)(wsb + 20971520);    // 2 MiB (over xg, post-s1)

    unsigned short* pk_bf = (unsigned short*)(wsb + 25165824);  // 16 MiB [M][C]x4
    unsigned short* y_bf  = (unsigned short*)(wsb + 25165824);  // 4 MiB overlay (post-stage3)
    unsigned short* b_r = (unsigned short*)(wsb + 41943040);    // 4 MiB
    unsigned short* b_v = (unsigned short*)(wsb + 46137344);    // 4 MiB
    unsigned short* b_o = (unsigned short*)(wsb + 50331648);    // 4 MiB
    unsigned short* b_g = (unsigned short*)(wsb + 54525952);    // 4 MiB
    unsigned short* h_cat = (unsigned short*)(wsb + 58720256);  // 1.25 MiB [2048][320]
    float4* cdots = (float4*)(wsb + 60030976);                  // 256 KiB
    unsigned short* wt_a1 = (unsigned short*)(wsb + 60293120);
    unsigned short* wt_v1 = (unsigned short*)(wsb + 60424192);
    unsigned short* wt_g1 = (unsigned short*)(wsb + 60489728);
    unsigned short* wt_a2 = (unsigned short*)(wsb + 60817408);
    unsigned short* wt_v2 = (unsigned short*)(wsb + 60948480);
    unsigned short* wt_g2 = (unsigned short*)(wsb + 61014016);
    unsigned short* wt_w1 = (unsigned short*)(wsb + 61341696);
    unsigned short* wt_w2 = (unsigned short*)(wsb + 61472768);
    unsigned short* wtA = (unsigned short*)(wsb + 61603840);    // 2 MiB (W_k)
    unsigned short* wtB = (unsigned short*)(wsb + 63700992);    // 2 MiB (W_v)
    unsigned short* wtC = (unsigned short*)(wsb + 65798144);    // 2 MiB (W_r) end 67,895,296

    const dim3 blk(256);
    const dim3 tblk(32, 8);

    // 1) premix all six token-shift variants (bf16)
    premix_kernel<<<dim3(1024), blk, 0, stream>>>(
        x, mr, mk, mv, mw, ma, mg, xr, xk, xv, xw, xa, xg);

    // 2) transpose W_k, W_v, W_r + all small weights
    trans_all_kernel<<<dim3(3712), tblk, 0, stream>>>(
        W_k, W_v, W_r, w1, a1, v1, g1, a2, v2, g2, w2,
        wtA, wtB, wtC, wt_w1, wt_a1, wt_v1, wt_g1, wt_a2, wt_v2, wt_g2, wt_w2);

    // 3) stage-1: r, k, v, a1, v1, g1, w1 (one launch)
    gemm_s1_kernel<<<dim3(54, 32), blk, 0, stream>>>(
        xr, xk, xv, xw, xa, xg, wtA, wtB, wtC,
        wt_a1, wt_v1, wt_g1, wt_w1, b_r, pk_bf, b_v, h_cat);

    // 4) W_o -> wtD (over dead xg)
    wtrans_kernel<<<dim3(32, 32), tblk, 0, stream>>>(W_o, wtD);

    // 5) stage-2: a2, v2, g2, w2
    gemm_s2_kernel<<<dim3(64, 32), blk, 0, stream>>>(
        h_cat, wt_a2, wt_v2, wt_g2, wt_w2, pk_bf, b_g);

    // 6) stage3 + repack + dots (E/K12/A12/B12 over dead premix)
    stage3_dots_kernel<<<dim3(32 * 256), blk, 0, stream>>>(
        pk_bf, b_v, v_first, b_r, w0, a0, v0, k_k, k_a,
        E, K12, A12, B12, cdots);

    // 7) sequential scan
    scan_kernel<<<dim3(512), blk, 0, stream>>>(
        E, K12, A12, B12, b_r, b_v, cdots, b_o);

    // 8) groupnorm + bonus + gate -> y_bf (over dead pk_bf)
    post_kernel<<<dim3(8192), blk, 0, stream>>>(
        b_o, b_r, K12, b_v, b_g, r_k, ln_w, ln_b, y_bf);

    // 9) output projection + residual
    gemm_final_kernel<<<dim3(16, 32), blk, 0, stream>>>(y_bf, wtD, residual, out);
}

// Round 9
// 247.234 us; speedup vs baseline: 5.4122x; 1.1697x over previous
//
#include <hip/hip_runtime.h>
#include <math.h>

// Problem constants
#define B_DIM 2
#define T_SEQ 1024
#define C_DIM 1024
#define H_DIM 16
#define N_DIM 64
#define M_ROWS (B_DIM * T_SEQ)   // 2048
#define NBLK 512                 // T/2 two-step blocks

// MFMA GEMM tiling
#define GBM 64
#define GBN 64
#define GBK 64
#define LDK 88

// LDS column swizzle: rows {r,r+8,r+16,r+24} share banks at stride-88 shorts;
// XOR the 8-short granule index with (row>>3)&3 to spread them. Preserves
// 16B alignment of b128 reads and 8B writes.
#define SW(r, c) ((c) ^ (((((r) >> 3) & 3)) << 3))

typedef __attribute__((ext_vector_type(8))) short bf16x8;
typedef __attribute__((ext_vector_type(4))) float f32x4;
typedef unsigned short ushortx4 __attribute__((ext_vector_type(4)));
typedef unsigned short ushortx8 __attribute__((ext_vector_type(8)));

__device__ __forceinline__ unsigned short f2bf(float f) {
    unsigned int u = __float_as_uint(f);
    u = (u + 0x7FFFu + ((u >> 16) & 1u)) >> 16;   // RNE
    return (unsigned short)u;
}
__device__ __forceinline__ float bf2f(unsigned short h) {
    return __uint_as_float(((unsigned int)h) << 16);
}
__device__ __forceinline__ float bflo(unsigned int u) {
    return __uint_as_float(u << 16);
}
__device__ __forceinline__ float bfhi(unsigned int u) {
    return __uint_as_float(u & 0xFFFF0000u);
}
__device__ __forceinline__ unsigned int pack2(float lo, float hi) {
    return (unsigned int)f2bf(lo) | ((unsigned int)f2bf(hi) << 16);
}

__device__ __forceinline__ float wred64(float v) {
#pragma unroll
    for (int m = 32; m; m >>= 1) v += __shfl_xor(v, m);
    return v;
}

// DPP wave-64 sum network: after 6 adds the FULL sum is in lane 63. old=0.
#define DPPADD(v, ctrl)                                                        \
    v += __int_as_float(__builtin_amdgcn_update_dpp(                           \
        0, __float_as_int(v), (ctrl), 0xF, 0xF, false))

#define DPP6X4(a, b, c, d)                                                     \
    do {                                                                       \
        DPPADD(a, 0x111); DPPADD(b, 0x111); DPPADD(c, 0x111); DPPADD(d, 0x111);\
        DPPADD(a, 0x112); DPPADD(b, 0x112); DPPADD(c, 0x112); DPPADD(d, 0x112);\
        DPPADD(a, 0x114); DPPADD(b, 0x114); DPPADD(c, 0x114); DPPADD(d, 0x114);\
        DPPADD(a, 0x118); DPPADD(b, 0x118); DPPADD(c, 0x118); DPPADD(d, 0x118);\
        DPPADD(a, 0x142); DPPADD(b, 0x142); DPPADD(c, 0x142); DPPADD(d, 0x142);\
        DPPADD(a, 0x143); DPPADD(b, 0x143); DPPADD(c, 0x143); DPPADD(d, 0x143);\
    } while (0)

__device__ __forceinline__ float rdl63(float v) {
    return __int_as_float(__builtin_amdgcn_readlane(__float_as_int(v), 63));
}

// ---------------- premix: all six token-shift mixes, fp32 -> bf16 ----------------
__global__ __launch_bounds__(256) void premix_kernel(
    const float* __restrict__ x,
    const float* mr, const float* mk, const float* mv,
    const float* mw, const float* ma, const float* mg,
    unsigned short* xr, unsigned short* xk, unsigned short* xv,
    unsigned short* xw, unsigned short* xa, unsigned short* xg)
{
    const int g = blockIdx.x * 256 + threadIdx.x;
    const size_t base = (size_t)g * 8;
    const int row = (int)(base >> 10);
    const int col = (int)(base & 1023);
    const int t_in = row & (T_SEQ - 1);

    const float* xp = x + (size_t)row * C_DIM + col;
    float4 a0 = *(const float4*)xp;
    float4 a1 = *(const float4*)(xp + 4);
    float4 p0 = make_float4(0.f, 0.f, 0.f, 0.f), p1 = p0;
    if (t_in > 0) {
        p0 = *(const float4*)(xp - C_DIM);
        p1 = *(const float4*)(xp - C_DIM + 4);
    }
    const float d0x = p0.x - a0.x, d0y = p0.y - a0.y, d0z = p0.z - a0.z, d0w = p0.w - a0.w;
    const float d1x = p1.x - a1.x, d1y = p1.y - a1.y, d1z = p1.z - a1.z, d1w = p1.w - a1.w;

    const float* ms[6] = {mr, mk, mv, mw, ma, mg};
    unsigned short* outs[6] = {xr, xk, xv, xw, xa, xg};
#pragma unroll
    for (int i = 0; i < 6; ++i) {
        const float4 m0 = *(const float4*)(ms[i] + col);
        const float4 m1 = *(const float4*)(ms[i] + col + 4);
        ushortx8 o;
        o[0] = f2bf(fmaf(d0x, m0.x, a0.x));
        o[1] = f2bf(fmaf(d0y, m0.y, a0.y));
        o[2] = f2bf(fmaf(d0z, m0.z, a0.z));
        o[3] = f2bf(fmaf(d0w, m0.w, a0.w));
        o[4] = f2bf(fmaf(d1x, m1.x, a1.x));
        o[5] = f2bf(fmaf(d1y, m1.y, a1.y));
        o[6] = f2bf(fmaf(d1z, m1.z, a1.z));
        o[7] = f2bf(fmaf(d1w, m1.w, a1.w));
        *(ushortx8*)(outs[i] + base) = o;
    }
}

// ---------------- single weight transpose (W_o, 1024x1024) ----------------
__global__ __launch_bounds__(256) void wtrans_kernel(
    const float* __restrict__ W, unsigned short* __restrict__ WT)
{
    __shared__ float tile[32][33];
    const int tx = threadIdx.x, ty = threadIdx.y;
    const int n0 = blockIdx.x * 32, k0 = blockIdx.y * 32;
#pragma unroll
    for (int i = 0; i < 4; ++i)
        tile[ty + i * 8][tx] = W[(size_t)(k0 + ty + i * 8) * 1024 + n0 + tx];
    __syncthreads();
#pragma unroll
    for (int i = 0; i < 4; ++i)
        WT[(size_t)(n0 + ty + i * 8) * 1024 + k0 + tx] = f2bf(tile[tx][ty + i * 8]);
}

// ---------------- batched transpose+convert: W_k, W_v, W_r + 8 small ----------------
__global__ __launch_bounds__(256) void trans_all_kernel(
    const float* Wk, const float* Wv, const float* Wr,
    const float* w1p, const float* a1p, const float* v1p, const float* g1p,
    const float* a2p, const float* v2p, const float* g2p, const float* w2p,
    unsigned short* wtA, unsigned short* wtB, unsigned short* wtC,
    unsigned short* wt_w1, unsigned short* wt_a1, unsigned short* wt_v1,
    unsigned short* wt_g1, unsigned short* wt_a2, unsigned short* wt_v2,
    unsigned short* wt_g2, unsigned short* wt_w2)
{
    __shared__ float tile[32][33];
    const int bid = blockIdx.x;
    const float* W; unsigned short* WT; int K, N, t0;
    if      (bid < 1024) { W = Wk;  WT = wtA;   K = 1024; N = 1024; t0 = 0;    }
    else if (bid < 2048) { W = Wv;  WT = wtB;   K = 1024; N = 1024; t0 = 1024; }
    else if (bid < 3072) { W = Wr;  WT = wtC;   K = 1024; N = 1024; t0 = 2048; }
    else if (bid < 3136) { W = w1p; WT = wt_w1; K = 1024; N = 64;   t0 = 3072; }
    else if (bid < 3200) { W = a1p; WT = wt_a1; K = 1024; N = 64;   t0 = 3136; }
    else if (bid < 3232) { W = v1p; WT = wt_v1; K = 1024; N = 32;   t0 = 3200; }
    else if (bid < 3392) { W = g1p; WT = wt_g1; K = 1024; N = 160;  t0 = 3232; }
    else if (bid < 3456) { W = a2p; WT = wt_a2; K = 64;   N = 1024; t0 = 3392; }
    else if (bid < 3488) { W = v2p; WT = wt_v2; K = 32;   N = 1024; t0 = 3456; }
    else if (bid < 3648) { W = g2p; WT = wt_g2; K = 160;  N = 1024; t0 = 3488; }
    else                 { W = w2p; WT = wt_w2; K = 64;   N = 1024; t0 = 3648; }
    const int lt = bid - t0;
    const int ntx = N >> 5;
    const int n0 = (lt % ntx) * 32;
    const int k0 = (lt / ntx) * 32;
    const int tx = threadIdx.x, ty = threadIdx.y;
#pragma unroll
    for (int i = 0; i < 4; ++i)
        tile[ty + i * 8][tx] = W[(size_t)(k0 + ty + i * 8) * N + n0 + tx];
    __syncthreads();
#pragma unroll
    for (int i = 0; i < 4; ++i)
        WT[(size_t)(n0 + ty + i * 8) * K + k0 + tx] = f2bf(tile[tx][ty + i * 8]);
}

// ---------------- generic MFMA GEMM core (bf16 A, bf16 B^T, LDS swizzled) ----------
__device__ __forceinline__ void gemm_core(
    const unsigned short* __restrict__ Aarr, int arow_stride,
    const unsigned short* __restrict__ WT, int K, int Nc, int bn0, int bm0,
    unsigned short* outp, int ostr, int ooff,
    unsigned short* outh, int hoff, int post)
{
    __shared__ unsigned short As[GBM][LDK];
    __shared__ unsigned short Bs[GBN][LDK];

    const int tid = threadIdx.x;
    const int lane = tid & 63;
    const int wid = tid >> 6;
    const int wr = wid >> 1, wc = wid & 1;
    const int l15 = lane & 15, l4 = lane >> 4;

    const int ar = tid >> 2;
    const int as = (tid & 3) << 4;
    const int row = bm0 + ar;
    const int brn = tid >> 2;
    const int bks = (tid & 3) << 4;
    const bool bn_ok = (bn0 + brn) < Nc;

    const int ra0 = wr * 32 + l15, ra1 = wr * 32 + 16 + l15;
    const int rb0 = wc * 32 + l15, rb1 = wc * 32 + 16 + l15;

    f32x4 acc[2][2] = {};

    for (int k0 = 0; k0 < K; k0 += GBK) {
#pragma unroll
        for (int i = 0; i < 2; ++i) {
            const int kk = as + 8 * i;
            ushortx8 av = {0, 0, 0, 0, 0, 0, 0, 0};
            if (k0 + kk < K)
                av = *(const ushortx8*)(Aarr + (size_t)row * arow_stride + k0 + kk);
            *(ushortx8*)&As[ar][SW(ar, kk)] = av;
        }
#pragma unroll
        for (int i = 0; i < 2; ++i) {
            const int kk = bks + 8 * i;
            ushortx8 bv = {0, 0, 0, 0, 0, 0, 0, 0};
            if (bn_ok && (k0 + kk < K))
                bv = *(const ushortx8*)(WT + (size_t)(bn0 + brn) * K + k0 + kk);
            *(ushortx8*)&Bs[brn][SW(brn, kk)] = bv;
        }
        __syncthreads();
#pragma unroll
        for (int ks = 0; ks < 2; ++ks) {
            const int cc = ks * 32 + l4 * 8;
            bf16x8 af0 = *(const bf16x8*)&As[ra0][SW(ra0, cc)];
            bf16x8 af1 = *(const bf16x8*)&As[ra1][SW(ra1, cc)];
            bf16x8 bg0 = *(const bf16x8*)&Bs[rb0][SW(rb0, cc)];
            bf16x8 bg1 = *(const bf16x8*)&Bs[rb1][SW(rb1, cc)];
            acc[0][0] = __builtin_amdgcn_mfma_f32_16x16x32_bf16(af0, bg0, acc[0][0], 0, 0, 0);
            acc[0][1] = __builtin_amdgcn_mfma_f32_16x16x32_bf16(af0, bg1, acc[0][1], 0, 0, 0);
            acc[1][0] = __builtin_amdgcn_mfma_f32_16x16x32_bf16(af1, bg0, acc[1][0], 0, 0, 0);
            acc[1][1] = __builtin_amdgcn_mfma_f32_16x16x32_bf16(af1, bg1, acc[1][1], 0, 0, 0);
        }
        __syncthreads();
    }

#pragma unroll
    for (int fi = 0; fi < 2; ++fi)
#pragma unroll
        for (int fj = 0; fj < 2; ++fj) {
            const int ocol = bn0 + wc * 32 + fj * 16 + l15;
            if (ocol < Nc) {
#pragma unroll
                for (int p = 0; p < 4; ++p) {
                    const int orow = bm0 + wr * 32 + fi * 16 + l4 * 4 + p;
                    float v = acc[fi][fj][p];
                    if (post == 1) v = tanhf(v);
                    else if (post == 2) v = 1.0f / (1.0f + expf(-v));
                    if (outh)
                        outh[(size_t)orow * 320 + hoff + ocol] = f2bf(v);
                    else
                        outp[((size_t)orow * 1024 + ocol) * ostr + ooff] = f2bf(v);
                }
            }
        }
}

// ---------------- stage-1: 7 GEMMs in one launch ----------------
__global__ __launch_bounds__(256) void gemm_s1_kernel(
    const unsigned short* xr, const unsigned short* xk, const unsigned short* xv,
    const unsigned short* xw, const unsigned short* xa, const unsigned short* xg,
    const unsigned short* wtA, const unsigned short* wtB, const unsigned short* wtC,
    const unsigned short* wt_a1, const unsigned short* wt_v1,
    const unsigned short* wt_g1, const unsigned short* wt_w1,
    unsigned short* b_r, unsigned short* pk_bf, unsigned short* b_v,
    unsigned short* h_cat)
{
    const int nt = blockIdx.x;
    const int bm0 = blockIdx.y * GBM;
    const unsigned short* A; const unsigned short* WT;
    unsigned short* outp = nullptr; unsigned short* outh = nullptr;
    int Nc = 1024, nb = 0, ostr = 1, ooff = 0, hoff = 0, post = 0;
    if (nt < 16)      { A = xr; WT = wtC; outp = b_r; nb = nt; }
    else if (nt < 32) { A = xk; WT = wtA; outp = pk_bf; ostr = 4; ooff = 1; nb = nt - 16; }
    else if (nt < 48) { A = xv; WT = wtB; outp = b_v; nb = nt - 32; }
    else if (nt == 48){ A = xa; WT = wt_a1; outh = h_cat; hoff = 0;   Nc = 64; }
    else if (nt == 49){ A = xv; WT = wt_v1; outh = h_cat; hoff = 64;  Nc = 32; }
    else if (nt < 53) { A = xg; WT = wt_g1; outh = h_cat; hoff = 96;  Nc = 160; nb = nt - 50; post = 2; }
    else              { A = xw; WT = wt_w1; outh = h_cat; hoff = 256; Nc = 64; post = 1; }
    gemm_core(A, 1024, WT, 1024, Nc, nb * 64, bm0, outp, ostr, ooff, outh, hoff, post);
}

// ---------------- stage-2: 4 GEMMs in one launch (A = h_cat) ----------------
__global__ __launch_bounds__(256) void gemm_s2_kernel(
    const unsigned short* __restrict__ h_cat,
    const unsigned short* wt_a2, const unsigned short* wt_v2,
    const unsigned short* wt_g2, const unsigned short* wt_w2,
    unsigned short* pk_bf, unsigned short* b_g)
{
    const int g = blockIdx.x >> 4;
    const int nb = blockIdx.x & 15;
    const int bm0 = blockIdx.y * GBM;
    const unsigned short* WT;
    unsigned short* outp; int K, aoff, ostr, ooff;
    if      (g == 0) { WT = wt_a2; K = 64;  aoff = 0;   outp = pk_bf; ostr = 4; ooff = 2; }
    else if (g == 1) { WT = wt_v2; K = 32;  aoff = 64;  outp = pk_bf; ostr = 4; ooff = 3; }
    else if (g == 2) { WT = wt_g2; K = 160; aoff = 96;  outp = b_g;   ostr = 1; ooff = 0; }
    else             { WT = wt_w2; K = 64;  aoff = 256; outp = pk_bf; ostr = 4; ooff = 0; }
    gemm_core(h_cat + aoff, 320, WT, K, 1024, nb * 64, bm0, outp, ostr, ooff, nullptr, 0, 0);
}

// ---------------- final GEMM: out = y_bf @ W_o + residual (f32 out) ----------------
__global__ __launch_bounds__(256) void gemm_final_kernel(
    const unsigned short* __restrict__ Y, const unsigned short* __restrict__ WT,
    const float* __restrict__ addend, float* __restrict__ out)
{
    const int K = 1024;
    __shared__ unsigned short As[GBM][LDK];
    __shared__ unsigned short Bs[GBN][LDK];

    const int tid = threadIdx.x;
    const int lane = tid & 63;
    const int wid = tid >> 6;
    const int wr = wid >> 1, wc = wid & 1;
    const int l15 = lane & 15, l4 = lane >> 4;
    const int bm0 = blockIdx.y * GBM;
    const int bn0 = blockIdx.x * GBN;
    const int ar = tid >> 2;
    const int as = (tid & 3) << 4;
    const int row = bm0 + ar;
    const int brn = tid >> 2;
    const int bks = (tid & 3) << 4;

    const int ra0 = wr * 32 + l15, ra1 = wr * 32 + 16 + l15;
    const int rb0 = wc * 32 + l15, rb1 = wc * 32 + 16 + l15;

    f32x4 acc[2][2] = {};

    for (int k0 = 0; k0 < K; k0 += GBK) {
#pragma unroll
        for (int i = 0; i < 2; ++i) {
            const int kk = as + 8 * i;
            *(ushortx8*)&As[ar][SW(ar, kk)] =
                *(const ushortx8*)(Y + (size_t)row * 1024 + k0 + kk);
        }
#pragma unroll
        for (int i = 0; i < 2; ++i) {
            const int kk = bks + 8 * i;
            *(ushortx8*)&Bs[brn][SW(brn, kk)] =
                *(const ushortx8*)(WT + (size_t)(bn0 + brn) * K + k0 + kk);
        }
        __syncthreads();
#pragma unroll
        for (int ks = 0; ks < 2; ++ks) {
            const int cc = ks * 32 + l4 * 8;
            bf16x8 af0 = *(const bf16x8*)&As[ra0][SW(ra0, cc)];
            bf16x8 af1 = *(const bf16x8*)&As[ra1][SW(ra1, cc)];
            bf16x8 bg0 = *(const bf16x8*)&Bs[rb0][SW(rb0, cc)];
            bf16x8 bg1 = *(const bf16x8*)&Bs[rb1][SW(rb1, cc)];
            acc[0][0] = __builtin_amdgcn_mfma_f32_16x16x32_bf16(af0, bg0, acc[0][0], 0, 0, 0);
            acc[0][1] = __builtin_amdgcn_mfma_f32_16x16x32_bf16(af0, bg1, acc[0][1], 0, 0, 0);
            acc[1][0] = __builtin_amdgcn_mfma_f32_16x16x32_bf16(af1, bg0, acc[1][0], 0, 0, 0);
            acc[1][1] = __builtin_amdgcn_mfma_f32_16x16x32_bf16(af1, bg1, acc[1][1], 0, 0, 0);
        }
        __syncthreads();
    }

#pragma unroll
    for (int fi = 0; fi < 2; ++fi)
#pragma unroll
        for (int fj = 0; fj < 2; ++fj) {
            const int ocol = bn0 + wc * 32 + fj * 16 + l15;
#pragma unroll
            for (int p = 0; p < 4; ++p) {
                const int orow = bm0 + wr * 32 + fi * 16 + l4 * 4 + p;
                out[(size_t)orow * 1024 + ocol] =
                    acc[fi][fj][p] + addend[(size_t)orow * 1024 + ocol];
            }
        }
}

// ---------------- fused stage3 + scan-weight precompute + dots + bonus ----------------
// block = 4 waves = 4 consecutive timesteps of one (b,h).
__global__ __launch_bounds__(256) void stage3_dots_kernel(
    const unsigned short* __restrict__ pk_bf, unsigned short* b_v,
    const float* __restrict__ v_first, const unsigned short* __restrict__ b_r,
    const float* w0, const float* a0, const float* v0,
    const float* k_k, const float* k_a, const float* r_k,
    float4* __restrict__ P4, unsigned int* __restrict__ VP,
    unsigned int* __restrict__ P1, float* __restrict__ TB,
    float4* __restrict__ cd)
{
    __shared__ float lds[4][64][6];
    const int tid = threadIdx.x;
    const int w = tid >> 6, lane = tid & 63;
    const int bh = blockIdx.x >> 8;
    const int j4 = blockIdx.x & 255;
    const int b = bh >> 4, h = bh & 15;
    const int t = j4 * 4 + w;
    const int row = b * T_SEQ + t;
    const int c = h * N_DIM + lane;
    const size_t idx = (size_t)row * C_DIM + c;

    const ushortx4 raw = *(const ushortx4*)(pk_bf + idx * 4);
    const float w_lora = bf2f(raw.x), kl = bf2f(raw.y);
    const float a_lora = bf2f(raw.z), v_gate = bf2f(raw.w);

    float kkv = kl * k_k[c];
    float ss = wred64(kkv * kkv);
    const float nrm = fmaxf(sqrtf(ss), 1e-12f);
    const float kkn = kkv / nrm;

    const float a = 1.0f / (1.0f + expf(-(a0[c] + a_lora)));

    const float u = w0[c] + w_lora;
    const float lnw = -log1pf(expf(-u)) - 0.5f;
    const float ew = expf(-expf(lnw));

    const float sv = 1.0f / (1.0f + expf(-(v0[c] + v_gate)));
    const float vl = bf2f(b_v[idx]);
    const float v = fmaf(v_first[idx] - vl, sv, vl);

    const float ko = kl * (1.0f + (a - 1.0f) * k_a[c]);
    const float aa = -kkn;
    const float bb = kkn * a;
    const float r1f = bf2f(b_r[idx]);

    b_v[idx] = f2bf(v);

    // bonus term for this t: sum over head of r*k*r_k
    const float t3 = wred64(r1f * ko * r_k[c]);
    if (lane == 0) TB[bh * 1024 + t] = t3;

    lds[w][lane][0] = ko;
    lds[w][lane][1] = aa;
    lds[w][lane][2] = bb;
    lds[w][lane][3] = r1f;
    lds[w][lane][4] = v;
    lds[w][lane][5] = ew;
    __syncthreads();

    if ((w & 1) == 0) {
        const int j = j4 * 2 + (w >> 1);
        const float ko2 = lds[w + 1][lane][0];
        const float aa2 = lds[w + 1][lane][1];
        const float bb2 = lds[w + 1][lane][2];
        const float r2f = lds[w + 1][lane][3];
        const float v2f = lds[w + 1][lane][4];
        const float ew2 = lds[w + 1][lane][5];
        const size_t pidx = (size_t)(bh * NBLK + j) * 64 + lane;

        float4 q;
        q.x = ew * ew2;                                       // E12 (f32)
        q.y = __uint_as_float(pack2(aa, ew * aa2));           // aa1 | eaa2
        q.z = __uint_as_float(pack2(ew * r1f, bb * ew2));     // err1 | b1e2
        q.w = __uint_as_float(pack2(ko * ew2, bb2));          // k1e2 | bb2
        P4[pidx] = q;
        P1[pidx] = pack2(ko2, r2f);                           // kk2 | r2
        VP[pidx] = pack2(v, v2f);                             // v1 | v2

        float ca = bb * aa2, ck = ko * aa2, cb = bb * r1f, cr = ko * r1f;
        DPP6X4(ca, ck, cb, cr);
        if (lane == 63)
            cd[bh * NBLK + j] = make_float4(ca, ck, cb, cr);
    }
}

// ---------------- sequential scan: 2-step blocked, precomputed weights ----------------
#define LOAD_BLK(Q4, Vu, Pu, CD, j)                                            \
    do {                                                                       \
        Q4 = p4p[(size_t)(j) * 64];                                            \
        Pu = p1p[(size_t)(j) * 64];                                            \
        Vu = vpp[(size_t)(j) * 64];                                            \
        CD = cdp[(j)];                                                         \
    } while (0)

#define COMP_BLK(Q4, Vu, Pu, CD, jblk)                                         \
    do {                                                                       \
        const unsigned int qy_ = __float_as_uint(Q4.y);                        \
        const unsigned int qz_ = __float_as_uint(Q4.z);                        \
        const unsigned int qw_ = __float_as_uint(Q4.w);                        \
        float p1_ = s * bflo(qy_);                                             \
        float u_  = s * bfhi(qy_);                                             \
        float w_  = s * bflo(qz_);                                             \
        float q_  = s * r_prev;                                                \
        DPP6X4(p1_, u_, w_, q_);                                               \
        const float ps1_ = rdl63(p1_);                                         \
        const float us_  = rdl63(u_);                                          \
        const float V1_ = bflo(Vu), V2_ = bfhi(Vu);                            \
        const float p2_ = fmaf(V1_, CD.y, fmaf(ps1_, CD.x, us_));              \
        if (lane == 63) {                                                      \
            const int tb_ = (jblk) * 2048;                                     \
            if ((jblk) > 0) op[tb_ - 1024] = f2bf(q_);                         \
            op[tb_] = f2bf(fmaf(V1_, CD.w, fmaf(ps1_, CD.z, w_)));             \
        }                                                                      \
        float ns_ = fmaf(s, Q4.x, ps1_ * bfhi(qz_));                           \
        ns_ = fmaf(p2_, bfhi(qw_), ns_);                                       \
        ns_ = fmaf(V1_, bflo(qw_), ns_);                                       \
        s = fmaf(V2_, bflo(Pu), ns_);                                          \
        r_prev = bfhi(Pu);                                                     \
    } while (0)

__global__ __launch_bounds__(256) void scan_kernel(
    const float4* __restrict__ P4, const unsigned int* __restrict__ VP,
    const unsigned int* __restrict__ P1, const float4* __restrict__ cdots,
    unsigned short* __restrict__ o)
{
    const int gw = (blockIdx.x * blockDim.x + threadIdx.x) >> 6;
    const int lane = threadIdx.x & 63;
    const int vi = gw & 63;
    const int bh = gw >> 6;
    const int b = bh >> 4;
    const int h = bh & 15;

    const float4* p4p = P4 + (size_t)(bh * NBLK) * 64 + lane;
    const unsigned int* p1p = P1 + (size_t)(bh * NBLK) * 64 + lane;
    const unsigned int* vpp = VP + (size_t)(bh * NBLK) * 64 + vi;
    const float4* cdp = cdots + bh * NBLK;
    unsigned short* op = o + (size_t)(b * T_SEQ) * C_DIM + h * N_DIM + vi;

    float s = 0.0f, r_prev = 0.0f;

    float4 qA, cdA; unsigned int vA, pA;
    float4 qB, cdB; unsigned int vB, pB;
    float4 qC, cdC; unsigned int vC, pC;
    float4 qD, cdD; unsigned int vD, pD;

    LOAD_BLK(qA, vA, pA, cdA, 0);
    LOAD_BLK(qB, vB, pB, cdB, 1);

    for (int j = 0; j < NBLK; j += 4) {
        LOAD_BLK(qC, vC, pC, cdC, j + 2);
        COMP_BLK(qA, vA, pA, cdA, j);
        LOAD_BLK(qD, vD, pD, cdD, j + 3);
        COMP_BLK(qB, vB, pB, cdB, j + 1);
        LOAD_BLK(qA, vA, pA, cdA, j + 4);   // over-reads past end on last iter: in-ws, unused
        COMP_BLK(qC, vC, pC, cdC, j + 2);
        LOAD_BLK(qB, vB, pB, cdB, j + 5);
        COMP_BLK(qD, vD, pD, cdD, j + 3);
    }

    float q = s * r_prev;
    DPPADD(q, 0x111); DPPADD(q, 0x112); DPPADD(q, 0x114);
    DPPADD(q, 0x118); DPPADD(q, 0x142); DPPADD(q, 0x143);
    if (lane == 63)
        op[(T_SEQ - 1) * C_DIM] = f2bf(q);
}

// ---------------- groupnorm + bonus + gate (bf16 in, bf16 y out) ----------------
__global__ __launch_bounds__(256) void post_kernel(
    const unsigned short* o, const unsigned short* v, const unsigned short* g,
    const float* __restrict__ TB,
    const float* ln_w, const float* ln_b,
    unsigned short* y)
{
    const int gw = (blockIdx.x * blockDim.x + threadIdx.x) >> 6;
    const int lane = threadIdx.x & 63;
    const int row = gw >> 4;
    const int h = gw & 15;
    const int c = h * N_DIM + lane;
    const size_t idx = (size_t)row * C_DIM + c;
    const int b = row >> 10;
    const int t = row & 1023;

    const float oo = bf2f(o[idx]);
    float s1 = oo, s2 = oo * oo;
#pragma unroll
    for (int m = 32; m; m >>= 1) {
        s1 += __shfl_xor(s1, m);
        s2 += __shfl_xor(s2, m);
    }
    const float mu = s1 * (1.0f / 64.0f);
    const float var = s2 * (1.0f / 64.0f) - mu * mu;
    float yv = (oo - mu) * rsqrtf(var + 0.00064f);
    yv = yv * ln_w[c] + ln_b[c];

    yv += TB[(b * 16 + h) * 1024 + t] * bf2f(v[idx]);
    y[idx] = f2bf(yv * bf2f(g[idx]));
}

extern "C" void kernel_launch(void* const* d_in, const int* in_sizes, int n_in,
                              void* d_out, int out_size, void* d_ws, size_t ws_size,
                              hipStream_t stream) {
    (void)in_sizes; (void)n_in; (void)out_size; (void)ws_size;

    const float* residual = (const float*)d_in[0];
    const float* x        = (const float*)d_in[1];
    const float* v_first  = (const float*)d_in[2];
    const float* mr = (const float*)d_in[6];
    const float* mw = (const float*)d_in[7];
    const float* mk = (const float*)d_in[8];
    const float* mv = (const float*)d_in[9];
    const float* ma = (const float*)d_in[10];
    const float* mg = (const float*)d_in[11];
    const float* w0 = (const float*)d_in[12];
    const float* w1 = (const float*)d_in[13];
    const float* w2 = (const float*)d_in[14];
    const float* a0 = (const float*)d_in[15];
    const float* a1 = (const float*)d_in[16];
    const float* a2 = (const float*)d_in[17];
    const float* v0 = (const float*)d_in[18];
    const float* v1 = (const float*)d_in[19];
    const float* v2 = (const float*)d_in[20];
    const float* g1 = (const float*)d_in[21];
    const float* g2 = (const float*)d_in[22];
    const float* k_k = (const float*)d_in[23];
    const float* k_a = (const float*)d_in[24];
    const float* r_k = (const float*)d_in[25];
    const float* W_r = (const float*)d_in[26];
    const float* W_k = (const float*)d_in[27];
    const float* W_v = (const float*)d_in[28];
    const float* W_o = (const float*)d_in[29];
    const float* ln_w = (const float*)d_in[30];
    const float* ln_b = (const float*)d_in[31];

    float* out = (float*)d_out;
    char* wsb = (char*)d_ws;

    // ---- workspace layout (bytes); top = 67,895,296 < 69,730,304 proven ----
    unsigned short* xr = (unsigned short*)(wsb + 0);            // 4 MiB each
    unsigned short* xk = (unsigned short*)(wsb + 4194304);
    unsigned short* xv = (unsigned short*)(wsb + 8388608);
    unsigned short* xw = (unsigned short*)(wsb + 12582912);
    unsigned short* xa = (unsigned short*)(wsb + 16777216);
    unsigned short* xg = (unsigned short*)(wsb + 20971520);     // ends 25,165,824
    // overlays (premix dead after stage-1):
    float4*       P4 = (float4*)(wsb + 0);                      // 16 MiB [0,16M)
    unsigned int* VP = (unsigned int*)(wsb + 16777216);         // 4 MiB [16M,20M)
    unsigned short* wtD = (unsigned short*)(wsb + 20971520);    // 2 MiB (over xg head, post-s1)

    unsigned short* pk_bf = (unsigned short*)(wsb + 25165824);  // 16 MiB [M][C]x4
    unsigned short* y_bf  = (unsigned short*)(wsb + 25165824);  // 4 MiB overlay (post-stage3)
    unsigned short* b_r = (unsigned short*)(wsb + 41943040);    // 4 MiB
    unsigned short* b_v = (unsigned short*)(wsb + 46137344);    // 4 MiB
    unsigned short* b_o = (unsigned short*)(wsb + 50331648);    // 4 MiB
    unsigned short* b_g = (unsigned short*)(wsb + 54525952);    // 4 MiB
    unsigned short* h_cat = (unsigned short*)(wsb + 58720256);  // 1.25 MiB [2048][320]
    float4* cdots = (float4*)(wsb + 60030976);                  // 256 KiB
    unsigned short* wt_a1 = (unsigned short*)(wsb + 60293120);
    unsigned short* wt_v1 = (unsigned short*)(wsb + 60424192);
    unsigned short* wt_g1 = (unsigned short*)(wsb + 60489728);
    unsigned short* wt_a2 = (unsigned short*)(wsb + 60817408);
    unsigned short* wt_v2 = (unsigned short*)(wsb + 60948480);
    unsigned short* wt_g2 = (unsigned short*)(wsb + 61014016);
    unsigned short* wt_w1 = (unsigned short*)(wsb + 61341696);
    unsigned short* wt_w2 = (unsigned short*)(wsb + 61472768);
    unsigned short* wtA = (unsigned short*)(wsb + 61603840);    // 2 MiB (W_k)
    unsigned short* wtB = (unsigned short*)(wsb + 63700992);    // 2 MiB (W_v)
    unsigned short* wtC = (unsigned short*)(wsb + 65798144);    // 2 MiB (W_r) end 67,895,296
    // overlays (wtA/wtB/wtC dead after stage-1):
    unsigned int* P1 = (unsigned int*)(wsb + 61603840);         // 4 MiB over wtA+wtB
    float*        TB = (float*)(wsb + 65798144);                // 128 KiB over wtC head

    const dim3 blk(256);
    const dim3 tblk(32, 8);

    // 1) premix all six token-shift variants (bf16)
    premix_kernel<<<dim3(1024), blk, 0, stream>>>(
        x, mr, mk, mv, mw, ma, mg, xr, xk, xv, xw, xa, xg);

    // 2) transpose W_k, W_v, W_r + all small weights
    trans_all_kernel<<<dim3(3712), tblk, 0, stream>>>(
        W_k, W_v, W_r, w1, a1, v1, g1, a2, v2, g2, w2,
        wtA, wtB, wtC, wt_w1, wt_a1, wt_v1, wt_g1, wt_a2, wt_v2, wt_g2, wt_w2);

    // 3) stage-1: r, k, v, a1, v1, g1, w1 (one launch)
    gemm_s1_kernel<<<dim3(54, 32), blk, 0, stream>>>(
        xr, xk, xv, xw, xa, xg, wtA, wtB, wtC,
        wt_a1, wt_v1, wt_g1, wt_w1, b_r, pk_bf, b_v, h_cat);

    // 4) W_o -> wtD (over dead xg head)
    wtrans_kernel<<<dim3(32, 32), tblk, 0, stream>>>(W_o, wtD);

    // 5) stage-2: a2, v2, g2, w2
    gemm_s2_kernel<<<dim3(64, 32), blk, 0, stream>>>(
        h_cat, wt_a2, wt_v2, wt_g2, wt_w2, pk_bf, b_g);

    // 6) stage3 + scan-weight precompute + dots + bonus
    stage3_dots_kernel<<<dim3(32 * 256), blk, 0, stream>>>(
        pk_bf, b_v, v_first, b_r, w0, a0, v0, k_k, k_a, r_k,
        P4, VP, P1, TB, cdots);

    // 7) sequential scan
    scan_kernel<<<dim3(512), blk, 0, stream>>>(P4, VP, P1, cdots, b_o);

    // 8) groupnorm + bonus + gate -> y_bf (over dead pk_bf)
    post_kernel<<<dim3(8192), blk, 0, stream>>>(
        b_o, b_v, b_g, TB, ln_w, ln_b, y_bf);

    // 9) output projection + residual
    gemm_final_kernel<<<dim3(16, 32), blk, 0, stream>>>(y_bf, wtD, residual, out);
}